// Round 9
// baseline (309.334 us; speedup 1.0000x reference)
//
#include <hip/hip_runtime.h>
#include <cstddef>

// learned_qp_solver: B=4096, NUM=256, NC=1530, IND=260, H=1024, OUT=1786, 5 iters.
//
//   KKT solve closed form:  x = G v + (b_eq/z0) z,  G = C^{-1} - z z^T / z0 (symmetric)
//   MLP on matrix cores (fp16 in / fp32 accum, v_mfma_f32_16x16x16_f16).
//   Fused QP kernel: 512 blocks x 512 threads; 8 rows/block; solve split across
//   two 4-wave halves over K; G read row-wise via symmetry (float4, L2-hot);
//   stencils via shuffles + wave halos.
//   __launch_bounds__(512,2): VGPR budget 256 -> NO scratch spills (round-8 lesson:
//   (512,4) squeezed to 64 VGPR and spilled ~90 MB of scratch traffic to HBM).
//
// ws layout (bytes):
//   [0,          29360128)  NO   fp32 [B][1792]
//   [29360128,   37748736)  h    fp16 [B][1024]
//   [37748736,   41406464)  W2T  fp16 [1786][1024]
//   [41406464,   41939456)  W1T  fp16 [1024][260]
//   [41939456,   42201600)  G    fp32 [256][256]
//   [42201600,   42202624)  zc   fp32 [256]

#define NUMV 256
#define QP_ITERS 5
#define NO_LD 1792
#define RPB 8

typedef _Float16 f16x4 __attribute__((ext_vector_type(4)));
typedef float f32x4 __attribute__((ext_vector_type(4)));

// ---------------- compile-time pentadiagonal Cholesky tables ----------------
struct FacT {
  double invd[256];
  double l1[257];
  double l2[258];
  double z[256];
  float  zcf[256];
};

constexpr double csqrt_(double x) {
  double g = (x > 1.0) ? x : 1.0;
  for (int i = 0; i < 64; ++i) g = 0.5 * (g + x / g);
  return g;
}

constexpr FacT make_fac() {
  FacT f{};
  const double T = 0.05, a = 1.0 / (T * T), b2 = a * a;
  double c0[256] = {}, c1[255] = {}, c2[254] = {};
  double dd[256] = {}, l1[256] = {}, l2[256] = {};
  for (int j = 0; j < 256; j++) {
    double cd1 = (j == 0 || j == 255) ? 1.0 : 2.0;
    double cd2 = (j == 0 || j == 255) ? 1.0 : ((j == 1 || j == 254) ? 5.0 : 6.0);
    c0[j] = 3.0 + 2.0 * a * cd1 + 2.0 * b2 * cd2;
  }
  for (int j = 0; j < 255; j++) c1[j] = -2.0 * a + 2.0 * b2 * ((j == 0 || j == 254) ? -2.0 : -4.0);
  for (int j = 0; j < 254; j++) c2[j] = 2.0 * b2;
  dd[0] = csqrt_(c0[0]); l1[0] = 0.0; l2[0] = 0.0;
  l1[1] = c1[0] / dd[0]; l2[1] = 0.0;
  dd[1] = csqrt_(c0[1] - l1[1] * l1[1]);
  for (int j = 2; j < 256; j++) {
    l2[j] = c2[j - 2] / dd[j - 2];
    l1[j] = (c1[j - 1] - l2[j] * l1[j - 1]) / dd[j - 1];
    dd[j] = csqrt_(c0[j] - l1[j] * l1[j] - l2[j] * l2[j]);
  }
  for (int j = 0; j < 256; j++) f.invd[j] = 1.0 / dd[j];
  for (int j = 0; j < 256; j++) f.l1[j] = l1[j];
  f.l1[256] = 0.0;
  for (int j = 0; j < 256; j++) f.l2[j] = l2[j];
  f.l2[256] = 0.0; f.l2[257] = 0.0;
  double w[256] = {}, zz[256] = {};
  w[0] = 1.0 / dd[0];
  w[1] = (-l1[1] * w[0]) / dd[1];
  for (int j = 2; j < 256; j++) w[j] = (-l1[j] * w[j - 1] - l2[j] * w[j - 2]) / dd[j];
  zz[255] = w[255] / dd[255];
  zz[254] = (w[254] - l1[255] * zz[255]) / dd[254];
  for (int j = 253; j >= 0; j--)
    zz[j] = (w[j] - l1[j + 1] * zz[j + 1] - l2[j + 2] * zz[j + 2]) / dd[j];
  for (int j = 0; j < 256; j++) f.z[j] = zz[j];
  for (int j = 0; j < 256; j++) f.zcf[j] = (float)(zz[j] / zz[0]);
  return f;
}

constexpr FacT FAC_HOST = make_fac();
__constant__ FacT FAC = FAC_HOST;

// ---- build G = C^{-1} - z z^T/z0: 8 blocks x 32 cols, fp64 recurrences in LDS ----
__global__ __launch_bounds__(32) void build_g(float* __restrict__ G, float* __restrict__ zc)
{
  __shared__ double w[256][32];
  const int t = threadIdx.x;
  const int c = blockIdx.x * 32 + t;
  double w1 = 0.0, w2 = 0.0;
#pragma unroll 4
  for (int j = 0; j < 256; j++) {
    double rhs = (j == c) ? 1.0 : 0.0;
    double wj = (rhs - FAC.l1[j] * w1 - FAC.l2[j] * w2) * FAC.invd[j];
    w[j][t] = wj;
    w2 = w1; w1 = wj;
  }
  const double zr = FAC.z[c] / FAC.z[0];
  double y1 = 0.0, y2 = 0.0;
#pragma unroll 4
  for (int j = 255; j >= 0; j--) {
    double yj = (w[j][t] - FAC.l1[j + 1] * y1 - FAC.l2[j + 2] * y2) * FAC.invd[j];
    G[(size_t)j * 256 + c] = (float)(yj - FAC.z[j] * zr);
    y2 = y1; y1 = yj;
  }
  zc[c] = FAC.zcf[c];
}

// ---------------- transpose + fp32->fp16 convert: in [K][N] -> out [N][K] ----------------
__global__ __launch_bounds__(256) void transpose_cvt(
    const float* __restrict__ in, _Float16* __restrict__ out, int K, int N)
{
  __shared__ float t[32][33];
  const int bk = blockIdx.x * 32, bn = blockIdx.y * 32;
  const int x = threadIdx.x, y = threadIdx.y;
  for (int yy = y; yy < 32; yy += 8) {
    const int k = bk + yy, n = bn + x;
    t[yy][x] = (k < K && n < N) ? in[(size_t)k * N + n] : 0.f;
  }
  __syncthreads();
  for (int yy = y; yy < 32; yy += 8) {
    const int n = bn + yy, k = bk + x;
    if (n < N && k < K) out[(size_t)n * K + k] = (_Float16)t[x][yy];
  }
}

// ---------------- MFMA GEMM: C = A * Bt^T + bias, tile 64x128, 4 waves ----------------
template<bool A_FP32, bool OUT_H16>
__global__ __launch_bounds__(256) void mfma_gemm(
    const void* __restrict__ Av, const _Float16* __restrict__ Bt,
    const float* __restrict__ bias, void* __restrict__ Cv,
    int M, int Nv, int K, int lda, int ldk, int ldc)
{
  __shared__ _Float16 At[64][36];
  __shared__ _Float16 Bs[128][36];
  const int tid = threadIdx.x;
  const int lane = tid & 63, wid = tid >> 6;
  const int wc = wid;
  const int lrow = lane & 15, lb = lane >> 4;
  const int m0 = blockIdx.x * 64, n0 = blockIdx.y * 128;
  const int arow = tid >> 2, akq = tid & 3;
  const int brow = tid >> 1, bkh = tid & 1;

  f32x4 acc[4][2];
#pragma unroll
  for (int i = 0; i < 4; i++)
#pragma unroll
    for (int j = 0; j < 2; j++) acc[i][j] = (f32x4)0.0f;

  const int nsteps = (K + 31) / 32;
  for (int t = 0; t < nsteps; ++t) {
    const int k0 = t * 32;
    if (A_FP32) {
      const float* A = (const float*)Av;
#pragma unroll
      for (int i = 0; i < 2; i++) {
        const int k = k0 + akq * 8 + i * 4;
        f16x4 hv = {};
        if (k + 4 <= K) {
          const float4 v = *reinterpret_cast<const float4*>(&A[(size_t)(m0 + arow) * lda + k]);
          hv[0] = (_Float16)v.x; hv[1] = (_Float16)v.y;
          hv[2] = (_Float16)v.z; hv[3] = (_Float16)v.w;
        }
        *reinterpret_cast<f16x4*>(&At[arow][akq * 8 + i * 4]) = hv;
      }
    } else {
      const _Float16* A = (const _Float16*)Av;
#pragma unroll
      for (int i = 0; i < 2; i++) {
        const int k = k0 + akq * 8 + i * 4;
        f16x4 hv = {};
        if (k + 4 <= K) hv = *reinterpret_cast<const f16x4*>(&A[(size_t)(m0 + arow) * lda + k]);
        *reinterpret_cast<f16x4*>(&At[arow][akq * 8 + i * 4]) = hv;
      }
    }
    {
      const int n = n0 + brow;
#pragma unroll
      for (int i = 0; i < 4; i++) {
        const int k = k0 + bkh * 16 + i * 4;
        f16x4 hv = {};
        if (n < Nv && k + 4 <= K)
          hv = *reinterpret_cast<const f16x4*>(&Bt[(size_t)n * ldk + k]);
        *reinterpret_cast<f16x4*>(&Bs[brow][bkh * 16 + i * 4]) = hv;
      }
    }
    __syncthreads();
#pragma unroll
    for (int h = 0; h < 2; h++) {
      f16x4 af[4], bf[2];
#pragma unroll
      for (int i = 0; i < 4; i++)
        af[i] = *reinterpret_cast<const f16x4*>(&At[i * 16 + lrow][h * 16 + lb * 4]);
#pragma unroll
      for (int j = 0; j < 2; j++)
        bf[j] = *reinterpret_cast<const f16x4*>(&Bs[wc * 32 + j * 16 + lrow][h * 16 + lb * 4]);
#pragma unroll
      for (int i = 0; i < 4; i++)
#pragma unroll
        for (int j = 0; j < 2; j++)
          acc[i][j] = __builtin_amdgcn_mfma_f32_16x16x16f16(af[i], bf[j], acc[i][j], 0, 0, 0);
    }
    __syncthreads();
  }
#pragma unroll
  for (int i = 0; i < 4; i++) {
#pragma unroll
    for (int j = 0; j < 2; j++) {
      const int gcol = n0 + wc * 32 + j * 16 + lrow;
      if (gcol < Nv) {
        const float bv = bias[gcol];
#pragma unroll
        for (int r = 0; r < 4; r++) {
          const int grow = m0 + i * 16 + lb * 4 + r;
          float v = acc[i][j][r] + bv;
          if (OUT_H16) {
            v = fmaxf(v, 0.f);
            ((_Float16*)Cv)[(size_t)grow * ldc + gcol] = (_Float16)v;
          } else {
            ((float*)Cv)[(size_t)grow * ldc + gcol] = v;
          }
        }
      }
    }
  }
}

// ---------------- fused QP: init + 5 x (solve + update) + accum ----------------
// 512 threads: j = tid&255 (column), half = tid>>8 (K-split for solve).
// G read row-wise (symmetric) as float4; stencils via shuffles + wave halos.
__global__ __launch_bounds__(512, 2) void qp_all(
    const float* __restrict__ NO, const float* __restrict__ ss,
    const float* __restrict__ sinit,
    const float* __restrict__ p_smax, const float* __restrict__ p_smin,
    const float* __restrict__ p_sdmax, const float* __restrict__ p_sdmin,
    const float* __restrict__ p_sddmax, const float* __restrict__ p_sddmin,
    const float* __restrict__ G, const float* __restrict__ zc_,
    float* __restrict__ out, int B)
{
  __shared__ float vs[RPB][256];
  __shared__ float xpart[RPB][256];
  __shared__ float haloXR[4][RPB][2];   // x at lanes 0,1 of each jwave (right halo)
  __shared__ float haloXL[4][RPB][2];   // x at lanes 62,63 (left halo)
  __shared__ float haloPR[4][RPB][2];   // xp at lanes 0,1 (right halo)
  __shared__ float red[4][RPB][3];

  const int tid = threadIdx.x;
  const int j = tid & 255;
  const int half = tid >> 8;
  const int lane = tid & 63;
  const int jw = (tid >> 6) & 3;
  const int r0 = blockIdx.x * RPB;
  const bool h1 = j < 255, h2 = j < 254;
  const float smax = *p_smax, smin = *p_smin;
  const float sdmax = *p_sdmax, sdmin = *p_sdmin;
  const float sddmax = *p_sddmax, sddmin = *p_sddmin;
  const float K0 = smax + smin, K1 = sdmax + sdmin, K2 = sddmax + sddmin;
  const float invT = 20.f, invT2 = 400.f;

  const size_t primOff = (size_t)B * NUMV;
  const size_t fpOff = primOff + (size_t)QP_ITERS * B;
  const size_t accPOff = fpOff + (size_t)QP_ITERS * B;
  const size_t accFOff = accPOff + (size_t)B;

  float lam[RPB], ssv[RPB], beqr[RPB], xp[RPB];
  float zcj = 0.f, accP = 0.f, accF = 0.f;

  if (half == 0) {
    zcj = zc_[j];
#pragma unroll
    for (int r = 0; r < RPB; r++) {
      lam[r] = NO[(size_t)(r0 + r) * NO_LD + j];
      ssv[r] = ss[(size_t)(r0 + r) * NUMV + j];
      beqr[r] = sinit[r0 + r];
      xp[r] = 0.f;
    }
    // ---- init v0 = lam0 + ss + b_aug0 @ A_control (direct shifted loads) ----
#pragma unroll
    for (int r = 0; r < RPB; r++) {
      const float* no = NO + (size_t)(r0 + r) * NO_LD;
      const float D0 = K0 - fmaxf(0.f, no[256 + j]) + fmaxf(0.f, no[512 + j]);
      const float D1j = h1 ? (K1 - fmaxf(0.f, no[768 + j]) + fmaxf(0.f, no[1023 + j])) : 0.f;
      const float D1m = (j >= 1) ? (K1 - fmaxf(0.f, no[768 + j - 1]) + fmaxf(0.f, no[1023 + j - 1])) : 0.f;
      const float D2j = h2 ? (K2 - fmaxf(0.f, no[1278 + j]) + fmaxf(0.f, no[1532 + j])) : 0.f;
      const float D2m1 = (j >= 1 && h1) ? (K2 - fmaxf(0.f, no[1278 + j - 1]) + fmaxf(0.f, no[1532 + j - 1])) : 0.f;
      const float D2m2 = (j >= 2) ? (K2 - fmaxf(0.f, no[1278 + j - 2]) + fmaxf(0.f, no[1532 + j - 2])) : 0.f;
      vs[r][j] = lam[r] + ssv[r] + D0 + (D1m - D1j) * invT + (D2m2 - 2.f * D2m1 + D2j) * invT2;
    }
  }
  __syncthreads();

  // G row pointer for this column (G symmetric: G[k][j] == G[j][k])
  const float* Grow = G + (size_t)j * 256;

  for (int it = 0; it < QP_ITERS; ++it) {
    // ---- solve: x = G v + beq*zc, K-split across halves ----
    float acc[RPB];
    if (half == 0) {
#pragma unroll
      for (int r = 0; r < RPB; r++) acc[r] = beqr[r] * zcj;
    } else {
#pragma unroll
      for (int r = 0; r < RPB; r++) acc[r] = 0.f;
    }
    const int kb = half << 7;
#pragma unroll 2
    for (int k0 = 0; k0 < 128; k0 += 4) {
      const float4 g4 = *reinterpret_cast<const float4*>(&Grow[kb + k0]);
#pragma unroll
      for (int r = 0; r < RPB; r++) {
        const float4 v4 = *reinterpret_cast<const float4*>(&vs[r][kb + k0]);
        acc[r] = fmaf(v4.x, g4.x, acc[r]);
        acc[r] = fmaf(v4.y, g4.y, acc[r]);
        acc[r] = fmaf(v4.z, g4.z, acc[r]);
        acc[r] = fmaf(v4.w, g4.w, acc[r]);
      }
    }
    if (half == 1) {
#pragma unroll
      for (int r = 0; r < RPB; r++) xpart[r][j] = acc[r];
    }
    __syncthreads();    // S1: xpart ready

    if (half == 0) {
#pragma unroll
      for (int r = 0; r < RPB; r++) {
        acc[r] += xpart[r][j];
        if (lane < 2) {
          haloXR[jw][r][lane] = acc[r];
          haloPR[jw][r][lane] = xp[r];
        }
        if (lane >= 62) haloXL[jw][r][lane - 62] = acc[r];
      }
    }
    __syncthreads();    // S2: halos ready

    if (half == 0) {
#pragma unroll
      for (int r = 0; r < RPB; r++) {
        const float x0 = acc[r];
        // 5-point x window via shuffles + halos
        const float xu1 = __shfl_down(x0, 1), xu2 = __shfl_down(x0, 2);
        const float xd1 = __shfl_up(x0, 1), xd2 = __shfl_up(x0, 2);
        const float nR0 = (jw < 3) ? haloXR[jw + 1][r][0] : 0.f;
        const float nR1 = (jw < 3) ? haloXR[jw + 1][r][1] : 0.f;
        const float nL0 = (jw > 0) ? haloXL[jw - 1][r][0] : 0.f;  // prev lane 62
        const float nL1 = (jw > 0) ? haloXL[jw - 1][r][1] : 0.f;  // prev lane 63
        const float x1 = (lane == 63) ? nR0 : xu1;
        const float x2 = (lane == 62) ? nR0 : ((lane == 63) ? nR1 : xu2);
        const float xm1 = (lane == 0) ? nL1 : xd1;
        const float xm2 = (lane == 0) ? nL0 : ((lane == 1) ? nL1 : xd2);

        const float vj = (x1 - x0) * invT;
        const float aj = (x2 - 2.f * x1 + x0) * invT2;
        const float vm1 = (x0 - xm1) * invT;
        const float am1 = (x1 - 2.f * x0 + xm1) * invT2;
        const float am2 = (x0 - 2.f * xm1 + xm2) * invT2;

        // residual + E at j
        const float rv0a = fmaxf(0.f, x0 - smax), rv0b = fmaxf(0.f, smin - x0);
        const float E0 = rv0a - rv0b;
        float rv1a = 0.f, rv1b = 0.f, rv2a = 0.f, rv2b = 0.f, E1 = 0.f, E2 = 0.f;
        if (h1) { rv1a = fmaxf(0.f, vj - sdmax); rv1b = fmaxf(0.f, sdmin - vj); E1 = rv1a - rv1b; }
        if (h2) { rv2a = fmaxf(0.f, aj - sddmax); rv2b = fmaxf(0.f, sddmin - aj); E2 = rv2a - rv2b; }
        float res2 = rv0a * rv0a + rv0b * rv0b + rv1a * rv1a + rv1b * rv1b
                   + rv2a * rv2a + rv2b * rv2b;

        // E neighbors (recomputed locally)
        const float E1m = (j >= 1) ? (fmaxf(0.f, vm1 - sdmax) - fmaxf(0.f, sdmin - vm1)) : 0.f;
        const float E2m1 = (j >= 1 && h1) ? (fmaxf(0.f, am1 - sddmax) - fmaxf(0.f, sddmin - am1)) : 0.f;
        const float E2m2 = (j >= 2) ? (fmaxf(0.f, am2 - sddmax) - fmaxf(0.f, sddmin - am2)) : 0.f;

        const float dl = E0 + (E1m - E1) * invT + (E2m2 - 2.f * E2m1 + E2) * invT2;
        const float lnew = lam[r] - dl;
        const float fpl2 = dl * dl;

        // s_new at j
        const float sn0a = fmaxf(0.f, smax - x0), sn0b = fmaxf(0.f, x0 - smin);
        float sn1a = 0.f, sn1b = 0.f, sn2a = 0.f, sn2b = 0.f;
        if (h1) { sn1a = fmaxf(0.f, sdmax - vj); sn1b = fmaxf(0.f, vj - sdmin); }
        if (h2) { sn2a = fmaxf(0.f, sddmax - aj); sn2b = fmaxf(0.f, aj - sddmin); }

        // s_prev at j
        float sp0a, sp0b, sp1a = 0.f, sp1b = 0.f, sp2a = 0.f, sp2b = 0.f;
        if (it == 0) {
          const float* no = NO + (size_t)(r0 + r) * NO_LD;
          sp0a = fmaxf(0.f, no[256 + j]); sp0b = fmaxf(0.f, no[512 + j]);
          if (h1) { sp1a = fmaxf(0.f, no[768 + j]); sp1b = fmaxf(0.f, no[1023 + j]); }
          if (h2) { sp2a = fmaxf(0.f, no[1278 + j]); sp2b = fmaxf(0.f, no[1532 + j]); }
        } else {
          const float p0 = xp[r];
          const float pu1 = __shfl_down(p0, 1), pu2 = __shfl_down(p0, 2);
          const float pR0 = (jw < 3) ? haloPR[jw + 1][r][0] : 0.f;
          const float pR1 = (jw < 3) ? haloPR[jw + 1][r][1] : 0.f;
          const float p1 = (lane == 63) ? pR0 : pu1;
          const float p2 = (lane == 62) ? pR0 : ((lane == 63) ? pR1 : pu2);
          const float vp = (p1 - p0) * invT;
          const float ap = (p2 - 2.f * p1 + p0) * invT2;
          sp0a = fmaxf(0.f, smax - p0); sp0b = fmaxf(0.f, p0 - smin);
          if (h1) { sp1a = fmaxf(0.f, sdmax - vp); sp1b = fmaxf(0.f, vp - sdmin); }
          if (h2) { sp2a = fmaxf(0.f, sddmax - ap); sp2b = fmaxf(0.f, ap - sddmin); }
        }
        const float d0a = sp0a - sn0a, d0b = sp0b - sn0b;
        const float d1a = sp1a - sn1a, d1b = sp1b - sn1b;
        const float d2a = sp2a - sn2a, d2b = sp2b - sn2b;
        float fps2 = d0a * d0a + d0b * d0b + d1a * d1a + d1b * d1b
                   + d2a * d2a + d2b * d2b;

        // D terms and next v
        const float D0 = fminf(smax, x0) + fmaxf(smin, x0);
        const float D1 = h1 ? (fminf(sdmax, vj) + fmaxf(sdmin, vj)) : 0.f;
        const float D2 = h2 ? (fminf(sddmax, aj) + fmaxf(sddmin, aj)) : 0.f;
        const float D1m = (j >= 1) ? (fminf(sdmax, vm1) + fmaxf(sdmin, vm1)) : 0.f;
        const float D2m1 = (j >= 1 && h1) ? (fminf(sddmax, am1) + fmaxf(sddmin, am1)) : 0.f;
        const float D2m2 = (j >= 2) ? (fminf(sddmax, am2) + fmaxf(sddmin, am2)) : 0.f;

        vs[r][j] = lnew + ssv[r] + D0 + (D1m - D1) * invT + (D2m2 - 2.f * D2m1 + D2) * invT2;
        lam[r] = lnew;
        xp[r] = x0;
        if (it == QP_ITERS - 1) out[(size_t)(r0 + r) * NUMV + j] = x0;

        // per-row wave reduction, then cross-wave via red
        float a = res2, b = fps2, c = fpl2;
        for (int o = 32; o > 0; o >>= 1) {
          a += __shfl_down(a, o);
          b += __shfl_down(b, o);
          c += __shfl_down(c, o);
        }
        if (lane == 0) { red[jw][r][0] = a; red[jw][r][1] = b; red[jw][r][2] = c; }
      }
    }
    __syncthreads();    // S3: red + vs ready

    if (tid < RPB) {
      const float r2 = red[0][tid][0] + red[1][tid][0] + red[2][tid][0] + red[3][tid][0];
      const float s2 = red[0][tid][1] + red[1][tid][1] + red[2][tid][1] + red[3][tid][1];
      const float l2 = red[0][tid][2] + red[1][tid][2] + red[2][tid][2] + red[3][tid][2];
      const float pr = sqrtf(r2);
      const float fp = sqrtf(s2) + sqrtf(l2);
      out[primOff + (size_t)it * B + r0 + tid] = pr;
      out[fpOff + (size_t)it * B + r0 + tid] = fp;
      accP += pr; accF += fp;
    }
  }
  if (tid < RPB) {
    out[accPOff + r0 + tid] = accP * (1.f / QP_ITERS);
    out[accFOff + r0 + tid] = accF * (1.f / QP_ITERS);
  }
}

extern "C" void kernel_launch(void* const* d_in, const int* in_sizes, int n_in,
                              void* d_out, int out_size, void* d_ws, size_t ws_size,
                              hipStream_t stream)
{
  const float* inp = (const float*)d_in[0];       // [B][260]
  const float* sinit = (const float*)d_in[1];     // [B][1]
  const float* ssamp = (const float*)d_in[2];     // [B][256]
  const float* p_smax = (const float*)d_in[3];
  const float* p_smin = (const float*)d_in[4];
  const float* p_sdmax = (const float*)d_in[5];
  const float* p_sdmin = (const float*)d_in[6];
  const float* p_sddmax = (const float*)d_in[7];
  const float* p_sddmin = (const float*)d_in[8];
  const float* W1 = (const float*)d_in[11];       // [260][1024]
  const float* b1 = (const float*)d_in[12];       // [1024]
  const float* W2 = (const float*)d_in[13];       // [1024][1786]
  const float* b2 = (const float*)d_in[14];       // [1786]
  float* out = (float*)d_out;

  const int B = in_sizes[1];                      // 4096
  const int IND = in_sizes[9];                    // 260
  const int H = in_sizes[12];                     // 1024
  const int OUTN = in_sizes[14];                  // 1786

  char* ws = (char*)d_ws;
  float* NO = (float*)ws;                                      // [B][1792] fp32
  char* p = ws + (size_t)B * NO_LD * 4;                        // 29,360,128
  _Float16* hH = (_Float16*)p;                                 // [B][1024] fp16
  char* q = p + (size_t)B * H * 2;                             // 37,748,736
  _Float16* W2T = (_Float16*)q;                                // [1786][1024] fp16
  char* q2 = q + (size_t)OUTN * H * 2;                         // 41,406,464
  _Float16* W1T = (_Float16*)q2;                               // [1024][260] fp16
  char* r2 = q2 + (size_t)H * IND * 2 + 1024;                  // aligned region
  float* G = (float*)r2;                                       // [256][256] fp32
  float* zc = (float*)(r2 + 262144);                           // [256]

  build_g<<<8, 32, 0, stream>>>(G, zc);
  {
    dim3 g((IND + 31) / 32, (H + 31) / 32), blk(32, 8);
    transpose_cvt<<<g, blk, 0, stream>>>(W1, W1T, IND, H);
  }
  {
    dim3 g((H + 31) / 32, (OUTN + 31) / 32), blk(32, 8);
    transpose_cvt<<<g, blk, 0, stream>>>(W2, W2T, H, OUTN);
  }
  {
    dim3 g(B / 64, H / 128);
    mfma_gemm<true, true><<<g, 256, 0, stream>>>(inp, W1T, b1, hH, B, H, IND, IND, IND, H);
  }
  {
    dim3 g(B / 64, (OUTN + 127) / 128);
    mfma_gemm<false, false><<<g, 256, 0, stream>>>(hH, W2T, b2, NO, B, OUTN, H, H, H, NO_LD);
  }
  qp_all<<<B / RPB, 512, 0, stream>>>(NO, ssamp, sinit,
                                      p_smax, p_smin, p_sdmax, p_sdmin,
                                      p_sddmax, p_sddmin, G, zc, out, B);
}

// Round 11
// 304.528 us; speedup vs baseline: 1.0158x; 1.0158x over previous
//
#include <hip/hip_runtime.h>
#include <cstddef>

// learned_qp_solver: B=4096, NUM=256, NC=1530, IND=260, H=1024, OUT=1786, 5 iters.
//
//   KKT solve closed form:  x = G v + (b_eq/z0) z,  G = C^{-1} - z z^T / z0 (symmetric)
//   MLP on matrix cores (fp16 in / fp32 accum, v_mfma_f32_16x16x16_f16).
//   Solve on MFMA with SCALED split-fp16 (round-10 lesson: G's residual plane
//   Gl = G - fp16(G) ~ 3e-5 is DENORMAL in fp16 and MFMA flushes it -> G collapsed
//   to plain-fp16 precision -> 2063 absmax). Fix: store Gl*2048 and Vl*2048
//   (normal range), accumulate corrections in a separate fp32 accumulator,
//   x = accH + accL/2048 + beq*zc. True fp32-equivalent precision.
//
// ws layout (bytes), 46.4 MB; X/V/lam aliased onto dead hH/W2T/W1T regions:
//   [0,          29360128)  NO   fp32 [B][1792]
//   [29360128,   37748736)  hH   fp16 [B][1024]  -> after GEMM2: Xa, Xb (fp32 [B][256])
//   [37748736,   41406464)  W2T  fp16 [1786][1024] -> after GEMM2: Vh, Vl (fp16 [B][256])
//   [41406464,   41938944)  W1T  fp16 [1024][260]  (Vl tail overlaps; dead by then)
//   [41943040,   46137344)  lam  fp32 [B][256]
//   [46137344,   46268416)  Gh   fp16 [256][256]
//   [46268416,   46399488)  Gl   fp16 [256][256]  (scaled x2048)
//   [46399488,   46400512)  zc   fp32 [256]

#define NUMV 256
#define QP_ITERS 5
#define NO_LD 1792
#define LSCALE 2048.0f
#define INV_LSCALE (1.0f / 2048.0f)

typedef _Float16 f16x4 __attribute__((ext_vector_type(4)));
typedef float f32x4 __attribute__((ext_vector_type(4)));

// ---------------- compile-time pentadiagonal Cholesky tables ----------------
struct FacT {
  double invd[256];
  double l1[257];
  double l2[258];
  double z[256];
  float  zcf[256];
};

constexpr double csqrt_(double x) {
  double g = (x > 1.0) ? x : 1.0;
  for (int i = 0; i < 64; ++i) g = 0.5 * (g + x / g);
  return g;
}

constexpr FacT make_fac() {
  FacT f{};
  const double T = 0.05, a = 1.0 / (T * T), b2 = a * a;
  double c0[256] = {}, c1[255] = {}, c2[254] = {};
  double dd[256] = {}, l1[256] = {}, l2[256] = {};
  for (int j = 0; j < 256; j++) {
    double cd1 = (j == 0 || j == 255) ? 1.0 : 2.0;
    double cd2 = (j == 0 || j == 255) ? 1.0 : ((j == 1 || j == 254) ? 5.0 : 6.0);
    c0[j] = 3.0 + 2.0 * a * cd1 + 2.0 * b2 * cd2;
  }
  for (int j = 0; j < 255; j++) c1[j] = -2.0 * a + 2.0 * b2 * ((j == 0 || j == 254) ? -2.0 : -4.0);
  for (int j = 0; j < 254; j++) c2[j] = 2.0 * b2;
  dd[0] = csqrt_(c0[0]); l1[0] = 0.0; l2[0] = 0.0;
  l1[1] = c1[0] / dd[0]; l2[1] = 0.0;
  dd[1] = csqrt_(c0[1] - l1[1] * l1[1]);
  for (int j = 2; j < 256; j++) {
    l2[j] = c2[j - 2] / dd[j - 2];
    l1[j] = (c1[j - 1] - l2[j] * l1[j - 1]) / dd[j - 1];
    dd[j] = csqrt_(c0[j] - l1[j] * l1[j] - l2[j] * l2[j]);
  }
  for (int j = 0; j < 256; j++) f.invd[j] = 1.0 / dd[j];
  for (int j = 0; j < 256; j++) f.l1[j] = l1[j];
  f.l1[256] = 0.0;
  for (int j = 0; j < 256; j++) f.l2[j] = l2[j];
  f.l2[256] = 0.0; f.l2[257] = 0.0;
  double w[256] = {}, zz[256] = {};
  w[0] = 1.0 / dd[0];
  w[1] = (-l1[1] * w[0]) / dd[1];
  for (int j = 2; j < 256; j++) w[j] = (-l1[j] * w[j - 1] - l2[j] * w[j - 2]) / dd[j];
  zz[255] = w[255] / dd[255];
  zz[254] = (w[254] - l1[255] * zz[255]) / dd[254];
  for (int j = 253; j >= 0; j--)
    zz[j] = (w[j] - l1[j + 1] * zz[j + 1] - l2[j + 2] * zz[j + 2]) / dd[j];
  for (int j = 0; j < 256; j++) f.z[j] = zz[j];
  for (int j = 0; j < 256; j++) f.zcf[j] = (float)(zz[j] / zz[0]);
  return f;
}

constexpr FacT FAC_HOST = make_fac();
__constant__ FacT FAC = FAC_HOST;

// ---- build Gh/Gl = scaled split-fp16 of (C^{-1} - z z^T/z0); 8 blocks x 32 cols ----
__global__ __launch_bounds__(32) void build_g(
    _Float16* __restrict__ Gh, _Float16* __restrict__ Gl, float* __restrict__ zc)
{
  __shared__ double w[256][32];
  const int t = threadIdx.x;
  const int c = blockIdx.x * 32 + t;
  double w1 = 0.0, w2 = 0.0;
#pragma unroll 4
  for (int j = 0; j < 256; j++) {
    double rhs = (j == c) ? 1.0 : 0.0;
    double wj = (rhs - FAC.l1[j] * w1 - FAC.l2[j] * w2) * FAC.invd[j];
    w[j][t] = wj;
    w2 = w1; w1 = wj;
  }
  const double zr = FAC.z[c] / FAC.z[0];
  double y1 = 0.0, y2 = 0.0;
#pragma unroll 4
  for (int j = 255; j >= 0; j--) {
    double yj = (w[j][t] - FAC.l1[j + 1] * y1 - FAC.l2[j + 2] * y2) * FAC.invd[j];
    const float g = (float)(yj - FAC.z[j] * zr);
    const _Float16 gh = (_Float16)g;
    Gh[(size_t)j * 256 + c] = gh;               // symmetric: [j][c] == [c][j]
    Gl[(size_t)j * 256 + c] = (_Float16)((g - (float)gh) * LSCALE);  // normal range
    y2 = y1; y1 = yj;
  }
  zc[c] = FAC.zcf[c];
}

// ---------------- transpose + fp32->fp16 convert: in [K][N] -> out [N][K] ----------------
__global__ __launch_bounds__(256) void transpose_cvt(
    const float* __restrict__ in, _Float16* __restrict__ out, int K, int N)
{
  __shared__ float t[32][33];
  const int bk = blockIdx.x * 32, bn = blockIdx.y * 32;
  const int x = threadIdx.x, y = threadIdx.y;
  for (int yy = y; yy < 32; yy += 8) {
    const int k = bk + yy, n = bn + x;
    t[yy][x] = (k < K && n < N) ? in[(size_t)k * N + n] : 0.f;
  }
  __syncthreads();
  for (int yy = y; yy < 32; yy += 8) {
    const int n = bn + yy, k = bk + x;
    if (n < N && k < K) out[(size_t)n * K + k] = (_Float16)t[x][yy];
  }
}

// ---------------- MFMA GEMM: C = A * Bt^T + bias, tile 64x128, 4 waves ----------------
template<bool A_FP32, bool OUT_H16>
__global__ __launch_bounds__(256) void mfma_gemm(
    const void* __restrict__ Av, const _Float16* __restrict__ Bt,
    const float* __restrict__ bias, void* __restrict__ Cv,
    int M, int Nv, int K, int lda, int ldk, int ldc)
{
  __shared__ _Float16 At[64][36];
  __shared__ _Float16 Bs[128][36];
  const int tid = threadIdx.x;
  const int lane = tid & 63, wid = tid >> 6;
  const int wc = wid;
  const int lrow = lane & 15, lb = lane >> 4;
  const int m0 = blockIdx.x * 64, n0 = blockIdx.y * 128;
  const int arow = tid >> 2, akq = tid & 3;
  const int brow = tid >> 1, bkh = tid & 1;

  f32x4 acc[4][2];
#pragma unroll
  for (int i = 0; i < 4; i++)
#pragma unroll
    for (int j = 0; j < 2; j++) acc[i][j] = (f32x4)0.0f;

  const int nsteps = (K + 31) / 32;
  for (int t = 0; t < nsteps; ++t) {
    const int k0 = t * 32;
    if (A_FP32) {
      const float* A = (const float*)Av;
#pragma unroll
      for (int i = 0; i < 2; i++) {
        const int k = k0 + akq * 8 + i * 4;
        f16x4 hv = {};
        if (k + 4 <= K) {
          const float4 v = *reinterpret_cast<const float4*>(&A[(size_t)(m0 + arow) * lda + k]);
          hv[0] = (_Float16)v.x; hv[1] = (_Float16)v.y;
          hv[2] = (_Float16)v.z; hv[3] = (_Float16)v.w;
        }
        *reinterpret_cast<f16x4*>(&At[arow][akq * 8 + i * 4]) = hv;
      }
    } else {
      const _Float16* A = (const _Float16*)Av;
#pragma unroll
      for (int i = 0; i < 2; i++) {
        const int k = k0 + akq * 8 + i * 4;
        f16x4 hv = {};
        if (k + 4 <= K) hv = *reinterpret_cast<const f16x4*>(&A[(size_t)(m0 + arow) * lda + k]);
        *reinterpret_cast<f16x4*>(&At[arow][akq * 8 + i * 4]) = hv;
      }
    }
    {
      const int n = n0 + brow;
#pragma unroll
      for (int i = 0; i < 4; i++) {
        const int k = k0 + bkh * 16 + i * 4;
        f16x4 hv = {};
        if (n < Nv && k + 4 <= K)
          hv = *reinterpret_cast<const f16x4*>(&Bt[(size_t)n * ldk + k]);
        *reinterpret_cast<f16x4*>(&Bs[brow][bkh * 16 + i * 4]) = hv;
      }
    }
    __syncthreads();
#pragma unroll
    for (int h = 0; h < 2; h++) {
      f16x4 af[4], bf[2];
#pragma unroll
      for (int i = 0; i < 4; i++)
        af[i] = *reinterpret_cast<const f16x4*>(&At[i * 16 + lrow][h * 16 + lb * 4]);
#pragma unroll
      for (int j = 0; j < 2; j++)
        bf[j] = *reinterpret_cast<const f16x4*>(&Bs[wc * 32 + j * 16 + lrow][h * 16 + lb * 4]);
#pragma unroll
      for (int i = 0; i < 4; i++)
#pragma unroll
        for (int j = 0; j < 2; j++)
          acc[i][j] = __builtin_amdgcn_mfma_f32_16x16x16f16(af[i], bf[j], acc[i][j], 0, 0, 0);
    }
    __syncthreads();
  }
#pragma unroll
  for (int i = 0; i < 4; i++) {
#pragma unroll
    for (int j = 0; j < 2; j++) {
      const int gcol = n0 + wc * 32 + j * 16 + lrow;
      if (gcol < Nv) {
        const float bv = bias[gcol];
#pragma unroll
        for (int r = 0; r < 4; r++) {
          const int grow = m0 + i * 16 + lb * 4 + r;
          float v = acc[i][j][r] + bv;
          if (OUT_H16) {
            v = fmaxf(v, 0.f);
            ((_Float16*)Cv)[(size_t)grow * ldc + gcol] = (_Float16)v;
          } else {
            ((float*)Cv)[(size_t)grow * ldc + gcol] = v;
          }
        }
      }
    }
  }
}

// ---- solve via scaled split-fp16 MFMA ----
// accH = Vh*Gh ; accL = Vh*Gl' + Vl'*Gh  (Gl',Vl' scaled x2048)
// X = accH + accL/2048 + beq x zc ; tile 64x128, 4 waves.
__global__ __launch_bounds__(256) void solve_mfma(
    const _Float16* __restrict__ Vh, const _Float16* __restrict__ Vl,
    const _Float16* __restrict__ Gh, const _Float16* __restrict__ Gl,
    const float* __restrict__ beq, const float* __restrict__ zc,
    float* __restrict__ X, int B)
{
  __shared__ _Float16 Ah[64][40], Al[64][40];
  __shared__ _Float16 Bh[128][40], Bl[128][40];
  const int tid = threadIdx.x;
  const int lane = tid & 63, wc = tid >> 6;
  const int lrow = lane & 15, lb = lane >> 4;
  const int m0 = blockIdx.x * 64, n0 = blockIdx.y * 128;
  const int arow = tid >> 2, ak = (tid & 3) * 8;
  const int brow = tid >> 1, bk = (tid & 1) * 16;

  f32x4 accH[4][2], accL[4][2];
#pragma unroll
  for (int i = 0; i < 4; i++)
#pragma unroll
    for (int j = 0; j < 2; j++) { accH[i][j] = (f32x4)0.0f; accL[i][j] = (f32x4)0.0f; }

#pragma unroll 1
  for (int t = 0; t < 8; ++t) {
    const int k0 = t * 32;
    // stage A (Vh, Vl'): 64 rows x 32 k
    *reinterpret_cast<f16x4*>(&Ah[arow][ak]) =
        *reinterpret_cast<const f16x4*>(&Vh[(size_t)(m0 + arow) * 256 + k0 + ak]);
    *reinterpret_cast<f16x4*>(&Ah[arow][ak + 4]) =
        *reinterpret_cast<const f16x4*>(&Vh[(size_t)(m0 + arow) * 256 + k0 + ak + 4]);
    *reinterpret_cast<f16x4*>(&Al[arow][ak]) =
        *reinterpret_cast<const f16x4*>(&Vl[(size_t)(m0 + arow) * 256 + k0 + ak]);
    *reinterpret_cast<f16x4*>(&Al[arow][ak + 4]) =
        *reinterpret_cast<const f16x4*>(&Vl[(size_t)(m0 + arow) * 256 + k0 + ak + 4]);
    // stage B (Gh, Gl'): 128 cols x 32 k (G symmetric -> row-read is col-read)
#pragma unroll
    for (int i = 0; i < 4; i++) {
      *reinterpret_cast<f16x4*>(&Bh[brow][bk + i * 4]) =
          *reinterpret_cast<const f16x4*>(&Gh[(size_t)(n0 + brow) * 256 + k0 + bk + i * 4]);
      *reinterpret_cast<f16x4*>(&Bl[brow][bk + i * 4]) =
          *reinterpret_cast<const f16x4*>(&Gl[(size_t)(n0 + brow) * 256 + k0 + bk + i * 4]);
    }
    __syncthreads();
#pragma unroll
    for (int h = 0; h < 2; h++) {
      f16x4 ah[4], al[4], bh[2], bl[2];
#pragma unroll
      for (int i = 0; i < 4; i++) {
        ah[i] = *reinterpret_cast<const f16x4*>(&Ah[i * 16 + lrow][h * 16 + lb * 4]);
        al[i] = *reinterpret_cast<const f16x4*>(&Al[i * 16 + lrow][h * 16 + lb * 4]);
      }
#pragma unroll
      for (int j = 0; j < 2; j++) {
        bh[j] = *reinterpret_cast<const f16x4*>(&Bh[wc * 32 + j * 16 + lrow][h * 16 + lb * 4]);
        bl[j] = *reinterpret_cast<const f16x4*>(&Bl[wc * 32 + j * 16 + lrow][h * 16 + lb * 4]);
      }
#pragma unroll
      for (int i = 0; i < 4; i++)
#pragma unroll
        for (int j = 0; j < 2; j++) {
          accH[i][j] = __builtin_amdgcn_mfma_f32_16x16x16f16(ah[i], bh[j], accH[i][j], 0, 0, 0);
          accL[i][j] = __builtin_amdgcn_mfma_f32_16x16x16f16(ah[i], bl[j], accL[i][j], 0, 0, 0);
          accL[i][j] = __builtin_amdgcn_mfma_f32_16x16x16f16(al[i], bh[j], accL[i][j], 0, 0, 0);
        }
    }
    __syncthreads();
  }
  // epilogue: D col = lane&15, row = 4*(lane>>4)+reg
#pragma unroll
  for (int i = 0; i < 4; i++) {
#pragma unroll
    for (int j = 0; j < 2; j++) {
      const int gcol = n0 + wc * 32 + j * 16 + lrow;
      const float zv = zc[gcol];
#pragma unroll
      for (int r = 0; r < 4; r++) {
        const int grow = m0 + i * 16 + lb * 4 + r;
        X[(size_t)grow * 256 + gcol] =
            accH[i][j][r] + accL[i][j][r] * INV_LSCALE + beq[grow] * zv;
      }
    }
  }
}

// ---------------- initial rhs V0 = lam0 + ss + b_aug0 @ A_control (scaled split) ----
__global__ __launch_bounds__(256) void init_v(
    const float* __restrict__ NO, const float* __restrict__ ss,
    const float* __restrict__ p_smax, const float* __restrict__ p_smin,
    const float* __restrict__ p_sdmax, const float* __restrict__ p_sdmin,
    const float* __restrict__ p_sddmax, const float* __restrict__ p_sddmin,
    _Float16* __restrict__ Vh, _Float16* __restrict__ Vl, int B)
{
  __shared__ float d1s[258], d2s[258];
  const int r = blockIdx.x, j = threadIdx.x;
  const float K0 = *p_smax + *p_smin, K1 = *p_sdmax + *p_sdmin, K2 = *p_sddmax + *p_sddmin;
  const float invT = 20.f, invT2 = 400.f;
  const float* no = NO + (size_t)r * NO_LD;
  float s1 = fmaxf(0.f, no[256 + j]), s2 = fmaxf(0.f, no[512 + j]);
  float D0 = K0 - s1 + s2;
  float D1 = 0.f, D2 = 0.f;
  if (j < 255) D1 = K1 - fmaxf(0.f, no[768 + j]) + fmaxf(0.f, no[1023 + j]);
  if (j < 254) D2 = K2 - fmaxf(0.f, no[1278 + j]) + fmaxf(0.f, no[1532 + j]);
  d1s[2 + j] = D1; d2s[2 + j] = D2;
  if (j < 2) { d1s[j] = 0.f; d2s[j] = 0.f; }
  __syncthreads();
  float qn = D0 + (d1s[j + 1] - d1s[j + 2]) * invT
                + (d2s[j] - 2.f * d2s[j + 1] + d2s[j + 2]) * invT2;
  const float vn = no[j] + ss[(size_t)r * NUMV + j] + qn;
  const _Float16 vh = (_Float16)vn;
  Vh[(size_t)r * NUMV + j] = vh;
  Vl[(size_t)r * NUMV + j] = (_Float16)((vn - (float)vh) * LSCALE);
}

// ---------------- per-iteration update: one block per row (round-5 validated) ----
__global__ __launch_bounds__(256) void qp_update(
    const float* __restrict__ X, const float* __restrict__ Xp,
    const float* __restrict__ NO, float* lam,
    const float* __restrict__ ss,
    const float* __restrict__ p_smax, const float* __restrict__ p_smin,
    const float* __restrict__ p_sdmax, const float* __restrict__ p_sdmin,
    const float* __restrict__ p_sddmax, const float* __restrict__ p_sddmin,
    _Float16* __restrict__ Vh, _Float16* __restrict__ Vl,
    float* __restrict__ out, int B, int it)
{
  __shared__ float xs[258], xps[258];
  __shared__ float e1s[258], e2s[258], d1s[258], d2s[258];
  __shared__ double red[3][4];
  const int r = blockIdx.x, j = threadIdx.x;
  const float smax = *p_smax, smin = *p_smin;
  const float sdmax = *p_sdmax, sdmin = *p_sdmin;
  const float sddmax = *p_sddmax, sddmin = *p_sddmin;
  const float invT = 20.f, invT2 = 400.f;

  const float x0 = X[(size_t)r * NUMV + j];
  xs[j] = x0;
  if (j < 2) xs[256 + j] = 0.f;
  float xp0 = 0.f;
  if (it > 0) {
    xp0 = Xp[(size_t)r * NUMV + j];
    xps[j] = xp0;
    if (j < 2) xps[256 + j] = 0.f;
  }
  __syncthreads();

  const bool h1 = j < 255, h2 = j < 254;
  const float x1 = xs[j + 1], x2 = xs[j + 2];
  const float v = (x1 - x0) * invT;
  const float aa = (x2 - 2.f * x1 + x0) * invT2;

  float rv0a = fmaxf(0.f, x0 - smax), rv0b = fmaxf(0.f, smin - x0);
  float rv1a = 0.f, rv1b = 0.f, rv2a = 0.f, rv2b = 0.f;
  float E1 = 0.f, E2 = 0.f;
  const float E0 = rv0a - rv0b;
  if (h1) { rv1a = fmaxf(0.f, v - sdmax); rv1b = fmaxf(0.f, sdmin - v); E1 = rv1a - rv1b; }
  if (h2) { rv2a = fmaxf(0.f, aa - sddmax); rv2b = fmaxf(0.f, sddmin - aa); E2 = rv2a - rv2b; }
  double res2 = (double)(rv0a * rv0a + rv0b * rv0b + rv1a * rv1a + rv1b * rv1b
                       + rv2a * rv2a + rv2b * rv2b);

  const float sn0a = fmaxf(0.f, smax - x0), sn0b = fmaxf(0.f, x0 - smin);
  float sn1a = 0.f, sn1b = 0.f, sn2a = 0.f, sn2b = 0.f;
  if (h1) { sn1a = fmaxf(0.f, sdmax - v); sn1b = fmaxf(0.f, v - sdmin); }
  if (h2) { sn2a = fmaxf(0.f, sddmax - aa); sn2b = fmaxf(0.f, aa - sddmin); }

  const float D0n = fminf(smax, x0) + fmaxf(smin, x0);
  const float D1n = h1 ? (fminf(sdmax, v) + fmaxf(sdmin, v)) : 0.f;
  const float D2n = h2 ? (fminf(sddmax, aa) + fmaxf(sddmin, aa)) : 0.f;

  float sp0a, sp0b, sp1a = 0.f, sp1b = 0.f, sp2a = 0.f, sp2b = 0.f;
  if (it == 0) {
    const float* no = NO + (size_t)r * NO_LD;
    sp0a = fmaxf(0.f, no[256 + j]); sp0b = fmaxf(0.f, no[512 + j]);
    if (h1) { sp1a = fmaxf(0.f, no[768 + j]); sp1b = fmaxf(0.f, no[1023 + j]); }
    if (h2) { sp2a = fmaxf(0.f, no[1278 + j]); sp2b = fmaxf(0.f, no[1532 + j]); }
  } else {
    const float xp1 = xps[j + 1], xp2 = xps[j + 2];
    const float vp = (xp1 - xp0) * invT;
    const float ap = (xp2 - 2.f * xp1 + xp0) * invT2;
    sp0a = fmaxf(0.f, smax - xp0); sp0b = fmaxf(0.f, xp0 - smin);
    if (h1) { sp1a = fmaxf(0.f, sdmax - vp); sp1b = fmaxf(0.f, vp - sdmin); }
    if (h2) { sp2a = fmaxf(0.f, sddmax - ap); sp2b = fmaxf(0.f, ap - sddmin); }
  }
  const float d0a = sp0a - sn0a, d0b = sp0b - sn0b;
  const float d1a = sp1a - sn1a, d1b = sp1b - sn1b;
  const float d2a = sp2a - sn2a, d2b = sp2b - sn2b;
  double fps2 = (double)(d0a * d0a + d0b * d0b + d1a * d1a + d1b * d1b
                       + d2a * d2a + d2b * d2b);

  e1s[2 + j] = E1; e2s[2 + j] = E2; d1s[2 + j] = D1n; d2s[2 + j] = D2n;
  if (j < 2) { e1s[j] = 0.f; e2s[j] = 0.f; d1s[j] = 0.f; d2s[j] = 0.f; }
  __syncthreads();

  const float lamj = (it == 0) ? NO[(size_t)r * NO_LD + j] : lam[(size_t)r * NUMV + j];
  const float lnew = lamj - (E0 + (e1s[j + 1] - e1s[j + 2]) * invT
                                + (e2s[j] - 2.f * e2s[j + 1] + e2s[j + 2]) * invT2);
  const float dl = lamj - lnew;
  double fpl2 = (double)(dl * dl);
  lam[(size_t)r * NUMV + j] = lnew;

  const size_t primOff = (size_t)B * NUMV;
  const size_t fpOff = primOff + (size_t)QP_ITERS * B;
  if (it < QP_ITERS - 1) {
    float qn = D0n + (d1s[j + 1] - d1s[j + 2]) * invT
                   + (d2s[j] - 2.f * d2s[j + 1] + d2s[j + 2]) * invT2;
    const float vn = lnew + ss[(size_t)r * NUMV + j] + qn;
    const _Float16 vh = (_Float16)vn;
    Vh[(size_t)r * NUMV + j] = vh;
    Vl[(size_t)r * NUMV + j] = (_Float16)((vn - (float)vh) * LSCALE);
  } else {
    out[(size_t)r * NUMV + j] = x0;
  }

  for (int o = 32; o > 0; o >>= 1) {
    res2 += __shfl_down(res2, o);
    fps2 += __shfl_down(fps2, o);
    fpl2 += __shfl_down(fpl2, o);
  }
  const int wid = j >> 6, lane = j & 63;
  if (lane == 0) { red[0][wid] = res2; red[1][wid] = fps2; red[2][wid] = fpl2; }
  __syncthreads();
  if (j == 0) {
    double r2 = red[0][0] + red[0][1] + red[0][2] + red[0][3];
    double s2_ = red[1][0] + red[1][1] + red[1][2] + red[1][3];
    double l2_ = red[2][0] + red[2][1] + red[2][2] + red[2][3];
    out[primOff + (size_t)it * B + r] = sqrtf((float)r2);
    out[fpOff + (size_t)it * B + r] = sqrtf((float)s2_) + sqrtf((float)l2_);
  }
}

// ---------------- final acc_primal / acc_fixed ----------------
__global__ __launch_bounds__(256) void accum_out(float* __restrict__ out, int B)
{
  const int r = blockIdx.x * 256 + threadIdx.x;
  const size_t primOff = (size_t)B * NUMV;
  const size_t fpOff = primOff + (size_t)QP_ITERS * B;
  const size_t accPOff = fpOff + (size_t)QP_ITERS * B;
  const size_t accFOff = accPOff + (size_t)B;
  float sp = 0.f, sf = 0.f;
  for (int it = 0; it < QP_ITERS; it++) {
    sp += out[primOff + (size_t)it * B + r];
    sf += out[fpOff + (size_t)it * B + r];
  }
  out[accPOff + r] = sp * (1.f / QP_ITERS);
  out[accFOff + r] = sf * (1.f / QP_ITERS);
}

extern "C" void kernel_launch(void* const* d_in, const int* in_sizes, int n_in,
                              void* d_out, int out_size, void* d_ws, size_t ws_size,
                              hipStream_t stream)
{
  const float* inp = (const float*)d_in[0];       // [B][260]
  const float* sinit = (const float*)d_in[1];     // [B][1]
  const float* ssamp = (const float*)d_in[2];     // [B][256]
  const float* p_smax = (const float*)d_in[3];
  const float* p_smin = (const float*)d_in[4];
  const float* p_sdmax = (const float*)d_in[5];
  const float* p_sdmin = (const float*)d_in[6];
  const float* p_sddmax = (const float*)d_in[7];
  const float* p_sddmin = (const float*)d_in[8];
  const float* W1 = (const float*)d_in[11];       // [260][1024]
  const float* b1 = (const float*)d_in[12];       // [1024]
  const float* W2 = (const float*)d_in[13];       // [1024][1786]
  const float* b2 = (const float*)d_in[14];       // [1786]
  float* out = (float*)d_out;

  const int B = in_sizes[1];                      // 4096
  const int IND = in_sizes[9];                    // 260
  const int H = in_sizes[12];                     // 1024
  const int OUTN = in_sizes[14];                  // 1786

  char* ws = (char*)d_ws;
  float* NO = (float*)ws;                                      // [B][1792] fp32
  char* p = ws + (size_t)B * NO_LD * 4;                        // 29,360,128
  _Float16* hH = (_Float16*)p;                                 // [B][1024] fp16 (dead after GEMM2)
  float* Xa = (float*)p;                                       // alias: fp32 [B][256]
  float* Xb = (float*)(p + (size_t)B * NUMV * 4);              // alias: fp32 [B][256]
  char* q = p + (size_t)B * H * 2;                             // 37,748,736
  _Float16* W2T = (_Float16*)q;                                // [1786][1024] fp16 (dead after GEMM2)
  _Float16* Vh = (_Float16*)q;                                 // alias: fp16 [B][256]
  _Float16* Vl = (_Float16*)(q + (size_t)B * NUMV * 2);        // alias: fp16 [B][256]
  char* q2 = q + (size_t)OUTN * H * 2;                         // 41,406,464
  _Float16* W1T = (_Float16*)q2;                               // [1024][260] fp16 (dead after GEMM1)
  char* r3 = ws + 41943040;                                    // 41,943,040
  float* lam = (float*)r3;                                     // fp32 [B][256]
  char* r4 = r3 + (size_t)B * NUMV * 4;                        // 46,137,344
  _Float16* Gh = (_Float16*)r4;                                // [256][256] fp16
  _Float16* Gl = (_Float16*)(r4 + 131072);                     // [256][256] fp16 (x2048)
  float* zc = (float*)(r4 + 262144);                           // [256] fp32

  build_g<<<8, 32, 0, stream>>>(Gh, Gl, zc);
  {
    dim3 g((IND + 31) / 32, (H + 31) / 32), blk(32, 8);
    transpose_cvt<<<g, blk, 0, stream>>>(W1, W1T, IND, H);
  }
  {
    dim3 g((H + 31) / 32, (OUTN + 31) / 32), blk(32, 8);
    transpose_cvt<<<g, blk, 0, stream>>>(W2, W2T, H, OUTN);
  }
  {
    dim3 g(B / 64, H / 128);
    mfma_gemm<true, true><<<g, 256, 0, stream>>>(inp, W1T, b1, hH, B, H, IND, IND, IND, H);
  }
  {
    dim3 g(B / 64, (OUTN + 127) / 128);
    mfma_gemm<false, false><<<g, 256, 0, stream>>>(hH, W2T, b2, NO, B, OUTN, H, H, H, NO_LD);
  }
  init_v<<<B, 256, 0, stream>>>(NO, ssamp, p_smax, p_smin, p_sdmax, p_sdmin,
                                p_sddmax, p_sddmin, Vh, Vl, B);
  float* Xcur = Xa;
  float* Xprev = Xb;
  for (int it = 0; it < QP_ITERS; it++) {
    dim3 g(B / 64, 2);
    solve_mfma<<<g, 256, 0, stream>>>(Vh, Vl, Gh, Gl, sinit, zc, Xcur, B);
    qp_update<<<B, 256, 0, stream>>>(Xcur, Xprev, NO, lam, ssamp,
                                     p_smax, p_smin, p_sdmax, p_sdmin,
                                     p_sddmax, p_sddmin, Vh, Vl, out, B, it);
    float* t = Xcur; Xcur = Xprev; Xprev = t;
  }
  accum_out<<<B / 256, 256, 0, stream>>>(out, B);
}

// Round 12
// 298.723 us; speedup vs baseline: 1.0355x; 1.0194x over previous
//
#include <hip/hip_runtime.h>
#include <cstddef>

// learned_qp_solver: B=4096, NUM=256, NC=1530, IND=260, H=1024, OUT=1786, 5 iters.
//
//   KKT solve closed form:  x = G v + (b_eq/z0) z,  G = C^{-1} - z z^T / z0 (symmetric)
//   MLP on matrix cores: 128x128 tile, v_mfma_f32_16x16x32_f16 (K=32, f16x8 frags).
//   A and B fragments use the IDENTICAL lane->k mapping, so any consistent k-order
//   yields exact dot products (A/B layouts symmetric); C/D layout HW-verified.
//   Solve: scaled split-fp16 (round-11 validated: Gl,Vl scaled x2048 to dodge fp16
//   denormal flush; x = accH + accL/2048 + beq*zc), rewritten as 1-wave blocks,
//   tile 16x32, grid (256,8)=2048 (round-11 lesson: (64,2)=128 blocks was 0.5/CU).
//
// ws layout (bytes), 46.4 MB; X/V/lam aliased onto dead hH/W2T/W1T regions:
//   [0,          29360128)  NO   fp32 [B][1792]
//   [29360128,   37748736)  hH   fp16 [B][1024]  -> after GEMM2: Xa, Xb (fp32 [B][256])
//   [37748736,   41406464)  W2T  fp16 [1786][1024] -> after GEMM2: Vh, Vl (fp16 [B][256])
//   [41406464,   41938944)  W1T  fp16 [1024][260]
//   [41943040,   46137344)  lam  fp32 [B][256]
//   [46137344,   46268416)  Gh   fp16 [256][256]
//   [46268416,   46399488)  Gl   fp16 [256][256]  (scaled x2048)
//   [46399488,   46400512)  zc   fp32 [256]

#define NUMV 256
#define QP_ITERS 5
#define NO_LD 1792
#define LSCALE 2048.0f
#define INV_LSCALE (1.0f / 2048.0f)

typedef _Float16 f16x4 __attribute__((ext_vector_type(4)));
typedef _Float16 f16x8 __attribute__((ext_vector_type(8)));
typedef float f32x4 __attribute__((ext_vector_type(4)));

// ---------------- compile-time pentadiagonal Cholesky tables ----------------
struct FacT {
  double invd[256];
  double l1[257];
  double l2[258];
  double z[256];
  float  zcf[256];
};

constexpr double csqrt_(double x) {
  double g = (x > 1.0) ? x : 1.0;
  for (int i = 0; i < 64; ++i) g = 0.5 * (g + x / g);
  return g;
}

constexpr FacT make_fac() {
  FacT f{};
  const double T = 0.05, a = 1.0 / (T * T), b2 = a * a;
  double c0[256] = {}, c1[255] = {}, c2[254] = {};
  double dd[256] = {}, l1[256] = {}, l2[256] = {};
  for (int j = 0; j < 256; j++) {
    double cd1 = (j == 0 || j == 255) ? 1.0 : 2.0;
    double cd2 = (j == 0 || j == 255) ? 1.0 : ((j == 1 || j == 254) ? 5.0 : 6.0);
    c0[j] = 3.0 + 2.0 * a * cd1 + 2.0 * b2 * cd2;
  }
  for (int j = 0; j < 255; j++) c1[j] = -2.0 * a + 2.0 * b2 * ((j == 0 || j == 254) ? -2.0 : -4.0);
  for (int j = 0; j < 254; j++) c2[j] = 2.0 * b2;
  dd[0] = csqrt_(c0[0]); l1[0] = 0.0; l2[0] = 0.0;
  l1[1] = c1[0] / dd[0]; l2[1] = 0.0;
  dd[1] = csqrt_(c0[1] - l1[1] * l1[1]);
  for (int j = 2; j < 256; j++) {
    l2[j] = c2[j - 2] / dd[j - 2];
    l1[j] = (c1[j - 1] - l2[j] * l1[j - 1]) / dd[j - 1];
    dd[j] = csqrt_(c0[j] - l1[j] * l1[j] - l2[j] * l2[j]);
  }
  for (int j = 0; j < 256; j++) f.invd[j] = 1.0 / dd[j];
  for (int j = 0; j < 256; j++) f.l1[j] = l1[j];
  f.l1[256] = 0.0;
  for (int j = 0; j < 256; j++) f.l2[j] = l2[j];
  f.l2[256] = 0.0; f.l2[257] = 0.0;
  double w[256] = {}, zz[256] = {};
  w[0] = 1.0 / dd[0];
  w[1] = (-l1[1] * w[0]) / dd[1];
  for (int j = 2; j < 256; j++) w[j] = (-l1[j] * w[j - 1] - l2[j] * w[j - 2]) / dd[j];
  zz[255] = w[255] / dd[255];
  zz[254] = (w[254] - l1[255] * zz[255]) / dd[254];
  for (int j = 253; j >= 0; j--)
    zz[j] = (w[j] - l1[j + 1] * zz[j + 1] - l2[j + 2] * zz[j + 2]) / dd[j];
  for (int j = 0; j < 256; j++) f.z[j] = zz[j];
  for (int j = 0; j < 256; j++) f.zcf[j] = (float)(zz[j] / zz[0]);
  return f;
}

constexpr FacT FAC_HOST = make_fac();
__constant__ FacT FAC = FAC_HOST;

// ---- build Gh/Gl = scaled split-fp16 of (C^{-1} - z z^T/z0); 8 blocks x 32 cols ----
__global__ __launch_bounds__(32) void build_g(
    _Float16* __restrict__ Gh, _Float16* __restrict__ Gl, float* __restrict__ zc)
{
  __shared__ double w[256][32];
  const int t = threadIdx.x;
  const int c = blockIdx.x * 32 + t;
  double w1 = 0.0, w2 = 0.0;
#pragma unroll 4
  for (int j = 0; j < 256; j++) {
    double rhs = (j == c) ? 1.0 : 0.0;
    double wj = (rhs - FAC.l1[j] * w1 - FAC.l2[j] * w2) * FAC.invd[j];
    w[j][t] = wj;
    w2 = w1; w1 = wj;
  }
  const double zr = FAC.z[c] / FAC.z[0];
  double y1 = 0.0, y2 = 0.0;
#pragma unroll 4
  for (int j = 255; j >= 0; j--) {
    double yj = (w[j][t] - FAC.l1[j + 1] * y1 - FAC.l2[j + 2] * y2) * FAC.invd[j];
    const float g = (float)(yj - FAC.z[j] * zr);
    const _Float16 gh = (_Float16)g;
    Gh[(size_t)j * 256 + c] = gh;               // symmetric: [j][c] == [c][j]
    Gl[(size_t)j * 256 + c] = (_Float16)((g - (float)gh) * LSCALE);  // normal range
    y2 = y1; y1 = yj;
  }
  zc[c] = FAC.zcf[c];
}

// ---------------- transpose + fp32->fp16 convert: in [K][N] -> out [N][K] ----------------
__global__ __launch_bounds__(256) void transpose_cvt(
    const float* __restrict__ in, _Float16* __restrict__ out, int K, int N)
{
  __shared__ float t[32][33];
  const int bk = blockIdx.x * 32, bn = blockIdx.y * 32;
  const int x = threadIdx.x, y = threadIdx.y;
  for (int yy = y; yy < 32; yy += 8) {
    const int k = bk + yy, n = bn + x;
    t[yy][x] = (k < K && n < N) ? in[(size_t)k * N + n] : 0.f;
  }
  __syncthreads();
  for (int yy = y; yy < 32; yy += 8) {
    const int n = bn + yy, k = bk + x;
    if (n < N && k < K) out[(size_t)n * K + k] = (_Float16)t[x][yy];
  }
}

// ---------------- MFMA GEMM: C = A * Bt^T + bias, 128x128 tile, 4 waves, K=32 ----
// A: [M][lda] fp32 (A_FP32) or fp16;  Bt: [N][ldk] fp16 (pre-transposed weights).
// v_mfma_f32_16x16x32_f16: frags f16x8, lane->k map 8*(lane>>4)+j (same for A & B).
template<bool A_FP32, bool OUT_H16>
__global__ __launch_bounds__(256) void mfma_gemm(
    const void* __restrict__ Av, const _Float16* __restrict__ Bt,
    const float* __restrict__ bias, void* __restrict__ Cv,
    int M, int Nv, int K, int lda, int ldk, int ldc)
{
  __shared__ _Float16 At[128][40];   // 80B stride: 16B-aligned b128 frag reads
  __shared__ _Float16 Bs[128][40];
  const int tid = threadIdx.x;
  const int lane = tid & 63, wid = tid >> 6;
  const int wr = wid >> 1, wc = wid & 1;        // wave -> 64x64 quadrant
  const int lrow = lane & 15, lb = lane >> 4;
  const int m0 = blockIdx.x * 128, n0 = blockIdx.y * 128;
  const int srow = tid >> 1, skh = (tid & 1) * 16;

  f32x4 acc[4][4];
#pragma unroll
  for (int i = 0; i < 4; i++)
#pragma unroll
    for (int j = 0; j < 4; j++) acc[i][j] = (f32x4)0.0f;

  const int nsteps = (K + 31) / 32;
  for (int t = 0; t < nsteps; ++t) {
    const int k0 = t * 32;
    // ---- stage A tile [128 rows][32 k] ----
    if (A_FP32) {
      const float* A = (const float*)Av;
#pragma unroll
      for (int i = 0; i < 4; i++) {
        const int k = k0 + skh + i * 4;
        f16x4 hv = {};
        if (k + 4 <= K) {
          const float4 v = *reinterpret_cast<const float4*>(&A[(size_t)(m0 + srow) * lda + k]);
          hv[0] = (_Float16)v.x; hv[1] = (_Float16)v.y;
          hv[2] = (_Float16)v.z; hv[3] = (_Float16)v.w;
        } else if (k < K) {
          for (int e = 0; e < 4; e++)
            if (k + e < K) hv[e] = (_Float16)A[(size_t)(m0 + srow) * lda + k + e];
        }
        *reinterpret_cast<f16x4*>(&At[srow][skh + i * 4]) = hv;
      }
    } else {
      const _Float16* A = (const _Float16*)Av;
#pragma unroll
      for (int i = 0; i < 4; i++) {
        const int k = k0 + skh + i * 4;
        f16x4 hv = {};
        if (k + 4 <= K) hv = *reinterpret_cast<const f16x4*>(&A[(size_t)(m0 + srow) * lda + k]);
        *reinterpret_cast<f16x4*>(&At[srow][skh + i * 4]) = hv;
      }
    }
    // ---- stage B tile [128 cols][32 k] from W^T ----
    {
      const int n = n0 + srow;
#pragma unroll
      for (int i = 0; i < 4; i++) {
        const int k = k0 + skh + i * 4;
        f16x4 hv = {};
        if (n < Nv && k + 4 <= K)
          hv = *reinterpret_cast<const f16x4*>(&Bt[(size_t)n * ldk + k]);
        *reinterpret_cast<f16x4*>(&Bs[srow][skh + i * 4]) = hv;
      }
    }
    __syncthreads();
    // ---- 16 MFMAs (K=32) per wave ----
    f16x8 af[4], bf[4];
#pragma unroll
    for (int i = 0; i < 4; i++)
      af[i] = *reinterpret_cast<const f16x8*>(&At[wr * 64 + i * 16 + lrow][lb * 8]);
#pragma unroll
    for (int j = 0; j < 4; j++)
      bf[j] = *reinterpret_cast<const f16x8*>(&Bs[wc * 64 + j * 16 + lrow][lb * 8]);
#pragma unroll
    for (int i = 0; i < 4; i++)
#pragma unroll
      for (int j = 0; j < 4; j++)
        acc[i][j] = __builtin_amdgcn_mfma_f32_16x16x32_f16(af[i], bf[j], acc[i][j], 0, 0, 0);
    __syncthreads();
  }
  // ---- epilogue: D col = lane&15, row = 4*(lane>>4)+reg ----
#pragma unroll
  for (int i = 0; i < 4; i++) {
#pragma unroll
    for (int j = 0; j < 4; j++) {
      const int gcol = n0 + wc * 64 + j * 16 + lrow;
      if (gcol < Nv) {
        const float bv = bias[gcol];
#pragma unroll
        for (int r = 0; r < 4; r++) {
          const int grow = m0 + wr * 64 + i * 16 + lb * 4 + r;
          float v = acc[i][j][r] + bv;
          if (OUT_H16) {
            v = fmaxf(v, 0.f);
            ((_Float16*)Cv)[(size_t)grow * ldc + gcol] = (_Float16)v;
          } else {
            ((float*)Cv)[(size_t)grow * ldc + gcol] = v;
          }
        }
      }
    }
  }
}

// ---- solve via scaled split-fp16 MFMA, 1-wave blocks, tile 16x32, K=32 ----
// accH = Vh*Gh ; accL = Vh*Gl' + Vl'*Gh  (Gl',Vl' scaled x2048)
// X = accH + accL/2048 + beq x zc. Fragments loaded DIRECTLY from global
// (V rows coalesce in 64B segments; G 256KB L2-hot). No LDS, no barriers.
__global__ __launch_bounds__(64) void solve_mfma(
    const _Float16* __restrict__ Vh, const _Float16* __restrict__ Vl,
    const _Float16* __restrict__ Gh, const _Float16* __restrict__ Gl,
    const float* __restrict__ beq, const float* __restrict__ zc,
    float* __restrict__ X, int B)
{
  const int lane = threadIdx.x;
  const int lr = lane & 15, lg = lane >> 4;
  const int m0 = blockIdx.x * 16, n0 = blockIdx.y * 32;
  f32x4 accH[2], accL[2];
#pragma unroll
  for (int nf = 0; nf < 2; nf++) { accH[nf] = (f32x4)0.0f; accL[nf] = (f32x4)0.0f; }
  const size_t arow = (size_t)(m0 + lr) * 256 + lg * 8;
#pragma unroll 2
  for (int k0 = 0; k0 < 256; k0 += 32) {
    const f16x8 ah = *reinterpret_cast<const f16x8*>(&Vh[arow + k0]);
    const f16x8 al = *reinterpret_cast<const f16x8*>(&Vl[arow + k0]);
#pragma unroll
    for (int nf = 0; nf < 2; nf++) {
      const size_t bidx = (size_t)(n0 + nf * 16 + lr) * 256 + k0 + lg * 8;
      const f16x8 bh = *reinterpret_cast<const f16x8*>(&Gh[bidx]);
      const f16x8 bl = *reinterpret_cast<const f16x8*>(&Gl[bidx]);
      accH[nf] = __builtin_amdgcn_mfma_f32_16x16x32_f16(ah, bh, accH[nf], 0, 0, 0);
      accL[nf] = __builtin_amdgcn_mfma_f32_16x16x32_f16(ah, bl, accL[nf], 0, 0, 0);
      accL[nf] = __builtin_amdgcn_mfma_f32_16x16x32_f16(al, bh, accL[nf], 0, 0, 0);
    }
  }
  // epilogue: D col = lane&15, row = 4*(lane>>4)+reg
  const int orow = m0 + lg * 4;
  float bq[4];
#pragma unroll
  for (int r = 0; r < 4; r++) bq[r] = beq[orow + r];
#pragma unroll
  for (int nf = 0; nf < 2; nf++) {
    const int col = n0 + nf * 16 + lr;
    const float zv = zc[col];
#pragma unroll
    for (int r = 0; r < 4; r++)
      X[(size_t)(orow + r) * 256 + col] = accH[nf][r] + accL[nf][r] * INV_LSCALE + bq[r] * zv;
  }
}

// ---------------- initial rhs V0 = lam0 + ss + b_aug0 @ A_control (scaled split) ----
__global__ __launch_bounds__(256) void init_v(
    const float* __restrict__ NO, const float* __restrict__ ss,
    const float* __restrict__ p_smax, const float* __restrict__ p_smin,
    const float* __restrict__ p_sdmax, const float* __restrict__ p_sdmin,
    const float* __restrict__ p_sddmax, const float* __restrict__ p_sddmin,
    _Float16* __restrict__ Vh, _Float16* __restrict__ Vl, int B)
{
  __shared__ float d1s[258], d2s[258];
  const int r = blockIdx.x, j = threadIdx.x;
  const float K0 = *p_smax + *p_smin, K1 = *p_sdmax + *p_sdmin, K2 = *p_sddmax + *p_sddmin;
  const float invT = 20.f, invT2 = 400.f;
  const float* no = NO + (size_t)r * NO_LD;
  float s1 = fmaxf(0.f, no[256 + j]), s2 = fmaxf(0.f, no[512 + j]);
  float D0 = K0 - s1 + s2;
  float D1 = 0.f, D2 = 0.f;
  if (j < 255) D1 = K1 - fmaxf(0.f, no[768 + j]) + fmaxf(0.f, no[1023 + j]);
  if (j < 254) D2 = K2 - fmaxf(0.f, no[1278 + j]) + fmaxf(0.f, no[1532 + j]);
  d1s[2 + j] = D1; d2s[2 + j] = D2;
  if (j < 2) { d1s[j] = 0.f; d2s[j] = 0.f; }
  __syncthreads();
  float qn = D0 + (d1s[j + 1] - d1s[j + 2]) * invT
                + (d2s[j] - 2.f * d2s[j + 1] + d2s[j + 2]) * invT2;
  const float vn = no[j] + ss[(size_t)r * NUMV + j] + qn;
  const _Float16 vh = (_Float16)vn;
  Vh[(size_t)r * NUMV + j] = vh;
  Vl[(size_t)r * NUMV + j] = (_Float16)((vn - (float)vh) * LSCALE);
}

// ---------------- per-iteration update: one block per row (round-5 validated) ----
__global__ __launch_bounds__(256) void qp_update(
    const float* __restrict__ X, const float* __restrict__ Xp,
    const float* __restrict__ NO, float* lam,
    const float* __restrict__ ss,
    const float* __restrict__ p_smax, const float* __restrict__ p_smin,
    const float* __restrict__ p_sdmax, const float* __restrict__ p_sdmin,
    const float* __restrict__ p_sddmax, const float* __restrict__ p_sddmin,
    _Float16* __restrict__ Vh, _Float16* __restrict__ Vl,
    float* __restrict__ out, int B, int it)
{
  __shared__ float xs[258], xps[258];
  __shared__ float e1s[258], e2s[258], d1s[258], d2s[258];
  __shared__ double red[3][4];
  const int r = blockIdx.x, j = threadIdx.x;
  const float smax = *p_smax, smin = *p_smin;
  const float sdmax = *p_sdmax, sdmin = *p_sdmin;
  const float sddmax = *p_sddmax, sddmin = *p_sddmin;
  const float invT = 20.f, invT2 = 400.f;

  const float x0 = X[(size_t)r * NUMV + j];
  xs[j] = x0;
  if (j < 2) xs[256 + j] = 0.f;
  float xp0 = 0.f;
  if (it > 0) {
    xp0 = Xp[(size_t)r * NUMV + j];
    xps[j] = xp0;
    if (j < 2) xps[256 + j] = 0.f;
  }
  __syncthreads();

  const bool h1 = j < 255, h2 = j < 254;
  const float x1 = xs[j + 1], x2 = xs[j + 2];
  const float v = (x1 - x0) * invT;
  const float aa = (x2 - 2.f * x1 + x0) * invT2;

  float rv0a = fmaxf(0.f, x0 - smax), rv0b = fmaxf(0.f, smin - x0);
  float rv1a = 0.f, rv1b = 0.f, rv2a = 0.f, rv2b = 0.f;
  float E1 = 0.f, E2 = 0.f;
  const float E0 = rv0a - rv0b;
  if (h1) { rv1a = fmaxf(0.f, v - sdmax); rv1b = fmaxf(0.f, sdmin - v); E1 = rv1a - rv1b; }
  if (h2) { rv2a = fmaxf(0.f, aa - sddmax); rv2b = fmaxf(0.f, sddmin - aa); E2 = rv2a - rv2b; }
  double res2 = (double)(rv0a * rv0a + rv0b * rv0b + rv1a * rv1a + rv1b * rv1b
                       + rv2a * rv2a + rv2b * rv2b);

  const float sn0a = fmaxf(0.f, smax - x0), sn0b = fmaxf(0.f, x0 - smin);
  float sn1a = 0.f, sn1b = 0.f, sn2a = 0.f, sn2b = 0.f;
  if (h1) { sn1a = fmaxf(0.f, sdmax - v); sn1b = fmaxf(0.f, v - sdmin); }
  if (h2) { sn2a = fmaxf(0.f, sddmax - aa); sn2b = fmaxf(0.f, aa - sddmin); }

  const float D0n = fminf(smax, x0) + fmaxf(smin, x0);
  const float D1n = h1 ? (fminf(sdmax, v) + fmaxf(sdmin, v)) : 0.f;
  const float D2n = h2 ? (fminf(sddmax, aa) + fmaxf(sddmin, aa)) : 0.f;

  float sp0a, sp0b, sp1a = 0.f, sp1b = 0.f, sp2a = 0.f, sp2b = 0.f;
  if (it == 0) {
    const float* no = NO + (size_t)r * NO_LD;
    sp0a = fmaxf(0.f, no[256 + j]); sp0b = fmaxf(0.f, no[512 + j]);
    if (h1) { sp1a = fmaxf(0.f, no[768 + j]); sp1b = fmaxf(0.f, no[1023 + j]); }
    if (h2) { sp2a = fmaxf(0.f, no[1278 + j]); sp2b = fmaxf(0.f, no[1532 + j]); }
  } else {
    const float xp1 = xps[j + 1], xp2 = xps[j + 2];
    const float vp = (xp1 - xp0) * invT;
    const float ap = (xp2 - 2.f * xp1 + xp0) * invT2;
    sp0a = fmaxf(0.f, smax - xp0); sp0b = fmaxf(0.f, xp0 - smin);
    if (h1) { sp1a = fmaxf(0.f, sdmax - vp); sp1b = fmaxf(0.f, vp - sdmin); }
    if (h2) { sp2a = fmaxf(0.f, sddmax - ap); sp2b = fmaxf(0.f, ap - sddmin); }
  }
  const float d0a = sp0a - sn0a, d0b = sp0b - sn0b;
  const float d1a = sp1a - sn1a, d1b = sp1b - sn1b;
  const float d2a = sp2a - sn2a, d2b = sp2b - sn2b;
  double fps2 = (double)(d0a * d0a + d0b * d0b + d1a * d1a + d1b * d1b
                       + d2a * d2a + d2b * d2b);

  e1s[2 + j] = E1; e2s[2 + j] = E2; d1s[2 + j] = D1n; d2s[2 + j] = D2n;
  if (j < 2) { e1s[j] = 0.f; e2s[j] = 0.f; d1s[j] = 0.f; d2s[j] = 0.f; }
  __syncthreads();

  const float lamj = (it == 0) ? NO[(size_t)r * NO_LD + j] : lam[(size_t)r * NUMV + j];
  const float lnew = lamj - (E0 + (e1s[j + 1] - e1s[j + 2]) * invT
                                + (e2s[j] - 2.f * e2s[j + 1] + e2s[j + 2]) * invT2);
  const float dl = lamj - lnew;
  double fpl2 = (double)(dl * dl);
  lam[(size_t)r * NUMV + j] = lnew;

  const size_t primOff = (size_t)B * NUMV;
  const size_t fpOff = primOff + (size_t)QP_ITERS * B;
  if (it < QP_ITERS - 1) {
    float qn = D0n + (d1s[j + 1] - d1s[j + 2]) * invT
                   + (d2s[j] - 2.f * d2s[j + 1] + d2s[j + 2]) * invT2;
    const float vn = lnew + ss[(size_t)r * NUMV + j] + qn;
    const _Float16 vh = (_Float16)vn;
    Vh[(size_t)r * NUMV + j] = vh;
    Vl[(size_t)r * NUMV + j] = (_Float16)((vn - (float)vh) * LSCALE);
  } else {
    out[(size_t)r * NUMV + j] = x0;
  }

  for (int o = 32; o > 0; o >>= 1) {
    res2 += __shfl_down(res2, o);
    fps2 += __shfl_down(fps2, o);
    fpl2 += __shfl_down(fpl2, o);
  }
  const int wid = j >> 6, lane = j & 63;
  if (lane == 0) { red[0][wid] = res2; red[1][wid] = fps2; red[2][wid] = fpl2; }
  __syncthreads();
  if (j == 0) {
    double r2 = red[0][0] + red[0][1] + red[0][2] + red[0][3];
    double s2_ = red[1][0] + red[1][1] + red[1][2] + red[1][3];
    double l2_ = red[2][0] + red[2][1] + red[2][2] + red[2][3];
    out[primOff + (size_t)it * B + r] = sqrtf((float)r2);
    out[fpOff + (size_t)it * B + r] = sqrtf((float)s2_) + sqrtf((float)l2_);
  }
}

// ---------------- final acc_primal / acc_fixed ----------------
__global__ __launch_bounds__(256) void accum_out(float* __restrict__ out, int B)
{
  const int r = blockIdx.x * 256 + threadIdx.x;
  const size_t primOff = (size_t)B * NUMV;
  const size_t fpOff = primOff + (size_t)QP_ITERS * B;
  const size_t accPOff = fpOff + (size_t)QP_ITERS * B;
  const size_t accFOff = accPOff + (size_t)B;
  float sp = 0.f, sf = 0.f;
  for (int it = 0; it < QP_ITERS; it++) {
    sp += out[primOff + (size_t)it * B + r];
    sf += out[fpOff + (size_t)it * B + r];
  }
  out[accPOff + r] = sp * (1.f / QP_ITERS);
  out[accFOff + r] = sf * (1.f / QP_ITERS);
}

extern "C" void kernel_launch(void* const* d_in, const int* in_sizes, int n_in,
                              void* d_out, int out_size, void* d_ws, size_t ws_size,
                              hipStream_t stream)
{
  const float* inp = (const float*)d_in[0];       // [B][260]
  const float* sinit = (const float*)d_in[1];     // [B][1]
  const float* ssamp = (const float*)d_in[2];     // [B][256]
  const float* p_smax = (const float*)d_in[3];
  const float* p_smin = (const float*)d_in[4];
  const float* p_sdmax = (const float*)d_in[5];
  const float* p_sdmin = (const float*)d_in[6];
  const float* p_sddmax = (const float*)d_in[7];
  const float* p_sddmin = (const float*)d_in[8];
  const float* W1 = (const float*)d_in[11];       // [260][1024]
  const float* b1 = (const float*)d_in[12];       // [1024]
  const float* W2 = (const float*)d_in[13];       // [1024][1786]
  const float* b2 = (const float*)d_in[14];       // [1786]
  float* out = (float*)d_out;

  const int B = in_sizes[1];                      // 4096
  const int IND = in_sizes[9];                    // 260
  const int H = in_sizes[12];                     // 1024
  const int OUTN = in_sizes[14];                  // 1786

  char* ws = (char*)d_ws;
  float* NO = (float*)ws;                                      // [B][1792] fp32
  char* p = ws + (size_t)B * NO_LD * 4;                        // 29,360,128
  _Float16* hH = (_Float16*)p;                                 // [B][1024] fp16 (dead after GEMM2)
  float* Xa = (float*)p;                                       // alias: fp32 [B][256]
  float* Xb = (float*)(p + (size_t)B * NUMV * 4);              // alias: fp32 [B][256]
  char* q = p + (size_t)B * H * 2;                             // 37,748,736
  _Float16* W2T = (_Float16*)q;                                // [1786][1024] fp16 (dead after GEMM2)
  _Float16* Vh = (_Float16*)q;                                 // alias: fp16 [B][256]
  _Float16* Vl = (_Float16*)(q + (size_t)B * NUMV * 2);        // alias: fp16 [B][256]
  char* q2 = q + (size_t)OUTN * H * 2;                         // 41,406,464
  _Float16* W1T = (_Float16*)q2;                               // [1024][260] fp16 (dead after GEMM1)
  char* r3 = ws + 41943040;                                    // 41,943,040
  float* lam = (float*)r3;                                     // fp32 [B][256]
  char* r4 = r3 + (size_t)B * NUMV * 4;                        // 46,137,344
  _Float16* Gh = (_Float16*)r4;                                // [256][256] fp16
  _Float16* Gl = (_Float16*)(r4 + 131072);                     // [256][256] fp16 (x2048)
  float* zc = (float*)(r4 + 262144);                           // [256] fp32

  build_g<<<8, 32, 0, stream>>>(Gh, Gl, zc);
  {
    dim3 g((IND + 31) / 32, (H + 31) / 32), blk(32, 8);
    transpose_cvt<<<g, blk, 0, stream>>>(W1, W1T, IND, H);
  }
  {
    dim3 g((H + 31) / 32, (OUTN + 31) / 32), blk(32, 8);
    transpose_cvt<<<g, blk, 0, stream>>>(W2, W2T, H, OUTN);
  }
  {
    dim3 g(B / 128, H / 128);
    mfma_gemm<true, true><<<g, 256, 0, stream>>>(inp, W1T, b1, hH, B, H, IND, IND, IND, H);
  }
  {
    dim3 g(B / 128, (OUTN + 127) / 128);
    mfma_gemm<false, false><<<g, 256, 0, stream>>>(hH, W2T, b2, NO, B, OUTN, H, H, H, NO_LD);
  }
  init_v<<<B, 256, 0, stream>>>(NO, ssamp, p_smax, p_smin, p_sdmax, p_sdmin,
                                p_sddmax, p_sddmin, Vh, Vl, B);
  float* Xcur = Xa;
  float* Xprev = Xb;
  for (int it = 0; it < QP_ITERS; it++) {
    dim3 g(B / 16, 8);
    solve_mfma<<<g, 64, 0, stream>>>(Vh, Vl, Gh, Gl, sinit, zc, Xcur, B);
    qp_update<<<B, 256, 0, stream>>>(Xcur, Xprev, NO, lam, ssamp,
                                     p_smax, p_smin, p_sdmax, p_sdmin,
                                     p_sddmax, p_sddmin, Vh, Vl, out, B, it);
    float* t = Xcur; Xcur = Xprev; Xprev = t;
  }
  accum_out<<<B / 256, 256, 0, stream>>>(out, B);
}

// Round 13
// 279.977 us; speedup vs baseline: 1.1049x; 1.0670x over previous
//
#include <hip/hip_runtime.h>
#include <cstddef>

// learned_qp_solver: B=4096, NUM=256, NC=1530, IND=260, H=1024, OUT=1786, 5 iters.
//
//   KKT solve closed form:  x = G v + (b_eq/z0) z,  G = C^{-1} - z z^T / z0 (symmetric)
//   MLP on matrix cores: 128x128 tile, v_mfma_f32_16x16x32_f16 (K=32, f16x8 frags).
//   Solve: scaled split-fp16 (Gl,Vl scaled x2048 to dodge fp16 denormal flush;
//   x = accH + accL/2048 + beq*zc), 1-wave blocks, grid (256,8).
//   G build (round-12 lesson: fp64 fwd+bwd solves w/ LDS on dependent path = 64us
//   serial tumor): C^{-1} = U^T U with U = L^{-1} -> build_u does FORWARD-only
//   recurrences (1 block x 256 thr, no LDS), G assembled by split-fp16 MFMA GEMM
//   gemm_g = U^T(U^T)^T - z z^T/z0 (z from compile-time tables).
//
// ws layout (bytes), ~46.7 MB; X/V/lam aliased onto dead hH/W2T/W1T regions:
//   [0,          29360128)  NO   fp32 [B][1792]
//   [29360128,   37748736)  hH   fp16 [B][1024]  -> after GEMM2: Xa, Xb (fp32 [B][256])
//   [37748736,   41406464)  W2T  fp16 [1786][1024] -> after GEMM2: Vh, Vl (fp16 [B][256])
//   [41406464,   41938944)  W1T  fp16 [1024][260]
//   [41943040,   46137344)  lam  fp32 [B][256]
//   [46137344,   46268416)  Gh   fp16 [256][256]
//   [46268416,   46399488)  Gl   fp16 [256][256]  (scaled x2048)
//   [46399488,   46400512)  zc   fp32 [256]
//   [46400512,   46531584)  Uh   fp16 [256][256]  (U^T rows)
//   [46531584,   46662656)  Ul   fp16 [256][256]  (scaled x2048)

#define NUMV 256
#define QP_ITERS 5
#define NO_LD 1792
#define LSCALE 2048.0f
#define INV_LSCALE (1.0f / 2048.0f)

typedef _Float16 f16x4 __attribute__((ext_vector_type(4)));
typedef _Float16 f16x8 __attribute__((ext_vector_type(8)));
typedef float f32x4 __attribute__((ext_vector_type(4)));

// ---------------- compile-time pentadiagonal Cholesky tables ----------------
struct FacT {
  double invd[256];
  double l1[257];
  double l2[258];
  double z[256];
  float  zcf[256];
};

constexpr double csqrt_(double x) {
  double g = (x > 1.0) ? x : 1.0;
  for (int i = 0; i < 64; ++i) g = 0.5 * (g + x / g);
  return g;
}

constexpr FacT make_fac() {
  FacT f{};
  const double T = 0.05, a = 1.0 / (T * T), b2 = a * a;
  double c0[256] = {}, c1[255] = {}, c2[254] = {};
  double dd[256] = {}, l1[256] = {}, l2[256] = {};
  for (int j = 0; j < 256; j++) {
    double cd1 = (j == 0 || j == 255) ? 1.0 : 2.0;
    double cd2 = (j == 0 || j == 255) ? 1.0 : ((j == 1 || j == 254) ? 5.0 : 6.0);
    c0[j] = 3.0 + 2.0 * a * cd1 + 2.0 * b2 * cd2;
  }
  for (int j = 0; j < 255; j++) c1[j] = -2.0 * a + 2.0 * b2 * ((j == 0 || j == 254) ? -2.0 : -4.0);
  for (int j = 0; j < 254; j++) c2[j] = 2.0 * b2;
  dd[0] = csqrt_(c0[0]); l1[0] = 0.0; l2[0] = 0.0;
  l1[1] = c1[0] / dd[0]; l2[1] = 0.0;
  dd[1] = csqrt_(c0[1] - l1[1] * l1[1]);
  for (int j = 2; j < 256; j++) {
    l2[j] = c2[j - 2] / dd[j - 2];
    l1[j] = (c1[j - 1] - l2[j] * l1[j - 1]) / dd[j - 1];
    dd[j] = csqrt_(c0[j] - l1[j] * l1[j] - l2[j] * l2[j]);
  }
  for (int j = 0; j < 256; j++) f.invd[j] = 1.0 / dd[j];
  for (int j = 0; j < 256; j++) f.l1[j] = l1[j];
  f.l1[256] = 0.0;
  for (int j = 0; j < 256; j++) f.l2[j] = l2[j];
  f.l2[256] = 0.0; f.l2[257] = 0.0;
  double w[256] = {}, zz[256] = {};
  w[0] = 1.0 / dd[0];
  w[1] = (-l1[1] * w[0]) / dd[1];
  for (int j = 2; j < 256; j++) w[j] = (-l1[j] * w[j - 1] - l2[j] * w[j - 2]) / dd[j];
  zz[255] = w[255] / dd[255];
  zz[254] = (w[254] - l1[255] * zz[255]) / dd[254];
  for (int j = 253; j >= 0; j--)
    zz[j] = (w[j] - l1[j + 1] * zz[j + 1] - l2[j + 2] * zz[j + 2]) / dd[j];
  for (int j = 0; j < 256; j++) f.z[j] = zz[j];
  for (int j = 0; j < 256; j++) f.zcf[j] = (float)(zz[j] / zz[0]);
  return f;
}

constexpr FacT FAC_HOST = make_fac();
__constant__ FacT FAC = FAC_HOST;

// ---- build U^T rows (U = L^{-1}, forward solves only), scaled split-fp16 ----
// Thread c: w = L^{-1} e_c; writes UT[c][j] = w_j. No LDS, no backward pass.
__global__ __launch_bounds__(256) void build_u(
    _Float16* __restrict__ Uh, _Float16* __restrict__ Ul, float* __restrict__ zc)
{
  const int c = threadIdx.x;
  double w1 = 0.0, w2 = 0.0;
  for (int j0 = 0; j0 < 256; j0 += 8) {
    f16x8 bh, bl;
#pragma unroll
    for (int e = 0; e < 8; e++) {
      const int j = j0 + e;
      const double rhs = (j == c) ? 1.0 : 0.0;
      const double wj = (rhs - FAC.l1[j] * w1 - FAC.l2[j] * w2) * FAC.invd[j];
      const float wf = (float)wj;
      const _Float16 h = (_Float16)wf;
      bh[e] = h;
      bl[e] = (_Float16)((wf - (float)h) * LSCALE);
      w2 = w1; w1 = wj;
    }
    *reinterpret_cast<f16x8*>(&Uh[(size_t)c * 256 + j0]) = bh;
    *reinterpret_cast<f16x8*>(&Ul[(size_t)c * 256 + j0]) = bl;
  }
  zc[c] = FAC.zcf[c];
}

// ---- G = UT * UT^T - z z^T/z0 via split-fp16 MFMA; output re-split to Gh/Gl ----
// 1-wave blocks, tile 16x32, grid (16,8). Same validated frag layout as solve_mfma.
__global__ __launch_bounds__(64) void gemm_g(
    const _Float16* __restrict__ Uh, const _Float16* __restrict__ Ul,
    _Float16* __restrict__ Gh, _Float16* __restrict__ Gl)
{
  const int lane = threadIdx.x;
  const int lr = lane & 15, lg = lane >> 4;
  const int m0 = blockIdx.x * 16, n0 = blockIdx.y * 32;
  f32x4 accH[2], accL[2];
#pragma unroll
  for (int nf = 0; nf < 2; nf++) { accH[nf] = (f32x4)0.0f; accL[nf] = (f32x4)0.0f; }
  const size_t arow = (size_t)(m0 + lr) * 256 + lg * 8;
#pragma unroll 2
  for (int k0 = 0; k0 < 256; k0 += 32) {
    const f16x8 ah = *reinterpret_cast<const f16x8*>(&Uh[arow + k0]);
    const f16x8 al = *reinterpret_cast<const f16x8*>(&Ul[arow + k0]);
#pragma unroll
    for (int nf = 0; nf < 2; nf++) {
      const size_t bidx = (size_t)(n0 + nf * 16 + lr) * 256 + k0 + lg * 8;
      const f16x8 bh = *reinterpret_cast<const f16x8*>(&Uh[bidx]);
      const f16x8 bl = *reinterpret_cast<const f16x8*>(&Ul[bidx]);
      accH[nf] = __builtin_amdgcn_mfma_f32_16x16x32_f16(ah, bh, accH[nf], 0, 0, 0);
      accL[nf] = __builtin_amdgcn_mfma_f32_16x16x32_f16(ah, bl, accL[nf], 0, 0, 0);
      accL[nf] = __builtin_amdgcn_mfma_f32_16x16x32_f16(al, bh, accL[nf], 0, 0, 0);
    }
  }
  // epilogue: D col = lane&15, row = 4*(lane>>4)+reg
  const int row0 = m0 + lg * 4;
#pragma unroll
  for (int nf = 0; nf < 2; nf++) {
    const int col = n0 + nf * 16 + lr;
    const double zcd = FAC.z[col] / FAC.z[0];
#pragma unroll
    for (int r = 0; r < 4; r++) {
      const int row = row0 + r;
      const float g = accH[nf][r] + accL[nf][r] * INV_LSCALE
                    - (float)(FAC.z[row] * zcd);
      const _Float16 gh = (_Float16)g;
      Gh[(size_t)row * 256 + col] = gh;
      Gl[(size_t)row * 256 + col] = (_Float16)((g - (float)gh) * LSCALE);
    }
  }
}

// ---------------- transpose + fp32->fp16 convert: in [K][N] -> out [N][K] ----------------
__global__ __launch_bounds__(256) void transpose_cvt(
    const float* __restrict__ in, _Float16* __restrict__ out, int K, int N)
{
  __shared__ float t[32][33];
  const int bk = blockIdx.x * 32, bn = blockIdx.y * 32;
  const int x = threadIdx.x, y = threadIdx.y;
  for (int yy = y; yy < 32; yy += 8) {
    const int k = bk + yy, n = bn + x;
    t[yy][x] = (k < K && n < N) ? in[(size_t)k * N + n] : 0.f;
  }
  __syncthreads();
  for (int yy = y; yy < 32; yy += 8) {
    const int n = bn + yy, k = bk + x;
    if (n < N && k < K) out[(size_t)n * K + k] = (_Float16)t[x][yy];
  }
}

// ---------------- MFMA GEMM: C = A * Bt^T + bias, 128x128 tile, 4 waves, K=32 ----
template<bool A_FP32, bool OUT_H16>
__global__ __launch_bounds__(256) void mfma_gemm(
    const void* __restrict__ Av, const _Float16* __restrict__ Bt,
    const float* __restrict__ bias, void* __restrict__ Cv,
    int M, int Nv, int K, int lda, int ldk, int ldc)
{
  __shared__ _Float16 At[128][40];   // 80B stride: 16B-aligned b128 frag reads
  __shared__ _Float16 Bs[128][40];
  const int tid = threadIdx.x;
  const int lane = tid & 63, wid = tid >> 6;
  const int wr = wid >> 1, wc = wid & 1;        // wave -> 64x64 quadrant
  const int lrow = lane & 15, lb = lane >> 4;
  const int m0 = blockIdx.x * 128, n0 = blockIdx.y * 128;
  const int srow = tid >> 1, skh = (tid & 1) * 16;

  f32x4 acc[4][4];
#pragma unroll
  for (int i = 0; i < 4; i++)
#pragma unroll
    for (int j = 0; j < 4; j++) acc[i][j] = (f32x4)0.0f;

  const int nsteps = (K + 31) / 32;
  for (int t = 0; t < nsteps; ++t) {
    const int k0 = t * 32;
    if (A_FP32) {
      const float* A = (const float*)Av;
#pragma unroll
      for (int i = 0; i < 4; i++) {
        const int k = k0 + skh + i * 4;
        f16x4 hv = {};
        if (k + 4 <= K) {
          const float4 v = *reinterpret_cast<const float4*>(&A[(size_t)(m0 + srow) * lda + k]);
          hv[0] = (_Float16)v.x; hv[1] = (_Float16)v.y;
          hv[2] = (_Float16)v.z; hv[3] = (_Float16)v.w;
        } else if (k < K) {
          for (int e = 0; e < 4; e++)
            if (k + e < K) hv[e] = (_Float16)A[(size_t)(m0 + srow) * lda + k + e];
        }
        *reinterpret_cast<f16x4*>(&At[srow][skh + i * 4]) = hv;
      }
    } else {
      const _Float16* A = (const _Float16*)Av;
#pragma unroll
      for (int i = 0; i < 4; i++) {
        const int k = k0 + skh + i * 4;
        f16x4 hv = {};
        if (k + 4 <= K) hv = *reinterpret_cast<const f16x4*>(&A[(size_t)(m0 + srow) * lda + k]);
        *reinterpret_cast<f16x4*>(&At[srow][skh + i * 4]) = hv;
      }
    }
    {
      const int n = n0 + srow;
#pragma unroll
      for (int i = 0; i < 4; i++) {
        const int k = k0 + skh + i * 4;
        f16x4 hv = {};
        if (n < Nv && k + 4 <= K)
          hv = *reinterpret_cast<const f16x4*>(&Bt[(size_t)n * ldk + k]);
        *reinterpret_cast<f16x4*>(&Bs[srow][skh + i * 4]) = hv;
      }
    }
    __syncthreads();
    f16x8 af[4], bf[4];
#pragma unroll
    for (int i = 0; i < 4; i++)
      af[i] = *reinterpret_cast<const f16x8*>(&At[wr * 64 + i * 16 + lrow][lb * 8]);
#pragma unroll
    for (int j = 0; j < 4; j++)
      bf[j] = *reinterpret_cast<const f16x8*>(&Bs[wc * 64 + j * 16 + lrow][lb * 8]);
#pragma unroll
    for (int i = 0; i < 4; i++)
#pragma unroll
      for (int j = 0; j < 4; j++)
        acc[i][j] = __builtin_amdgcn_mfma_f32_16x16x32_f16(af[i], bf[j], acc[i][j], 0, 0, 0);
    __syncthreads();
  }
#pragma unroll
  for (int i = 0; i < 4; i++) {
#pragma unroll
    for (int j = 0; j < 4; j++) {
      const int gcol = n0 + wc * 64 + j * 16 + lrow;
      if (gcol < Nv) {
        const float bv = bias[gcol];
#pragma unroll
        for (int r = 0; r < 4; r++) {
          const int grow = m0 + wr * 64 + i * 16 + lb * 4 + r;
          float v = acc[i][j][r] + bv;
          if (OUT_H16) {
            v = fmaxf(v, 0.f);
            ((_Float16*)Cv)[(size_t)grow * ldc + gcol] = (_Float16)v;
          } else {
            ((float*)Cv)[(size_t)grow * ldc + gcol] = v;
          }
        }
      }
    }
  }
}

// ---- solve via scaled split-fp16 MFMA, 1-wave blocks, tile 16x32, K=32 ----
__global__ __launch_bounds__(64) void solve_mfma(
    const _Float16* __restrict__ Vh, const _Float16* __restrict__ Vl,
    const _Float16* __restrict__ Gh, const _Float16* __restrict__ Gl,
    const float* __restrict__ beq, const float* __restrict__ zc,
    float* __restrict__ X, int B)
{
  const int lane = threadIdx.x;
  const int lr = lane & 15, lg = lane >> 4;
  const int m0 = blockIdx.x * 16, n0 = blockIdx.y * 32;
  f32x4 accH[2], accL[2];
#pragma unroll
  for (int nf = 0; nf < 2; nf++) { accH[nf] = (f32x4)0.0f; accL[nf] = (f32x4)0.0f; }
  const size_t arow = (size_t)(m0 + lr) * 256 + lg * 8;
#pragma unroll 2
  for (int k0 = 0; k0 < 256; k0 += 32) {
    const f16x8 ah = *reinterpret_cast<const f16x8*>(&Vh[arow + k0]);
    const f16x8 al = *reinterpret_cast<const f16x8*>(&Vl[arow + k0]);
#pragma unroll
    for (int nf = 0; nf < 2; nf++) {
      const size_t bidx = (size_t)(n0 + nf * 16 + lr) * 256 + k0 + lg * 8;
      const f16x8 bh = *reinterpret_cast<const f16x8*>(&Gh[bidx]);
      const f16x8 bl = *reinterpret_cast<const f16x8*>(&Gl[bidx]);
      accH[nf] = __builtin_amdgcn_mfma_f32_16x16x32_f16(ah, bh, accH[nf], 0, 0, 0);
      accL[nf] = __builtin_amdgcn_mfma_f32_16x16x32_f16(ah, bl, accL[nf], 0, 0, 0);
      accL[nf] = __builtin_amdgcn_mfma_f32_16x16x32_f16(al, bh, accL[nf], 0, 0, 0);
    }
  }
  const int orow = m0 + lg * 4;
  float bq[4];
#pragma unroll
  for (int r = 0; r < 4; r++) bq[r] = beq[orow + r];
#pragma unroll
  for (int nf = 0; nf < 2; nf++) {
    const int col = n0 + nf * 16 + lr;
    const float zv = zc[col];
#pragma unroll
    for (int r = 0; r < 4; r++)
      X[(size_t)(orow + r) * 256 + col] = accH[nf][r] + accL[nf][r] * INV_LSCALE + bq[r] * zv;
  }
}

// ---------------- initial rhs V0 = lam0 + ss + b_aug0 @ A_control (scaled split) ----
__global__ __launch_bounds__(256) void init_v(
    const float* __restrict__ NO, const float* __restrict__ ss,
    const float* __restrict__ p_smax, const float* __restrict__ p_smin,
    const float* __restrict__ p_sdmax, const float* __restrict__ p_sdmin,
    const float* __restrict__ p_sddmax, const float* __restrict__ p_sddmin,
    _Float16* __restrict__ Vh, _Float16* __restrict__ Vl, int B)
{
  __shared__ float d1s[258], d2s[258];
  const int r = blockIdx.x, j = threadIdx.x;
  const float K0 = *p_smax + *p_smin, K1 = *p_sdmax + *p_sdmin, K2 = *p_sddmax + *p_sddmin;
  const float invT = 20.f, invT2 = 400.f;
  const float* no = NO + (size_t)r * NO_LD;
  float s1 = fmaxf(0.f, no[256 + j]), s2 = fmaxf(0.f, no[512 + j]);
  float D0 = K0 - s1 + s2;
  float D1 = 0.f, D2 = 0.f;
  if (j < 255) D1 = K1 - fmaxf(0.f, no[768 + j]) + fmaxf(0.f, no[1023 + j]);
  if (j < 254) D2 = K2 - fmaxf(0.f, no[1278 + j]) + fmaxf(0.f, no[1532 + j]);
  d1s[2 + j] = D1; d2s[2 + j] = D2;
  if (j < 2) { d1s[j] = 0.f; d2s[j] = 0.f; }
  __syncthreads();
  float qn = D0 + (d1s[j + 1] - d1s[j + 2]) * invT
                + (d2s[j] - 2.f * d2s[j + 1] + d2s[j + 2]) * invT2;
  const float vn = no[j] + ss[(size_t)r * NUMV + j] + qn;
  const _Float16 vh = (_Float16)vn;
  Vh[(size_t)r * NUMV + j] = vh;
  Vl[(size_t)r * NUMV + j] = (_Float16)((vn - (float)vh) * LSCALE);
}

// ---------------- per-iteration update: one block per row (round-5 validated) ----
__global__ __launch_bounds__(256) void qp_update(
    const float* __restrict__ X, const float* __restrict__ Xp,
    const float* __restrict__ NO, float* lam,
    const float* __restrict__ ss,
    const float* __restrict__ p_smax, const float* __restrict__ p_smin,
    const float* __restrict__ p_sdmax, const float* __restrict__ p_sdmin,
    const float* __restrict__ p_sddmax, const float* __restrict__ p_sddmin,
    _Float16* __restrict__ Vh, _Float16* __restrict__ Vl,
    float* __restrict__ out, int B, int it)
{
  __shared__ float xs[258], xps[258];
  __shared__ float e1s[258], e2s[258], d1s[258], d2s[258];
  __shared__ double red[3][4];
  const int r = blockIdx.x, j = threadIdx.x;
  const float smax = *p_smax, smin = *p_smin;
  const float sdmax = *p_sdmax, sdmin = *p_sdmin;
  const float sddmax = *p_sddmax, sddmin = *p_sddmin;
  const float invT = 20.f, invT2 = 400.f;

  const float x0 = X[(size_t)r * NUMV + j];
  xs[j] = x0;
  if (j < 2) xs[256 + j] = 0.f;
  float xp0 = 0.f;
  if (it > 0) {
    xp0 = Xp[(size_t)r * NUMV + j];
    xps[j] = xp0;
    if (j < 2) xps[256 + j] = 0.f;
  }
  __syncthreads();

  const bool h1 = j < 255, h2 = j < 254;
  const float x1 = xs[j + 1], x2 = xs[j + 2];
  const float v = (x1 - x0) * invT;
  const float aa = (x2 - 2.f * x1 + x0) * invT2;

  float rv0a = fmaxf(0.f, x0 - smax), rv0b = fmaxf(0.f, smin - x0);
  float rv1a = 0.f, rv1b = 0.f, rv2a = 0.f, rv2b = 0.f;
  float E1 = 0.f, E2 = 0.f;
  const float E0 = rv0a - rv0b;
  if (h1) { rv1a = fmaxf(0.f, v - sdmax); rv1b = fmaxf(0.f, sdmin - v); E1 = rv1a - rv1b; }
  if (h2) { rv2a = fmaxf(0.f, aa - sddmax); rv2b = fmaxf(0.f, sddmin - aa); E2 = rv2a - rv2b; }
  double res2 = (double)(rv0a * rv0a + rv0b * rv0b + rv1a * rv1a + rv1b * rv1b
                       + rv2a * rv2a + rv2b * rv2b);

  const float sn0a = fmaxf(0.f, smax - x0), sn0b = fmaxf(0.f, x0 - smin);
  float sn1a = 0.f, sn1b = 0.f, sn2a = 0.f, sn2b = 0.f;
  if (h1) { sn1a = fmaxf(0.f, sdmax - v); sn1b = fmaxf(0.f, v - sdmin); }
  if (h2) { sn2a = fmaxf(0.f, sddmax - aa); sn2b = fmaxf(0.f, aa - sddmin); }

  const float D0n = fminf(smax, x0) + fmaxf(smin, x0);
  const float D1n = h1 ? (fminf(sdmax, v) + fmaxf(sdmin, v)) : 0.f;
  const float D2n = h2 ? (fminf(sddmax, aa) + fmaxf(sddmin, aa)) : 0.f;

  float sp0a, sp0b, sp1a = 0.f, sp1b = 0.f, sp2a = 0.f, sp2b = 0.f;
  if (it == 0) {
    const float* no = NO + (size_t)r * NO_LD;
    sp0a = fmaxf(0.f, no[256 + j]); sp0b = fmaxf(0.f, no[512 + j]);
    if (h1) { sp1a = fmaxf(0.f, no[768 + j]); sp1b = fmaxf(0.f, no[1023 + j]); }
    if (h2) { sp2a = fmaxf(0.f, no[1278 + j]); sp2b = fmaxf(0.f, no[1532 + j]); }
  } else {
    const float xp1 = xps[j + 1], xp2 = xps[j + 2];
    const float vp = (xp1 - xp0) * invT;
    const float ap = (xp2 - 2.f * xp1 + xp0) * invT2;
    sp0a = fmaxf(0.f, smax - xp0); sp0b = fmaxf(0.f, xp0 - smin);
    if (h1) { sp1a = fmaxf(0.f, sdmax - vp); sp1b = fmaxf(0.f, vp - sdmin); }
    if (h2) { sp2a = fmaxf(0.f, sddmax - ap); sp2b = fmaxf(0.f, ap - sddmin); }
  }
  const float d0a = sp0a - sn0a, d0b = sp0b - sn0b;
  const float d1a = sp1a - sn1a, d1b = sp1b - sn1b;
  const float d2a = sp2a - sn2a, d2b = sp2b - sn2b;
  double fps2 = (double)(d0a * d0a + d0b * d0b + d1a * d1a + d1b * d1b
                       + d2a * d2a + d2b * d2b);

  e1s[2 + j] = E1; e2s[2 + j] = E2; d1s[2 + j] = D1n; d2s[2 + j] = D2n;
  if (j < 2) { e1s[j] = 0.f; e2s[j] = 0.f; d1s[j] = 0.f; d2s[j] = 0.f; }
  __syncthreads();

  const float lamj = (it == 0) ? NO[(size_t)r * NO_LD + j] : lam[(size_t)r * NUMV + j];
  const float lnew = lamj - (E0 + (e1s[j + 1] - e1s[j + 2]) * invT
                                + (e2s[j] - 2.f * e2s[j + 1] + e2s[j + 2]) * invT2);
  const float dl = lamj - lnew;
  double fpl2 = (double)(dl * dl);
  lam[(size_t)r * NUMV + j] = lnew;

  const size_t primOff = (size_t)B * NUMV;
  const size_t fpOff = primOff + (size_t)QP_ITERS * B;
  if (it < QP_ITERS - 1) {
    float qn = D0n + (d1s[j + 1] - d1s[j + 2]) * invT
                   + (d2s[j] - 2.f * d2s[j + 1] + d2s[j + 2]) * invT2;
    const float vn = lnew + ss[(size_t)r * NUMV + j] + qn;
    const _Float16 vh = (_Float16)vn;
    Vh[(size_t)r * NUMV + j] = vh;
    Vl[(size_t)r * NUMV + j] = (_Float16)((vn - (float)vh) * LSCALE);
  } else {
    out[(size_t)r * NUMV + j] = x0;
  }

  for (int o = 32; o > 0; o >>= 1) {
    res2 += __shfl_down(res2, o);
    fps2 += __shfl_down(fps2, o);
    fpl2 += __shfl_down(fpl2, o);
  }
  const int wid = j >> 6, lane = j & 63;
  if (lane == 0) { red[0][wid] = res2; red[1][wid] = fps2; red[2][wid] = fpl2; }
  __syncthreads();
  if (j == 0) {
    double r2 = red[0][0] + red[0][1] + red[0][2] + red[0][3];
    double s2_ = red[1][0] + red[1][1] + red[1][2] + red[1][3];
    double l2_ = red[2][0] + red[2][1] + red[2][2] + red[2][3];
    out[primOff + (size_t)it * B + r] = sqrtf((float)r2);
    out[fpOff + (size_t)it * B + r] = sqrtf((float)s2_) + sqrtf((float)l2_);
  }
}

// ---------------- final acc_primal / acc_fixed ----------------
__global__ __launch_bounds__(256) void accum_out(float* __restrict__ out, int B)
{
  const int r = blockIdx.x * 256 + threadIdx.x;
  const size_t primOff = (size_t)B * NUMV;
  const size_t fpOff = primOff + (size_t)QP_ITERS * B;
  const size_t accPOff = fpOff + (size_t)QP_ITERS * B;
  const size_t accFOff = accPOff + (size_t)B;
  float sp = 0.f, sf = 0.f;
  for (int it = 0; it < QP_ITERS; it++) {
    sp += out[primOff + (size_t)it * B + r];
    sf += out[fpOff + (size_t)it * B + r];
  }
  out[accPOff + r] = sp * (1.f / QP_ITERS);
  out[accFOff + r] = sf * (1.f / QP_ITERS);
}

extern "C" void kernel_launch(void* const* d_in, const int* in_sizes, int n_in,
                              void* d_out, int out_size, void* d_ws, size_t ws_size,
                              hipStream_t stream)
{
  const float* inp = (const float*)d_in[0];       // [B][260]
  const float* sinit = (const float*)d_in[1];     // [B][1]
  const float* ssamp = (const float*)d_in[2];     // [B][256]
  const float* p_smax = (const float*)d_in[3];
  const float* p_smin = (const float*)d_in[4];
  const float* p_sdmax = (const float*)d_in[5];
  const float* p_sdmin = (const float*)d_in[6];
  const float* p_sddmax = (const float*)d_in[7];
  const float* p_sddmin = (const float*)d_in[8];
  const float* W1 = (const float*)d_in[11];       // [260][1024]
  const float* b1 = (const float*)d_in[12];       // [1024]
  const float* W2 = (const float*)d_in[13];       // [1024][1786]
  const float* b2 = (const float*)d_in[14];       // [1786]
  float* out = (float*)d_out;

  const int B = in_sizes[1];                      // 4096
  const int IND = in_sizes[9];                    // 260
  const int H = in_sizes[12];                     // 1024
  const int OUTN = in_sizes[14];                  // 1786

  char* ws = (char*)d_ws;
  float* NO = (float*)ws;                                      // [B][1792] fp32
  char* p = ws + (size_t)B * NO_LD * 4;                        // 29,360,128
  _Float16* hH = (_Float16*)p;                                 // [B][1024] fp16 (dead after GEMM2)
  float* Xa = (float*)p;                                       // alias: fp32 [B][256]
  float* Xb = (float*)(p + (size_t)B * NUMV * 4);              // alias: fp32 [B][256]
  char* q = p + (size_t)B * H * 2;                             // 37,748,736
  _Float16* W2T = (_Float16*)q;                                // [1786][1024] fp16 (dead after GEMM2)
  _Float16* Vh = (_Float16*)q;                                 // alias: fp16 [B][256]
  _Float16* Vl = (_Float16*)(q + (size_t)B * NUMV * 2);        // alias: fp16 [B][256]
  char* q2 = q + (size_t)OUTN * H * 2;                         // 41,406,464
  _Float16* W1T = (_Float16*)q2;                               // [1024][260] fp16 (dead after GEMM1)
  char* r3 = ws + 41943040;                                    // 41,943,040
  float* lam = (float*)r3;                                     // fp32 [B][256]
  char* r4 = r3 + (size_t)B * NUMV * 4;                        // 46,137,344
  _Float16* Gh = (_Float16*)r4;                                // [256][256] fp16
  _Float16* Gl = (_Float16*)(r4 + 131072);                     // [256][256] fp16 (x2048)
  float* zc = (float*)(r4 + 262144);                           // [256] fp32
  _Float16* Uh = (_Float16*)(r4 + 263168);                     // [256][256] fp16 (U^T)
  _Float16* Ul = (_Float16*)(r4 + 263168 + 131072);            // [256][256] fp16 (x2048)

  build_u<<<1, 256, 0, stream>>>(Uh, Ul, zc);
  {
    dim3 g(16, 8);
    gemm_g<<<g, 64, 0, stream>>>(Uh, Ul, Gh, Gl);
  }
  {
    dim3 g((IND + 31) / 32, (H + 31) / 32), blk(32, 8);
    transpose_cvt<<<g, blk, 0, stream>>>(W1, W1T, IND, H);
  }
  {
    dim3 g((H + 31) / 32, (OUTN + 31) / 32), blk(32, 8);
    transpose_cvt<<<g, blk, 0, stream>>>(W2, W2T, H, OUTN);
  }
  {
    dim3 g(B / 128, H / 128);
    mfma_gemm<true, true><<<g, 256, 0, stream>>>(inp, W1T, b1, hH, B, H, IND, IND, IND, H);
  }
  {
    dim3 g(B / 128, (OUTN + 127) / 128);
    mfma_gemm<false, false><<<g, 256, 0, stream>>>(hH, W2T, b2, NO, B, OUTN, H, H, H, NO_LD);
  }
  init_v<<<B, 256, 0, stream>>>(NO, ssamp, p_smax, p_smin, p_sdmax, p_sdmin,
                                p_sddmax, p_sddmin, Vh, Vl, B);
  float* Xcur = Xa;
  float* Xprev = Xb;
  for (int it = 0; it < QP_ITERS; it++) {
    dim3 g(B / 16, 8);
    solve_mfma<<<g, 64, 0, stream>>>(Vh, Vl, Gh, Gl, sinit, zc, Xcur, B);
    qp_update<<<B, 256, 0, stream>>>(Xcur, Xprev, NO, lam, ssamp,
                                     p_smax, p_smin, p_sdmax, p_sdmin,
                                     p_sddmax, p_sddmin, Vh, Vl, out, B, it);
    float* t = Xcur; Xcur = Xprev; Xprev = t;
  }
  accum_out<<<B / 256, 256, 0, stream>>>(out, B);
}

// Round 14
// 259.628 us; speedup vs baseline: 1.1915x; 1.0784x over previous
//
#include <hip/hip_runtime.h>
#include <cstddef>

// learned_qp_solver: B=4096, NUM=256, NC=1530, IND=260, H=1024, OUT=1786, 5 iters.
//
//   KKT solve closed form:  x = G v + (b_eq/z0) z,  G = C^{-1} - z z^T / z0 (symmetric)
//   MLP on matrix cores: v_mfma_f32_16x16x32_f16 (K=32, f16x8 frags).
//   GEMM2 (fp16 A, K%64==0): BK=64 variant — 16B staging (f16x8 ld/ds_write_b128),
//   32 MFMAs per barrier pair (round-13 lesson: BK=32 had 8B stores w/ 4-way
//   conflicts + 2 barriers per 16 MFMAs -> MfmaUtil 9%).
//   Solve: scaled split-fp16 (Gl,Vl x2048 dodges fp16 denormal flush in MFMA),
//   1-wave blocks, grid (256,8).
//   G build: C^{-1} = U^T U, U = L^{-1}; build_u fwd-only recurrences, gemm_g MFMA.
//
// ws layout (bytes), ~46.7 MB; X/V/lam aliased onto dead hH/W2T/W1T regions:
//   [0,          29360128)  NO   fp32 [B][1792]
//   [29360128,   37748736)  hH   fp16 [B][1024]  -> after GEMM2: Xa, Xb (fp32 [B][256])
//   [37748736,   41406464)  W2T  fp16 [1786][1024] -> after GEMM2: Vh, Vl (fp16 [B][256])
//   [41406464,   41938944)  W1T  fp16 [1024][260]
//   [41943040,   46137344)  lam  fp32 [B][256]
//   [46137344,   46268416)  Gh   fp16 [256][256]
//   [46268416,   46399488)  Gl   fp16 [256][256]  (scaled x2048)
//   [46399488,   46400512)  zc   fp32 [256]
//   [46400512,   46531584)  Uh   fp16 [256][256]  (U^T rows)
//   [46531584,   46662656)  Ul   fp16 [256][256]  (scaled x2048)

#define NUMV 256
#define QP_ITERS 5
#define NO_LD 1792
#define LSCALE 2048.0f
#define INV_LSCALE (1.0f / 2048.0f)

typedef _Float16 f16x4 __attribute__((ext_vector_type(4)));
typedef _Float16 f16x8 __attribute__((ext_vector_type(8)));
typedef float f32x4 __attribute__((ext_vector_type(4)));

// ---------------- compile-time pentadiagonal Cholesky tables ----------------
struct FacT {
  double invd[256];
  double l1[257];
  double l2[258];
  double z[256];
  float  zcf[256];
};

constexpr double csqrt_(double x) {
  double g = (x > 1.0) ? x : 1.0;
  for (int i = 0; i < 64; ++i) g = 0.5 * (g + x / g);
  return g;
}

constexpr FacT make_fac() {
  FacT f{};
  const double T = 0.05, a = 1.0 / (T * T), b2 = a * a;
  double c0[256] = {}, c1[255] = {}, c2[254] = {};
  double dd[256] = {}, l1[256] = {}, l2[256] = {};
  for (int j = 0; j < 256; j++) {
    double cd1 = (j == 0 || j == 255) ? 1.0 : 2.0;
    double cd2 = (j == 0 || j == 255) ? 1.0 : ((j == 1 || j == 254) ? 5.0 : 6.0);
    c0[j] = 3.0 + 2.0 * a * cd1 + 2.0 * b2 * cd2;
  }
  for (int j = 0; j < 255; j++) c1[j] = -2.0 * a + 2.0 * b2 * ((j == 0 || j == 254) ? -2.0 : -4.0);
  for (int j = 0; j < 254; j++) c2[j] = 2.0 * b2;
  dd[0] = csqrt_(c0[0]); l1[0] = 0.0; l2[0] = 0.0;
  l1[1] = c1[0] / dd[0]; l2[1] = 0.0;
  dd[1] = csqrt_(c0[1] - l1[1] * l1[1]);
  for (int j = 2; j < 256; j++) {
    l2[j] = c2[j - 2] / dd[j - 2];
    l1[j] = (c1[j - 1] - l2[j] * l1[j - 1]) / dd[j - 1];
    dd[j] = csqrt_(c0[j] - l1[j] * l1[j] - l2[j] * l2[j]);
  }
  for (int j = 0; j < 256; j++) f.invd[j] = 1.0 / dd[j];
  for (int j = 0; j < 256; j++) f.l1[j] = l1[j];
  f.l1[256] = 0.0;
  for (int j = 0; j < 256; j++) f.l2[j] = l2[j];
  f.l2[256] = 0.0; f.l2[257] = 0.0;
  double w[256] = {}, zz[256] = {};
  w[0] = 1.0 / dd[0];
  w[1] = (-l1[1] * w[0]) / dd[1];
  for (int j = 2; j < 256; j++) w[j] = (-l1[j] * w[j - 1] - l2[j] * w[j - 2]) / dd[j];
  zz[255] = w[255] / dd[255];
  zz[254] = (w[254] - l1[255] * zz[255]) / dd[254];
  for (int j = 253; j >= 0; j--)
    zz[j] = (w[j] - l1[j + 1] * zz[j + 1] - l2[j + 2] * zz[j + 2]) / dd[j];
  for (int j = 0; j < 256; j++) f.z[j] = zz[j];
  for (int j = 0; j < 256; j++) f.zcf[j] = (float)(zz[j] / zz[0]);
  return f;
}

constexpr FacT FAC_HOST = make_fac();
__constant__ FacT FAC = FAC_HOST;

// ---- build U^T rows (U = L^{-1}, forward solves only), scaled split-fp16 ----
__global__ __launch_bounds__(256) void build_u(
    _Float16* __restrict__ Uh, _Float16* __restrict__ Ul, float* __restrict__ zc)
{
  const int c = threadIdx.x;
  double w1 = 0.0, w2 = 0.0;
  for (int j0 = 0; j0 < 256; j0 += 8) {
    f16x8 bh, bl;
#pragma unroll
    for (int e = 0; e < 8; e++) {
      const int j = j0 + e;
      const double rhs = (j == c) ? 1.0 : 0.0;
      const double wj = (rhs - FAC.l1[j] * w1 - FAC.l2[j] * w2) * FAC.invd[j];
      const float wf = (float)wj;
      const _Float16 h = (_Float16)wf;
      bh[e] = h;
      bl[e] = (_Float16)((wf - (float)h) * LSCALE);
      w2 = w1; w1 = wj;
    }
    *reinterpret_cast<f16x8*>(&Uh[(size_t)c * 256 + j0]) = bh;
    *reinterpret_cast<f16x8*>(&Ul[(size_t)c * 256 + j0]) = bl;
  }
  zc[c] = FAC.zcf[c];
}

// ---- G = UT * UT^T - z z^T/z0 via split-fp16 MFMA; output re-split to Gh/Gl ----
__global__ __launch_bounds__(64) void gemm_g(
    const _Float16* __restrict__ Uh, const _Float16* __restrict__ Ul,
    _Float16* __restrict__ Gh, _Float16* __restrict__ Gl)
{
  const int lane = threadIdx.x;
  const int lr = lane & 15, lg = lane >> 4;
  const int m0 = blockIdx.x * 16, n0 = blockIdx.y * 32;
  f32x4 accH[2], accL[2];
#pragma unroll
  for (int nf = 0; nf < 2; nf++) { accH[nf] = (f32x4)0.0f; accL[nf] = (f32x4)0.0f; }
  const size_t arow = (size_t)(m0 + lr) * 256 + lg * 8;
#pragma unroll 2
  for (int k0 = 0; k0 < 256; k0 += 32) {
    const f16x8 ah = *reinterpret_cast<const f16x8*>(&Uh[arow + k0]);
    const f16x8 al = *reinterpret_cast<const f16x8*>(&Ul[arow + k0]);
#pragma unroll
    for (int nf = 0; nf < 2; nf++) {
      const size_t bidx = (size_t)(n0 + nf * 16 + lr) * 256 + k0 + lg * 8;
      const f16x8 bh = *reinterpret_cast<const f16x8*>(&Uh[bidx]);
      const f16x8 bl = *reinterpret_cast<const f16x8*>(&Ul[bidx]);
      accH[nf] = __builtin_amdgcn_mfma_f32_16x16x32_f16(ah, bh, accH[nf], 0, 0, 0);
      accL[nf] = __builtin_amdgcn_mfma_f32_16x16x32_f16(ah, bl, accL[nf], 0, 0, 0);
      accL[nf] = __builtin_amdgcn_mfma_f32_16x16x32_f16(al, bh, accL[nf], 0, 0, 0);
    }
  }
  const int row0 = m0 + lg * 4;
#pragma unroll
  for (int nf = 0; nf < 2; nf++) {
    const int col = n0 + nf * 16 + lr;
    const double zcd = FAC.z[col] / FAC.z[0];
#pragma unroll
    for (int r = 0; r < 4; r++) {
      const int row = row0 + r;
      const float g = accH[nf][r] + accL[nf][r] * INV_LSCALE
                    - (float)(FAC.z[row] * zcd);
      const _Float16 gh = (_Float16)g;
      Gh[(size_t)row * 256 + col] = gh;
      Gl[(size_t)row * 256 + col] = (_Float16)((g - (float)gh) * LSCALE);
    }
  }
}

// ---------------- transpose + fp32->fp16 convert: in [K][N] -> out [N][K] ----------------
__global__ __launch_bounds__(256) void transpose_cvt(
    const float* __restrict__ in, _Float16* __restrict__ out, int K, int N)
{
  __shared__ float t[32][33];
  const int bk = blockIdx.x * 32, bn = blockIdx.y * 32;
  const int x = threadIdx.x, y = threadIdx.y;
  for (int yy = y; yy < 32; yy += 8) {
    const int k = bk + yy, n = bn + x;
    t[yy][x] = (k < K && n < N) ? in[(size_t)k * N + n] : 0.f;
  }
  __syncthreads();
  for (int yy = y; yy < 32; yy += 8) {
    const int n = bn + yy, k = bk + x;
    if (n < N && k < K) out[(size_t)n * K + k] = (_Float16)t[x][yy];
  }
}

// ---------------- MFMA GEMM (BK=32, handles fp32 A + K tails): GEMM1 ----------------
template<bool A_FP32, bool OUT_H16>
__global__ __launch_bounds__(256) void mfma_gemm(
    const void* __restrict__ Av, const _Float16* __restrict__ Bt,
    const float* __restrict__ bias, void* __restrict__ Cv,
    int M, int Nv, int K, int lda, int ldk, int ldc)
{
  __shared__ _Float16 At[128][40];
  __shared__ _Float16 Bs[128][40];
  const int tid = threadIdx.x;
  const int lane = tid & 63, wid = tid >> 6;
  const int wr = wid >> 1, wc = wid & 1;
  const int lrow = lane & 15, lb = lane >> 4;
  const int m0 = blockIdx.x * 128, n0 = blockIdx.y * 128;
  const int srow = tid >> 1, skh = (tid & 1) * 16;

  f32x4 acc[4][4];
#pragma unroll
  for (int i = 0; i < 4; i++)
#pragma unroll
    for (int j = 0; j < 4; j++) acc[i][j] = (f32x4)0.0f;

  const int nsteps = (K + 31) / 32;
  for (int t = 0; t < nsteps; ++t) {
    const int k0 = t * 32;
    if (A_FP32) {
      const float* A = (const float*)Av;
#pragma unroll
      for (int i = 0; i < 4; i++) {
        const int k = k0 + skh + i * 4;
        f16x4 hv = {};
        if (k + 4 <= K) {
          const float4 v = *reinterpret_cast<const float4*>(&A[(size_t)(m0 + srow) * lda + k]);
          hv[0] = (_Float16)v.x; hv[1] = (_Float16)v.y;
          hv[2] = (_Float16)v.z; hv[3] = (_Float16)v.w;
        } else if (k < K) {
          for (int e = 0; e < 4; e++)
            if (k + e < K) hv[e] = (_Float16)A[(size_t)(m0 + srow) * lda + k + e];
        }
        *reinterpret_cast<f16x4*>(&At[srow][skh + i * 4]) = hv;
      }
    } else {
      const _Float16* A = (const _Float16*)Av;
#pragma unroll
      for (int i = 0; i < 4; i++) {
        const int k = k0 + skh + i * 4;
        f16x4 hv = {};
        if (k + 4 <= K) hv = *reinterpret_cast<const f16x4*>(&A[(size_t)(m0 + srow) * lda + k]);
        *reinterpret_cast<f16x4*>(&At[srow][skh + i * 4]) = hv;
      }
    }
    {
      const int n = n0 + srow;
#pragma unroll
      for (int i = 0; i < 4; i++) {
        const int k = k0 + skh + i * 4;
        f16x4 hv = {};
        if (n < Nv && k + 4 <= K)
          hv = *reinterpret_cast<const f16x4*>(&Bt[(size_t)n * ldk + k]);
        *reinterpret_cast<f16x4*>(&Bs[srow][skh + i * 4]) = hv;
      }
    }
    __syncthreads();
    f16x8 af[4], bf[4];
#pragma unroll
    for (int i = 0; i < 4; i++)
      af[i] = *reinterpret_cast<const f16x8*>(&At[wr * 64 + i * 16 + lrow][lb * 8]);
#pragma unroll
    for (int j = 0; j < 4; j++)
      bf[j] = *reinterpret_cast<const f16x8*>(&Bs[wc * 64 + j * 16 + lrow][lb * 8]);
#pragma unroll
    for (int i = 0; i < 4; i++)
#pragma unroll
      for (int j = 0; j < 4; j++)
        acc[i][j] = __builtin_amdgcn_mfma_f32_16x16x32_f16(af[i], bf[j], acc[i][j], 0, 0, 0);
    __syncthreads();
  }
#pragma unroll
  for (int i = 0; i < 4; i++) {
#pragma unroll
    for (int j = 0; j < 4; j++) {
      const int gcol = n0 + wc * 64 + j * 16 + lrow;
      if (gcol < Nv) {
        const float bv = bias[gcol];
#pragma unroll
        for (int r = 0; r < 4; r++) {
          const int grow = m0 + wr * 64 + i * 16 + lb * 4 + r;
          float v = acc[i][j][r] + bv;
          if (OUT_H16) {
            v = fmaxf(v, 0.f);
            ((_Float16*)Cv)[(size_t)grow * ldc + gcol] = (_Float16)v;
          } else {
            ((float*)Cv)[(size_t)grow * ldc + gcol] = v;
          }
        }
      }
    }
  }
}

// ---------------- MFMA GEMM BK=64 (fp16 A, K%64==0, fp32 out): GEMM2 ----------------
// 16B staging (f16x8 / ds_write_b128), 32 MFMAs per barrier pair.
__global__ __launch_bounds__(256) void mfma_gemm64(
    const _Float16* __restrict__ A, const _Float16* __restrict__ Bt,
    const float* __restrict__ bias, float* __restrict__ C,
    int M, int Nv, int K, int lda, int ldk, int ldc)
{
  __shared__ _Float16 At[128][72];   // 144B rows: 16B-aligned, even bank spread
  __shared__ _Float16 Bs[128][72];
  const int tid = threadIdx.x;
  const int lane = tid & 63, wid = tid >> 6;
  const int wr = wid >> 1, wc = wid & 1;
  const int lrow = lane & 15, lb = lane >> 4;
  const int m0 = blockIdx.x * 128, n0 = blockIdx.y * 128;
  const int srow = tid >> 1, sh = (tid & 1) * 32;   // row, half-offset (halfs)

  f32x4 acc[4][4];
#pragma unroll
  for (int i = 0; i < 4; i++)
#pragma unroll
    for (int j = 0; j < 4; j++) acc[i][j] = (f32x4)0.0f;

  const int nsteps = K >> 6;
  for (int t = 0; t < nsteps; ++t) {
    const int k0 = t * 64;
    // stage A: each thread 4x f16x8 (one 64B half-row)
    const _Float16* asrc = &A[(size_t)(m0 + srow) * lda + k0 + sh];
#pragma unroll
    for (int i = 0; i < 4; i++)
      *reinterpret_cast<f16x8*>(&At[srow][sh + i * 8]) =
          *reinterpret_cast<const f16x8*>(asrc + i * 8);
    // stage B
    {
      const int n = n0 + srow;
      const _Float16* bsrc = &Bt[(size_t)n * ldk + k0 + sh];
#pragma unroll
      for (int i = 0; i < 4; i++) {
        f16x8 hv = {};
        if (n < Nv) hv = *reinterpret_cast<const f16x8*>(bsrc + i * 8);
        *reinterpret_cast<f16x8*>(&Bs[srow][sh + i * 8]) = hv;
      }
    }
    __syncthreads();
#pragma unroll
    for (int h = 0; h < 2; h++) {
      f16x8 af[4], bf[4];
#pragma unroll
      for (int i = 0; i < 4; i++)
        af[i] = *reinterpret_cast<const f16x8*>(&At[wr * 64 + i * 16 + lrow][h * 32 + lb * 8]);
#pragma unroll
      for (int j = 0; j < 4; j++)
        bf[j] = *reinterpret_cast<const f16x8*>(&Bs[wc * 64 + j * 16 + lrow][h * 32 + lb * 8]);
#pragma unroll
      for (int i = 0; i < 4; i++)
#pragma unroll
        for (int j = 0; j < 4; j++)
          acc[i][j] = __builtin_amdgcn_mfma_f32_16x16x32_f16(af[i], bf[j], acc[i][j], 0, 0, 0);
    }
    __syncthreads();
  }
#pragma unroll
  for (int i = 0; i < 4; i++) {
#pragma unroll
    for (int j = 0; j < 4; j++) {
      const int gcol = n0 + wc * 64 + j * 16 + lrow;
      if (gcol < Nv) {
        const float bv = bias[gcol];
#pragma unroll
        for (int r = 0; r < 4; r++) {
          const int grow = m0 + wr * 64 + i * 16 + lb * 4 + r;
          C[(size_t)grow * ldc + gcol] = acc[i][j][r] + bv;
        }
      }
    }
  }
}

// ---- solve via scaled split-fp16 MFMA, 1-wave blocks, tile 16x32, K=32 ----
__global__ __launch_bounds__(64) void solve_mfma(
    const _Float16* __restrict__ Vh, const _Float16* __restrict__ Vl,
    const _Float16* __restrict__ Gh, const _Float16* __restrict__ Gl,
    const float* __restrict__ beq, const float* __restrict__ zc,
    float* __restrict__ X, int B)
{
  const int lane = threadIdx.x;
  const int lr = lane & 15, lg = lane >> 4;
  const int m0 = blockIdx.x * 16, n0 = blockIdx.y * 32;
  f32x4 accH[2], accL[2];
#pragma unroll
  for (int nf = 0; nf < 2; nf++) { accH[nf] = (f32x4)0.0f; accL[nf] = (f32x4)0.0f; }
  const size_t arow = (size_t)(m0 + lr) * 256 + lg * 8;
#pragma unroll 2
  for (int k0 = 0; k0 < 256; k0 += 32) {
    const f16x8 ah = *reinterpret_cast<const f16x8*>(&Vh[arow + k0]);
    const f16x8 al = *reinterpret_cast<const f16x8*>(&Vl[arow + k0]);
#pragma unroll
    for (int nf = 0; nf < 2; nf++) {
      const size_t bidx = (size_t)(n0 + nf * 16 + lr) * 256 + k0 + lg * 8;
      const f16x8 bh = *reinterpret_cast<const f16x8*>(&Gh[bidx]);
      const f16x8 bl = *reinterpret_cast<const f16x8*>(&Gl[bidx]);
      accH[nf] = __builtin_amdgcn_mfma_f32_16x16x32_f16(ah, bh, accH[nf], 0, 0, 0);
      accL[nf] = __builtin_amdgcn_mfma_f32_16x16x32_f16(ah, bl, accL[nf], 0, 0, 0);
      accL[nf] = __builtin_amdgcn_mfma_f32_16x16x32_f16(al, bh, accL[nf], 0, 0, 0);
    }
  }
  const int orow = m0 + lg * 4;
  float bq[4];
#pragma unroll
  for (int r = 0; r < 4; r++) bq[r] = beq[orow + r];
#pragma unroll
  for (int nf = 0; nf < 2; nf++) {
    const int col = n0 + nf * 16 + lr;
    const float zv = zc[col];
#pragma unroll
    for (int r = 0; r < 4; r++)
      X[(size_t)(orow + r) * 256 + col] = accH[nf][r] + accL[nf][r] * INV_LSCALE + bq[r] * zv;
  }
}

// ---------------- initial rhs V0 = lam0 + ss + b_aug0 @ A_control (scaled split) ----
__global__ __launch_bounds__(256) void init_v(
    const float* __restrict__ NO, const float* __restrict__ ss,
    const float* __restrict__ p_smax, const float* __restrict__ p_smin,
    const float* __restrict__ p_sdmax, const float* __restrict__ p_sdmin,
    const float* __restrict__ p_sddmax, const float* __restrict__ p_sddmin,
    _Float16* __restrict__ Vh, _Float16* __restrict__ Vl, int B)
{
  __shared__ float d1s[258], d2s[258];
  const int r = blockIdx.x, j = threadIdx.x;
  const float K0 = *p_smax + *p_smin, K1 = *p_sdmax + *p_sdmin, K2 = *p_sddmax + *p_sddmin;
  const float invT = 20.f, invT2 = 400.f;
  const float* no = NO + (size_t)r * NO_LD;
  float s1 = fmaxf(0.f, no[256 + j]), s2 = fmaxf(0.f, no[512 + j]);
  float D0 = K0 - s1 + s2;
  float D1 = 0.f, D2 = 0.f;
  if (j < 255) D1 = K1 - fmaxf(0.f, no[768 + j]) + fmaxf(0.f, no[1023 + j]);
  if (j < 254) D2 = K2 - fmaxf(0.f, no[1278 + j]) + fmaxf(0.f, no[1532 + j]);
  d1s[2 + j] = D1; d2s[2 + j] = D2;
  if (j < 2) { d1s[j] = 0.f; d2s[j] = 0.f; }
  __syncthreads();
  float qn = D0 + (d1s[j + 1] - d1s[j + 2]) * invT
                + (d2s[j] - 2.f * d2s[j + 1] + d2s[j + 2]) * invT2;
  const float vn = no[j] + ss[(size_t)r * NUMV + j] + qn;
  const _Float16 vh = (_Float16)vn;
  Vh[(size_t)r * NUMV + j] = vh;
  Vl[(size_t)r * NUMV + j] = (_Float16)((vn - (float)vh) * LSCALE);
}

// ---------------- per-iteration update: one block per row (round-5 validated) ----
__global__ __launch_bounds__(256) void qp_update(
    const float* __restrict__ X, const float* __restrict__ Xp,
    const float* __restrict__ NO, float* lam,
    const float* __restrict__ ss,
    const float* __restrict__ p_smax, const float* __restrict__ p_smin,
    const float* __restrict__ p_sdmax, const float* __restrict__ p_sdmin,
    const float* __restrict__ p_sddmax, const float* __restrict__ p_sddmin,
    _Float16* __restrict__ Vh, _Float16* __restrict__ Vl,
    float* __restrict__ out, int B, int it)
{
  __shared__ float xs[258], xps[258];
  __shared__ float e1s[258], e2s[258], d1s[258], d2s[258];
  __shared__ double red[3][4];
  const int r = blockIdx.x, j = threadIdx.x;
  const float smax = *p_smax, smin = *p_smin;
  const float sdmax = *p_sdmax, sdmin = *p_sdmin;
  const float sddmax = *p_sddmax, sddmin = *p_sddmin;
  const float invT = 20.f, invT2 = 400.f;

  const float x0 = X[(size_t)r * NUMV + j];
  xs[j] = x0;
  if (j < 2) xs[256 + j] = 0.f;
  float xp0 = 0.f;
  if (it > 0) {
    xp0 = Xp[(size_t)r * NUMV + j];
    xps[j] = xp0;
    if (j < 2) xps[256 + j] = 0.f;
  }
  __syncthreads();

  const bool h1 = j < 255, h2 = j < 254;
  const float x1 = xs[j + 1], x2 = xs[j + 2];
  const float v = (x1 - x0) * invT;
  const float aa = (x2 - 2.f * x1 + x0) * invT2;

  float rv0a = fmaxf(0.f, x0 - smax), rv0b = fmaxf(0.f, smin - x0);
  float rv1a = 0.f, rv1b = 0.f, rv2a = 0.f, rv2b = 0.f;
  float E1 = 0.f, E2 = 0.f;
  const float E0 = rv0a - rv0b;
  if (h1) { rv1a = fmaxf(0.f, v - sdmax); rv1b = fmaxf(0.f, sdmin - v); E1 = rv1a - rv1b; }
  if (h2) { rv2a = fmaxf(0.f, aa - sddmax); rv2b = fmaxf(0.f, sddmin - aa); E2 = rv2a - rv2b; }
  double res2 = (double)(rv0a * rv0a + rv0b * rv0b + rv1a * rv1a + rv1b * rv1b
                       + rv2a * rv2a + rv2b * rv2b);

  const float sn0a = fmaxf(0.f, smax - x0), sn0b = fmaxf(0.f, x0 - smin);
  float sn1a = 0.f, sn1b = 0.f, sn2a = 0.f, sn2b = 0.f;
  if (h1) { sn1a = fmaxf(0.f, sdmax - v); sn1b = fmaxf(0.f, v - sdmin); }
  if (h2) { sn2a = fmaxf(0.f, sddmax - aa); sn2b = fmaxf(0.f, aa - sddmin); }

  const float D0n = fminf(smax, x0) + fmaxf(smin, x0);
  const float D1n = h1 ? (fminf(sdmax, v) + fmaxf(sdmin, v)) : 0.f;
  const float D2n = h2 ? (fminf(sddmax, aa) + fmaxf(sddmin, aa)) : 0.f;

  float sp0a, sp0b, sp1a = 0.f, sp1b = 0.f, sp2a = 0.f, sp2b = 0.f;
  if (it == 0) {
    const float* no = NO + (size_t)r * NO_LD;
    sp0a = fmaxf(0.f, no[256 + j]); sp0b = fmaxf(0.f, no[512 + j]);
    if (h1) { sp1a = fmaxf(0.f, no[768 + j]); sp1b = fmaxf(0.f, no[1023 + j]); }
    if (h2) { sp2a = fmaxf(0.f, no[1278 + j]); sp2b = fmaxf(0.f, no[1532 + j]); }
  } else {
    const float xp1 = xps[j + 1], xp2 = xps[j + 2];
    const float vp = (xp1 - xp0) * invT;
    const float ap = (xp2 - 2.f * xp1 + xp0) * invT2;
    sp0a = fmaxf(0.f, smax - xp0); sp0b = fmaxf(0.f, xp0 - smin);
    if (h1) { sp1a = fmaxf(0.f, sdmax - vp); sp1b = fmaxf(0.f, vp - sdmin); }
    if (h2) { sp2a = fmaxf(0.f, sddmax - ap); sp2b = fmaxf(0.f, ap - sddmin); }
  }
  const float d0a = sp0a - sn0a, d0b = sp0b - sn0b;
  const float d1a = sp1a - sn1a, d1b = sp1b - sn1b;
  const float d2a = sp2a - sn2a, d2b = sp2b - sn2b;
  double fps2 = (double)(d0a * d0a + d0b * d0b + d1a * d1a + d1b * d1b
                       + d2a * d2a + d2b * d2b);

  e1s[2 + j] = E1; e2s[2 + j] = E2; d1s[2 + j] = D1n; d2s[2 + j] = D2n;
  if (j < 2) { e1s[j] = 0.f; e2s[j] = 0.f; d1s[j] = 0.f; d2s[j] = 0.f; }
  __syncthreads();

  const float lamj = (it == 0) ? NO[(size_t)r * NO_LD + j] : lam[(size_t)r * NUMV + j];
  const float lnew = lamj - (E0 + (e1s[j + 1] - e1s[j + 2]) * invT
                                + (e2s[j] - 2.f * e2s[j + 1] + e2s[j + 2]) * invT2);
  const float dl = lamj - lnew;
  double fpl2 = (double)(dl * dl);
  lam[(size_t)r * NUMV + j] = lnew;

  const size_t primOff = (size_t)B * NUMV;
  const size_t fpOff = primOff + (size_t)QP_ITERS * B;
  if (it < QP_ITERS - 1) {
    float qn = D0n + (d1s[j + 1] - d1s[j + 2]) * invT
                   + (d2s[j] - 2.f * d2s[j + 1] + d2s[j + 2]) * invT2;
    const float vn = lnew + ss[(size_t)r * NUMV + j] + qn;
    const _Float16 vh = (_Float16)vn;
    Vh[(size_t)r * NUMV + j] = vh;
    Vl[(size_t)r * NUMV + j] = (_Float16)((vn - (float)vh) * LSCALE);
  } else {
    out[(size_t)r * NUMV + j] = x0;
  }

  for (int o = 32; o > 0; o >>= 1) {
    res2 += __shfl_down(res2, o);
    fps2 += __shfl_down(fps2, o);
    fpl2 += __shfl_down(fpl2, o);
  }
  const int wid = j >> 6, lane = j & 63;
  if (lane == 0) { red[0][wid] = res2; red[1][wid] = fps2; red[2][wid] = fpl2; }
  __syncthreads();
  if (j == 0) {
    double r2 = red[0][0] + red[0][1] + red[0][2] + red[0][3];
    double s2_ = red[1][0] + red[1][1] + red[1][2] + red[1][3];
    double l2_ = red[2][0] + red[2][1] + red[2][2] + red[2][3];
    out[primOff + (size_t)it * B + r] = sqrtf((float)r2);
    out[fpOff + (size_t)it * B + r] = sqrtf((float)s2_) + sqrtf((float)l2_);
  }
}

// ---------------- final acc_primal / acc_fixed ----------------
__global__ __launch_bounds__(256) void accum_out(float* __restrict__ out, int B)
{
  const int r = blockIdx.x * 256 + threadIdx.x;
  const size_t primOff = (size_t)B * NUMV;
  const size_t fpOff = primOff + (size_t)QP_ITERS * B;
  const size_t accPOff = fpOff + (size_t)QP_ITERS * B;
  const size_t accFOff = accPOff + (size_t)B;
  float sp = 0.f, sf = 0.f;
  for (int it = 0; it < QP_ITERS; it++) {
    sp += out[primOff + (size_t)it * B + r];
    sf += out[fpOff + (size_t)it * B + r];
  }
  out[accPOff + r] = sp * (1.f / QP_ITERS);
  out[accFOff + r] = sf * (1.f / QP_ITERS);
}

extern "C" void kernel_launch(void* const* d_in, const int* in_sizes, int n_in,
                              void* d_out, int out_size, void* d_ws, size_t ws_size,
                              hipStream_t stream)
{
  const float* inp = (const float*)d_in[0];       // [B][260]
  const float* sinit = (const float*)d_in[1];     // [B][1]
  const float* ssamp = (const float*)d_in[2];     // [B][256]
  const float* p_smax = (const float*)d_in[3];
  const float* p_smin = (const float*)d_in[4];
  const float* p_sdmax = (const float*)d_in[5];
  const float* p_sdmin = (const float*)d_in[6];
  const float* p_sddmax = (const float*)d_in[7];
  const float* p_sddmin = (const float*)d_in[8];
  const float* W1 = (const float*)d_in[11];       // [260][1024]
  const float* b1 = (const float*)d_in[12];       // [1024]
  const float* W2 = (const float*)d_in[13];       // [1024][1786]
  const float* b2 = (const float*)d_in[14];       // [1786]
  float* out = (float*)d_out;

  const int B = in_sizes[1];                      // 4096
  const int IND = in_sizes[9];                    // 260
  const int H = in_sizes[12];                     // 1024
  const int OUTN = in_sizes[14];                  // 1786

  char* ws = (char*)d_ws;
  float* NO = (float*)ws;                                      // [B][1792] fp32
  char* p = ws + (size_t)B * NO_LD * 4;                        // 29,360,128
  _Float16* hH = (_Float16*)p;                                 // [B][1024] fp16 (dead after GEMM2)
  float* Xa = (float*)p;                                       // alias: fp32 [B][256]
  float* Xb = (float*)(p + (size_t)B * NUMV * 4);              // alias: fp32 [B][256]
  char* q = p + (size_t)B * H * 2;                             // 37,748,736
  _Float16* W2T = (_Float16*)q;                                // [1786][1024] fp16 (dead after GEMM2)
  _Float16* Vh = (_Float16*)q;                                 // alias: fp16 [B][256]
  _Float16* Vl = (_Float16*)(q + (size_t)B * NUMV * 2);        // alias: fp16 [B][256]
  char* q2 = q + (size_t)OUTN * H * 2;                         // 41,406,464
  _Float16* W1T = (_Float16*)q2;                               // [1024][260] fp16 (dead after GEMM1)
  char* r3 = ws + 41943040;                                    // 41,943,040
  float* lam = (float*)r3;                                     // fp32 [B][256]
  char* r4 = r3 + (size_t)B * NUMV * 4;                        // 46,137,344
  _Float16* Gh = (_Float16*)r4;                                // [256][256] fp16
  _Float16* Gl = (_Float16*)(r4 + 131072);                     // [256][256] fp16 (x2048)
  float* zc = (float*)(r4 + 262144);                           // [256] fp32
  _Float16* Uh = (_Float16*)(r4 + 263168);                     // [256][256] fp16 (U^T)
  _Float16* Ul = (_Float16*)(r4 + 263168 + 131072);            // [256][256] fp16 (x2048)

  build_u<<<1, 256, 0, stream>>>(Uh, Ul, zc);
  {
    dim3 g(16, 8);
    gemm_g<<<g, 64, 0, stream>>>(Uh, Ul, Gh, Gl);
  }
  {
    dim3 g((IND + 31) / 32, (H + 31) / 32), blk(32, 8);
    transpose_cvt<<<g, blk, 0, stream>>>(W1, W1T, IND, H);
  }
  {
    dim3 g((H + 31) / 32, (OUTN + 31) / 32), blk(32, 8);
    transpose_cvt<<<g, blk, 0, stream>>>(W2, W2T, H, OUTN);
  }
  {
    dim3 g(B / 128, H / 128);
    mfma_gemm<true, true><<<g, 256, 0, stream>>>(inp, W1T, b1, hH, B, H, IND, IND, IND, H);
  }
  {
    dim3 g(B / 128, (OUTN + 127) / 128);
    mfma_gemm64<<<g, 256, 0, stream>>>(hH, W2T, b2, NO, B, OUTN, H, H, H, NO_LD);
  }
  init_v<<<B, 256, 0, stream>>>(NO, ssamp, p_smax, p_smin, p_sdmax, p_sdmin,
                                p_sddmax, p_sddmin, Vh, Vl, B);
  float* Xcur = Xa;
  float* Xprev = Xb;
  for (int it = 0; it < QP_ITERS; it++) {
    dim3 g(B / 16, 8);
    solve_mfma<<<g, 64, 0, stream>>>(Vh, Vl, Gh, Gl, sinit, zc, Xcur, B);
    qp_update<<<B, 256, 0, stream>>>(Xcur, Xprev, NO, lam, ssamp,
                                     p_smax, p_smin, p_sdmax, p_sdmin,
                                     p_sddmax, p_sddmin, Vh, Vl, out, B, it);
    float* t = Xcur; Xcur = Xprev; Xprev = t;
  }
  accum_out<<<B / 256, 256, 0, stream>>>(out, B);
}

// Round 15
// 230.208 us; speedup vs baseline: 1.3437x; 1.1278x over previous
//
#include <hip/hip_runtime.h>
#include <cstddef>

// learned_qp_solver: B=4096, NUM=256, NC=1530, IND=260, H=1024, OUT=1786, 5 iters.
//
//   KKT solve closed form:  x = G v + (b_eq/z0) z,  G = C^{-1} - z z^T / z0 (symmetric)
//   MLP on matrix cores: v_mfma_f32_16x16x32_f16 (K=32/BK=64, f16x8 frags).
//   Solve: scaled split-fp16 (Gl,Vl x2048 dodges fp16 denormal flush in MFMA),
//   1-wave blocks, grid (256,8).
//   G build: U = L^{-1} computed at COMPILE TIME (round-14 lesson: the on-device
//   serial fp64 recurrence was 46us of constant-load latency on one block).
//   Four constexpr 64-col quarters -> __constant__; split_u converts to split-fp16;
//   gemm_g assembles G = U^T (U^T)^T - z z^T/z0 on MFMA.
//
// ws layout (bytes), ~46.7 MB; X/V/lam aliased onto dead hH/W2T/W1T regions:
//   [0,          29360128)  NO   fp32 [B][1792]
//   [29360128,   37748736)  hH   fp16 [B][1024]  -> after GEMM2: Xa, Xb (fp32 [B][256])
//   [37748736,   41406464)  W2T  fp16 [1786][1024] -> after GEMM2: Vh, Vl (fp16 [B][256])
//   [41406464,   41938944)  W1T  fp16 [1024][260]
//   [41943040,   46137344)  lam  fp32 [B][256]
//   [46137344,   46268416)  Gh   fp16 [256][256]
//   [46268416,   46399488)  Gl   fp16 [256][256]  (scaled x2048)
//   [46399488,   46400512)  zc   fp32 [256]
//   [46400512,   46531584)  Uh   fp16 [256][256]  (U^T rows)
//   [46531584,   46662656)  Ul   fp16 [256][256]  (scaled x2048)

#define NUMV 256
#define QP_ITERS 5
#define NO_LD 1792
#define LSCALE 2048.0f
#define INV_LSCALE (1.0f / 2048.0f)

typedef _Float16 f16x4 __attribute__((ext_vector_type(4)));
typedef _Float16 f16x8 __attribute__((ext_vector_type(8)));
typedef float f32x4 __attribute__((ext_vector_type(4)));

// ---------------- compile-time pentadiagonal Cholesky tables ----------------
struct FacT {
  double invd[256];
  double l1[257];
  double l2[258];
  double z[256];
  float  zcf[256];
};

constexpr double csqrt_(double x) {
  double g = (x > 1.0) ? x : 1.0;
  for (int i = 0; i < 64; ++i) g = 0.5 * (g + x / g);
  return g;
}

constexpr FacT make_fac() {
  FacT f{};
  const double T = 0.05, a = 1.0 / (T * T), b2 = a * a;
  double c0[256] = {}, c1[255] = {}, c2[254] = {};
  double dd[256] = {}, l1[256] = {}, l2[256] = {};
  for (int j = 0; j < 256; j++) {
    double cd1 = (j == 0 || j == 255) ? 1.0 : 2.0;
    double cd2 = (j == 0 || j == 255) ? 1.0 : ((j == 1 || j == 254) ? 5.0 : 6.0);
    c0[j] = 3.0 + 2.0 * a * cd1 + 2.0 * b2 * cd2;
  }
  for (int j = 0; j < 255; j++) c1[j] = -2.0 * a + 2.0 * b2 * ((j == 0 || j == 254) ? -2.0 : -4.0);
  for (int j = 0; j < 254; j++) c2[j] = 2.0 * b2;
  dd[0] = csqrt_(c0[0]); l1[0] = 0.0; l2[0] = 0.0;
  l1[1] = c1[0] / dd[0]; l2[1] = 0.0;
  dd[1] = csqrt_(c0[1] - l1[1] * l1[1]);
  for (int j = 2; j < 256; j++) {
    l2[j] = c2[j - 2] / dd[j - 2];
    l1[j] = (c1[j - 1] - l2[j] * l1[j - 1]) / dd[j - 1];
    dd[j] = csqrt_(c0[j] - l1[j] * l1[j] - l2[j] * l2[j]);
  }
  for (int j = 0; j < 256; j++) f.invd[j] = 1.0 / dd[j];
  for (int j = 0; j < 256; j++) f.l1[j] = l1[j];
  f.l1[256] = 0.0;
  for (int j = 0; j < 256; j++) f.l2[j] = l2[j];
  f.l2[256] = 0.0; f.l2[257] = 0.0;
  double w[256] = {}, zz[256] = {};
  w[0] = 1.0 / dd[0];
  w[1] = (-l1[1] * w[0]) / dd[1];
  for (int j = 2; j < 256; j++) w[j] = (-l1[j] * w[j - 1] - l2[j] * w[j - 2]) / dd[j];
  zz[255] = w[255] / dd[255];
  zz[254] = (w[254] - l1[255] * zz[255]) / dd[254];
  for (int j = 253; j >= 0; j--)
    zz[j] = (w[j] - l1[j + 1] * zz[j + 1] - l2[j + 2] * zz[j + 2]) / dd[j];
  for (int j = 0; j < 256; j++) f.z[j] = zz[j];
  for (int j = 0; j < 256; j++) f.zcf[j] = (float)(zz[j] / zz[0]);
  return f;
}

constexpr FacT FAC_HOST = make_fac();
__constant__ FacT FAC = FAC_HOST;

// ---- compile-time U = L^{-1}: quarter (64 columns) per constexpr evaluation ----
struct UQ { float u[64][256]; };   // u[c - c0][j] = (L^{-1} e_{c})_j

constexpr UQ make_uq(int cbase) {
  UQ q{};
  const double T = 0.05, a = 1.0 / (T * T), b2 = a * a;
  double c0a[256] = {}, c1a[255] = {}, c2a[254] = {};
  double dd[256] = {}, l1[256] = {}, l2[256] = {};
  for (int j = 0; j < 256; j++) {
    double cd1 = (j == 0 || j == 255) ? 1.0 : 2.0;
    double cd2 = (j == 0 || j == 255) ? 1.0 : ((j == 1 || j == 254) ? 5.0 : 6.0);
    c0a[j] = 3.0 + 2.0 * a * cd1 + 2.0 * b2 * cd2;
  }
  for (int j = 0; j < 255; j++) c1a[j] = -2.0 * a + 2.0 * b2 * ((j == 0 || j == 254) ? -2.0 : -4.0);
  for (int j = 0; j < 254; j++) c2a[j] = 2.0 * b2;
  dd[0] = csqrt_(c0a[0]); l1[0] = 0.0; l2[0] = 0.0;
  l1[1] = c1a[0] / dd[0]; l2[1] = 0.0;
  dd[1] = csqrt_(c0a[1] - l1[1] * l1[1]);
  for (int j = 2; j < 256; j++) {
    l2[j] = c2a[j - 2] / dd[j - 2];
    l1[j] = (c1a[j - 1] - l2[j] * l1[j - 1]) / dd[j - 1];
    dd[j] = csqrt_(c0a[j] - l1[j] * l1[j] - l2[j] * l2[j]);
  }
  for (int c = cbase; c < cbase + 64; ++c) {
    double w1 = 0.0, w2 = 0.0;
    for (int j = c; j < 256; ++j) {
      const double rhs = (j == c) ? 1.0 : 0.0;
      const double wj = (rhs - l1[j] * w1 - l2[j] * w2) / dd[j];
      q.u[c - cbase][j] = (float)wj;
      w2 = w1; w1 = wj;
    }
  }
  return q;
}

constexpr UQ UQ0_H = make_uq(0);
constexpr UQ UQ1_H = make_uq(64);
constexpr UQ UQ2_H = make_uq(128);
constexpr UQ UQ3_H = make_uq(192);
__constant__ UQ UFQ0 = UQ0_H;
__constant__ UQ UFQ1 = UQ1_H;
__constant__ UQ UFQ2 = UQ2_H;
__constant__ UQ UFQ3 = UQ3_H;

// ---- split compile-time U into scaled split-fp16 Uh/Ul; write zc ----
__global__ __launch_bounds__(256) void split_u(
    _Float16* __restrict__ Uh, _Float16* __restrict__ Ul, float* __restrict__ zc)
{
  const int c = blockIdx.x, j = threadIdx.x;
  float wf;
  if (c < 64)       wf = UFQ0.u[c][j];
  else if (c < 128) wf = UFQ1.u[c - 64][j];
  else if (c < 192) wf = UFQ2.u[c - 128][j];
  else              wf = UFQ3.u[c - 192][j];
  const _Float16 h = (_Float16)wf;
  Uh[(size_t)c * 256 + j] = h;
  Ul[(size_t)c * 256 + j] = (_Float16)((wf - (float)h) * LSCALE);
  if (c == 0) zc[j] = FAC.zcf[j];
}

// ---- G = UT * UT^T - z z^T/z0 via split-fp16 MFMA; output re-split to Gh/Gl ----
__global__ __launch_bounds__(64) void gemm_g(
    const _Float16* __restrict__ Uh, const _Float16* __restrict__ Ul,
    _Float16* __restrict__ Gh, _Float16* __restrict__ Gl)
{
  const int lane = threadIdx.x;
  const int lr = lane & 15, lg = lane >> 4;
  const int m0 = blockIdx.x * 16, n0 = blockIdx.y * 32;
  f32x4 accH[2], accL[2];
#pragma unroll
  for (int nf = 0; nf < 2; nf++) { accH[nf] = (f32x4)0.0f; accL[nf] = (f32x4)0.0f; }
  const size_t arow = (size_t)(m0 + lr) * 256 + lg * 8;
#pragma unroll 2
  for (int k0 = 0; k0 < 256; k0 += 32) {
    const f16x8 ah = *reinterpret_cast<const f16x8*>(&Uh[arow + k0]);
    const f16x8 al = *reinterpret_cast<const f16x8*>(&Ul[arow + k0]);
#pragma unroll
    for (int nf = 0; nf < 2; nf++) {
      const size_t bidx = (size_t)(n0 + nf * 16 + lr) * 256 + k0 + lg * 8;
      const f16x8 bh = *reinterpret_cast<const f16x8*>(&Uh[bidx]);
      const f16x8 bl = *reinterpret_cast<const f16x8*>(&Ul[bidx]);
      accH[nf] = __builtin_amdgcn_mfma_f32_16x16x32_f16(ah, bh, accH[nf], 0, 0, 0);
      accL[nf] = __builtin_amdgcn_mfma_f32_16x16x32_f16(ah, bl, accL[nf], 0, 0, 0);
      accL[nf] = __builtin_amdgcn_mfma_f32_16x16x32_f16(al, bh, accL[nf], 0, 0, 0);
    }
  }
  const int row0 = m0 + lg * 4;
#pragma unroll
  for (int nf = 0; nf < 2; nf++) {
    const int col = n0 + nf * 16 + lr;
    const double zcd = FAC.z[col] / FAC.z[0];
#pragma unroll
    for (int r = 0; r < 4; r++) {
      const int row = row0 + r;
      const float g = accH[nf][r] + accL[nf][r] * INV_LSCALE
                    - (float)(FAC.z[row] * zcd);
      const _Float16 gh = (_Float16)g;
      Gh[(size_t)row * 256 + col] = gh;
      Gl[(size_t)row * 256 + col] = (_Float16)((g - (float)gh) * LSCALE);
    }
  }
}

// ---------------- transpose + fp32->fp16 convert: in [K][N] -> out [N][K] ----------------
__global__ __launch_bounds__(256) void transpose_cvt(
    const float* __restrict__ in, _Float16* __restrict__ out, int K, int N)
{
  __shared__ float t[32][33];
  const int bk = blockIdx.x * 32, bn = blockIdx.y * 32;
  const int x = threadIdx.x, y = threadIdx.y;
  for (int yy = y; yy < 32; yy += 8) {
    const int k = bk + yy, n = bn + x;
    t[yy][x] = (k < K && n < N) ? in[(size_t)k * N + n] : 0.f;
  }
  __syncthreads();
  for (int yy = y; yy < 32; yy += 8) {
    const int n = bn + yy, k = bk + x;
    if (n < N && k < K) out[(size_t)n * K + k] = (_Float16)t[x][yy];
  }
}

// ---------------- MFMA GEMM (BK=32, handles fp32 A + K tails): GEMM1 ----------------
template<bool A_FP32, bool OUT_H16>
__global__ __launch_bounds__(256) void mfma_gemm(
    const void* __restrict__ Av, const _Float16* __restrict__ Bt,
    const float* __restrict__ bias, void* __restrict__ Cv,
    int M, int Nv, int K, int lda, int ldk, int ldc)
{
  __shared__ _Float16 At[128][40];
  __shared__ _Float16 Bs[128][40];
  const int tid = threadIdx.x;
  const int lane = tid & 63, wid = tid >> 6;
  const int wr = wid >> 1, wc = wid & 1;
  const int lrow = lane & 15, lb = lane >> 4;
  const int m0 = blockIdx.x * 128, n0 = blockIdx.y * 128;
  const int srow = tid >> 1, skh = (tid & 1) * 16;

  f32x4 acc[4][4];
#pragma unroll
  for (int i = 0; i < 4; i++)
#pragma unroll
    for (int j = 0; j < 4; j++) acc[i][j] = (f32x4)0.0f;

  const int nsteps = (K + 31) / 32;
  for (int t = 0; t < nsteps; ++t) {
    const int k0 = t * 32;
    if (A_FP32) {
      const float* A = (const float*)Av;
#pragma unroll
      for (int i = 0; i < 4; i++) {
        const int k = k0 + skh + i * 4;
        f16x4 hv = {};
        if (k + 4 <= K) {
          const float4 v = *reinterpret_cast<const float4*>(&A[(size_t)(m0 + srow) * lda + k]);
          hv[0] = (_Float16)v.x; hv[1] = (_Float16)v.y;
          hv[2] = (_Float16)v.z; hv[3] = (_Float16)v.w;
        } else if (k < K) {
          for (int e = 0; e < 4; e++)
            if (k + e < K) hv[e] = (_Float16)A[(size_t)(m0 + srow) * lda + k + e];
        }
        *reinterpret_cast<f16x4*>(&At[srow][skh + i * 4]) = hv;
      }
    } else {
      const _Float16* A = (const _Float16*)Av;
#pragma unroll
      for (int i = 0; i < 4; i++) {
        const int k = k0 + skh + i * 4;
        f16x4 hv = {};
        if (k + 4 <= K) hv = *reinterpret_cast<const f16x4*>(&A[(size_t)(m0 + srow) * lda + k]);
        *reinterpret_cast<f16x4*>(&At[srow][skh + i * 4]) = hv;
      }
    }
    {
      const int n = n0 + srow;
#pragma unroll
      for (int i = 0; i < 4; i++) {
        const int k = k0 + skh + i * 4;
        f16x4 hv = {};
        if (n < Nv && k + 4 <= K)
          hv = *reinterpret_cast<const f16x4*>(&Bt[(size_t)n * ldk + k]);
        *reinterpret_cast<f16x4*>(&Bs[srow][skh + i * 4]) = hv;
      }
    }
    __syncthreads();
    f16x8 af[4], bf[4];
#pragma unroll
    for (int i = 0; i < 4; i++)
      af[i] = *reinterpret_cast<const f16x8*>(&At[wr * 64 + i * 16 + lrow][lb * 8]);
#pragma unroll
    for (int j = 0; j < 4; j++)
      bf[j] = *reinterpret_cast<const f16x8*>(&Bs[wc * 64 + j * 16 + lrow][lb * 8]);
#pragma unroll
    for (int i = 0; i < 4; i++)
#pragma unroll
      for (int j = 0; j < 4; j++)
        acc[i][j] = __builtin_amdgcn_mfma_f32_16x16x32_f16(af[i], bf[j], acc[i][j], 0, 0, 0);
    __syncthreads();
  }
#pragma unroll
  for (int i = 0; i < 4; i++) {
#pragma unroll
    for (int j = 0; j < 4; j++) {
      const int gcol = n0 + wc * 64 + j * 16 + lrow;
      if (gcol < Nv) {
        const float bv = bias[gcol];
#pragma unroll
        for (int r = 0; r < 4; r++) {
          const int grow = m0 + wr * 64 + i * 16 + lb * 4 + r;
          float v = acc[i][j][r] + bv;
          if (OUT_H16) {
            v = fmaxf(v, 0.f);
            ((_Float16*)Cv)[(size_t)grow * ldc + gcol] = (_Float16)v;
          } else {
            ((float*)Cv)[(size_t)grow * ldc + gcol] = v;
          }
        }
      }
    }
  }
}

// ---------------- MFMA GEMM BK=64 (fp16 A, K%64==0, fp32 out): GEMM2 ----------------
__global__ __launch_bounds__(256) void mfma_gemm64(
    const _Float16* __restrict__ A, const _Float16* __restrict__ Bt,
    const float* __restrict__ bias, float* __restrict__ C,
    int M, int Nv, int K, int lda, int ldk, int ldc)
{
  __shared__ _Float16 At[128][72];   // 144B rows: 16B-aligned, even bank spread
  __shared__ _Float16 Bs[128][72];
  const int tid = threadIdx.x;
  const int lane = tid & 63, wid = tid >> 6;
  const int wr = wid >> 1, wc = wid & 1;
  const int lrow = lane & 15, lb = lane >> 4;
  const int m0 = blockIdx.x * 128, n0 = blockIdx.y * 128;
  const int srow = tid >> 1, sh = (tid & 1) * 32;

  f32x4 acc[4][4];
#pragma unroll
  for (int i = 0; i < 4; i++)
#pragma unroll
    for (int j = 0; j < 4; j++) acc[i][j] = (f32x4)0.0f;

  const int nsteps = K >> 6;
  for (int t = 0; t < nsteps; ++t) {
    const int k0 = t * 64;
    const _Float16* asrc = &A[(size_t)(m0 + srow) * lda + k0 + sh];
#pragma unroll
    for (int i = 0; i < 4; i++)
      *reinterpret_cast<f16x8*>(&At[srow][sh + i * 8]) =
          *reinterpret_cast<const f16x8*>(asrc + i * 8);
    {
      const int n = n0 + srow;
      const _Float16* bsrc = &Bt[(size_t)n * ldk + k0 + sh];
#pragma unroll
      for (int i = 0; i < 4; i++) {
        f16x8 hv = {};
        if (n < Nv) hv = *reinterpret_cast<const f16x8*>(bsrc + i * 8);
        *reinterpret_cast<f16x8*>(&Bs[srow][sh + i * 8]) = hv;
      }
    }
    __syncthreads();
#pragma unroll
    for (int h = 0; h < 2; h++) {
      f16x8 af[4], bf[4];
#pragma unroll
      for (int i = 0; i < 4; i++)
        af[i] = *reinterpret_cast<const f16x8*>(&At[wr * 64 + i * 16 + lrow][h * 32 + lb * 8]);
#pragma unroll
      for (int j = 0; j < 4; j++)
        bf[j] = *reinterpret_cast<const f16x8*>(&Bs[wc * 64 + j * 16 + lrow][h * 32 + lb * 8]);
#pragma unroll
      for (int i = 0; i < 4; i++)
#pragma unroll
        for (int j = 0; j < 4; j++)
          acc[i][j] = __builtin_amdgcn_mfma_f32_16x16x32_f16(af[i], bf[j], acc[i][j], 0, 0, 0);
    }
    __syncthreads();
  }
#pragma unroll
  for (int i = 0; i < 4; i++) {
#pragma unroll
    for (int j = 0; j < 4; j++) {
      const int gcol = n0 + wc * 64 + j * 16 + lrow;
      if (gcol < Nv) {
        const float bv = bias[gcol];
#pragma unroll
        for (int r = 0; r < 4; r++) {
          const int grow = m0 + wr * 64 + i * 16 + lb * 4 + r;
          C[(size_t)grow * ldc + gcol] = acc[i][j][r] + bv;
        }
      }
    }
  }
}

// ---- solve via scaled split-fp16 MFMA, 1-wave blocks, tile 16x32, K=32 ----
__global__ __launch_bounds__(64) void solve_mfma(
    const _Float16* __restrict__ Vh, const _Float16* __restrict__ Vl,
    const _Float16* __restrict__ Gh, const _Float16* __restrict__ Gl,
    const float* __restrict__ beq, const float* __restrict__ zc,
    float* __restrict__ X, int B)
{
  const int lane = threadIdx.x;
  const int lr = lane & 15, lg = lane >> 4;
  const int m0 = blockIdx.x * 16, n0 = blockIdx.y * 32;
  f32x4 accH[2], accL[2];
#pragma unroll
  for (int nf = 0; nf < 2; nf++) { accH[nf] = (f32x4)0.0f; accL[nf] = (f32x4)0.0f; }
  const size_t arow = (size_t)(m0 + lr) * 256 + lg * 8;
#pragma unroll 2
  for (int k0 = 0; k0 < 256; k0 += 32) {
    const f16x8 ah = *reinterpret_cast<const f16x8*>(&Vh[arow + k0]);
    const f16x8 al = *reinterpret_cast<const f16x8*>(&Vl[arow + k0]);
#pragma unroll
    for (int nf = 0; nf < 2; nf++) {
      const size_t bidx = (size_t)(n0 + nf * 16 + lr) * 256 + k0 + lg * 8;
      const f16x8 bh = *reinterpret_cast<const f16x8*>(&Gh[bidx]);
      const f16x8 bl = *reinterpret_cast<const f16x8*>(&Gl[bidx]);
      accH[nf] = __builtin_amdgcn_mfma_f32_16x16x32_f16(ah, bh, accH[nf], 0, 0, 0);
      accL[nf] = __builtin_amdgcn_mfma_f32_16x16x32_f16(ah, bl, accL[nf], 0, 0, 0);
      accL[nf] = __builtin_amdgcn_mfma_f32_16x16x32_f16(al, bh, accL[nf], 0, 0, 0);
    }
  }
  const int orow = m0 + lg * 4;
  float bq[4];
#pragma unroll
  for (int r = 0; r < 4; r++) bq[r] = beq[orow + r];
#pragma unroll
  for (int nf = 0; nf < 2; nf++) {
    const int col = n0 + nf * 16 + lr;
    const float zv = zc[col];
#pragma unroll
    for (int r = 0; r < 4; r++)
      X[(size_t)(orow + r) * 256 + col] = accH[nf][r] + accL[nf][r] * INV_LSCALE + bq[r] * zv;
  }
}

// ---------------- initial rhs V0 = lam0 + ss + b_aug0 @ A_control (scaled split) ----
__global__ __launch_bounds__(256) void init_v(
    const float* __restrict__ NO, const float* __restrict__ ss,
    const float* __restrict__ p_smax, const float* __restrict__ p_smin,
    const float* __restrict__ p_sdmax, const float* __restrict__ p_sdmin,
    const float* __restrict__ p_sddmax, const float* __restrict__ p_sddmin,
    _Float16* __restrict__ Vh, _Float16* __restrict__ Vl, int B)
{
  __shared__ float d1s[258], d2s[258];
  const int r = blockIdx.x, j = threadIdx.x;
  const float K0 = *p_smax + *p_smin, K1 = *p_sdmax + *p_sdmin, K2 = *p_sddmax + *p_sddmin;
  const float invT = 20.f, invT2 = 400.f;
  const float* no = NO + (size_t)r * NO_LD;
  float s1 = fmaxf(0.f, no[256 + j]), s2 = fmaxf(0.f, no[512 + j]);
  float D0 = K0 - s1 + s2;
  float D1 = 0.f, D2 = 0.f;
  if (j < 255) D1 = K1 - fmaxf(0.f, no[768 + j]) + fmaxf(0.f, no[1023 + j]);
  if (j < 254) D2 = K2 - fmaxf(0.f, no[1278 + j]) + fmaxf(0.f, no[1532 + j]);
  d1s[2 + j] = D1; d2s[2 + j] = D2;
  if (j < 2) { d1s[j] = 0.f; d2s[j] = 0.f; }
  __syncthreads();
  float qn = D0 + (d1s[j + 1] - d1s[j + 2]) * invT
                + (d2s[j] - 2.f * d2s[j + 1] + d2s[j + 2]) * invT2;
  const float vn = no[j] + ss[(size_t)r * NUMV + j] + qn;
  const _Float16 vh = (_Float16)vn;
  Vh[(size_t)r * NUMV + j] = vh;
  Vl[(size_t)r * NUMV + j] = (_Float16)((vn - (float)vh) * LSCALE);
}

// ---------------- per-iteration update: one block per row (round-5 validated) ----
__global__ __launch_bounds__(256) void qp_update(
    const float* __restrict__ X, const float* __restrict__ Xp,
    const float* __restrict__ NO, float* lam,
    const float* __restrict__ ss,
    const float* __restrict__ p_smax, const float* __restrict__ p_smin,
    const float* __restrict__ p_sdmax, const float* __restrict__ p_sdmin,
    const float* __restrict__ p_sddmax, const float* __restrict__ p_sddmin,
    _Float16* __restrict__ Vh, _Float16* __restrict__ Vl,
    float* __restrict__ out, int B, int it)
{
  __shared__ float xs[258], xps[258];
  __shared__ float e1s[258], e2s[258], d1s[258], d2s[258];
  __shared__ double red[3][4];
  const int r = blockIdx.x, j = threadIdx.x;
  const float smax = *p_smax, smin = *p_smin;
  const float sdmax = *p_sdmax, sdmin = *p_sdmin;
  const float sddmax = *p_sddmax, sddmin = *p_sddmin;
  const float invT = 20.f, invT2 = 400.f;

  const float x0 = X[(size_t)r * NUMV + j];
  xs[j] = x0;
  if (j < 2) xs[256 + j] = 0.f;
  float xp0 = 0.f;
  if (it > 0) {
    xp0 = Xp[(size_t)r * NUMV + j];
    xps[j] = xp0;
    if (j < 2) xps[256 + j] = 0.f;
  }
  __syncthreads();

  const bool h1 = j < 255, h2 = j < 254;
  const float x1 = xs[j + 1], x2 = xs[j + 2];
  const float v = (x1 - x0) * invT;
  const float aa = (x2 - 2.f * x1 + x0) * invT2;

  float rv0a = fmaxf(0.f, x0 - smax), rv0b = fmaxf(0.f, smin - x0);
  float rv1a = 0.f, rv1b = 0.f, rv2a = 0.f, rv2b = 0.f;
  float E1 = 0.f, E2 = 0.f;
  const float E0 = rv0a - rv0b;
  if (h1) { rv1a = fmaxf(0.f, v - sdmax); rv1b = fmaxf(0.f, sdmin - v); E1 = rv1a - rv1b; }
  if (h2) { rv2a = fmaxf(0.f, aa - sddmax); rv2b = fmaxf(0.f, sddmin - aa); E2 = rv2a - rv2b; }
  double res2 = (double)(rv0a * rv0a + rv0b * rv0b + rv1a * rv1a + rv1b * rv1b
                       + rv2a * rv2a + rv2b * rv2b);

  const float sn0a = fmaxf(0.f, smax - x0), sn0b = fmaxf(0.f, x0 - smin);
  float sn1a = 0.f, sn1b = 0.f, sn2a = 0.f, sn2b = 0.f;
  if (h1) { sn1a = fmaxf(0.f, sdmax - v); sn1b = fmaxf(0.f, v - sdmin); }
  if (h2) { sn2a = fmaxf(0.f, sddmax - aa); sn2b = fmaxf(0.f, aa - sddmin); }

  const float D0n = fminf(smax, x0) + fmaxf(smin, x0);
  const float D1n = h1 ? (fminf(sdmax, v) + fmaxf(sdmin, v)) : 0.f;
  const float D2n = h2 ? (fminf(sddmax, aa) + fmaxf(sddmin, aa)) : 0.f;

  float sp0a, sp0b, sp1a = 0.f, sp1b = 0.f, sp2a = 0.f, sp2b = 0.f;
  if (it == 0) {
    const float* no = NO + (size_t)r * NO_LD;
    sp0a = fmaxf(0.f, no[256 + j]); sp0b = fmaxf(0.f, no[512 + j]);
    if (h1) { sp1a = fmaxf(0.f, no[768 + j]); sp1b = fmaxf(0.f, no[1023 + j]); }
    if (h2) { sp2a = fmaxf(0.f, no[1278 + j]); sp2b = fmaxf(0.f, no[1532 + j]); }
  } else {
    const float xp1 = xps[j + 1], xp2 = xps[j + 2];
    const float vp = (xp1 - xp0) * invT;
    const float ap = (xp2 - 2.f * xp1 + xp0) * invT2;
    sp0a = fmaxf(0.f, smax - xp0); sp0b = fmaxf(0.f, xp0 - smin);
    if (h1) { sp1a = fmaxf(0.f, sdmax - vp); sp1b = fmaxf(0.f, vp - sdmin); }
    if (h2) { sp2a = fmaxf(0.f, sddmax - ap); sp2b = fmaxf(0.f, ap - sddmin); }
  }
  const float d0a = sp0a - sn0a, d0b = sp0b - sn0b;
  const float d1a = sp1a - sn1a, d1b = sp1b - sn1b;
  const float d2a = sp2a - sn2a, d2b = sp2b - sn2b;
  double fps2 = (double)(d0a * d0a + d0b * d0b + d1a * d1a + d1b * d1b
                       + d2a * d2a + d2b * d2b);

  e1s[2 + j] = E1; e2s[2 + j] = E2; d1s[2 + j] = D1n; d2s[2 + j] = D2n;
  if (j < 2) { e1s[j] = 0.f; e2s[j] = 0.f; d1s[j] = 0.f; d2s[j] = 0.f; }
  __syncthreads();

  const float lamj = (it == 0) ? NO[(size_t)r * NO_LD + j] : lam[(size_t)r * NUMV + j];
  const float lnew = lamj - (E0 + (e1s[j + 1] - e1s[j + 2]) * invT
                                + (e2s[j] - 2.f * e2s[j + 1] + e2s[j + 2]) * invT2);
  const float dl = lamj - lnew;
  double fpl2 = (double)(dl * dl);
  lam[(size_t)r * NUMV + j] = lnew;

  const size_t primOff = (size_t)B * NUMV;
  const size_t fpOff = primOff + (size_t)QP_ITERS * B;
  if (it < QP_ITERS - 1) {
    float qn = D0n + (d1s[j + 1] - d1s[j + 2]) * invT
                   + (d2s[j] - 2.f * d2s[j + 1] + d2s[j + 2]) * invT2;
    const float vn = lnew + ss[(size_t)r * NUMV + j] + qn;
    const _Float16 vh = (_Float16)vn;
    Vh[(size_t)r * NUMV + j] = vh;
    Vl[(size_t)r * NUMV + j] = (_Float16)((vn - (float)vh) * LSCALE);
  } else {
    out[(size_t)r * NUMV + j] = x0;
  }

  for (int o = 32; o > 0; o >>= 1) {
    res2 += __shfl_down(res2, o);
    fps2 += __shfl_down(fps2, o);
    fpl2 += __shfl_down(fpl2, o);
  }
  const int wid = j >> 6, lane = j & 63;
  if (lane == 0) { red[0][wid] = res2; red[1][wid] = fps2; red[2][wid] = fpl2; }
  __syncthreads();
  if (j == 0) {
    double r2 = red[0][0] + red[0][1] + red[0][2] + red[0][3];
    double s2_ = red[1][0] + red[1][1] + red[1][2] + red[1][3];
    double l2_ = red[2][0] + red[2][1] + red[2][2] + red[2][3];
    out[primOff + (size_t)it * B + r] = sqrtf((float)r2);
    out[fpOff + (size_t)it * B + r] = sqrtf((float)s2_) + sqrtf((float)l2_);
  }
}

// ---------------- final acc_primal / acc_fixed ----------------
__global__ __launch_bounds__(256) void accum_out(float* __restrict__ out, int B)
{
  const int r = blockIdx.x * 256 + threadIdx.x;
  const size_t primOff = (size_t)B * NUMV;
  const size_t fpOff = primOff + (size_t)QP_ITERS * B;
  const size_t accPOff = fpOff + (size_t)QP_ITERS * B;
  const size_t accFOff = accPOff + (size_t)B;
  float sp = 0.f, sf = 0.f;
  for (int it = 0; it < QP_ITERS; it++) {
    sp += out[primOff + (size_t)it * B + r];
    sf += out[fpOff + (size_t)it * B + r];
  }
  out[accPOff + r] = sp * (1.f / QP_ITERS);
  out[accFOff + r] = sf * (1.f / QP_ITERS);
}

extern "C" void kernel_launch(void* const* d_in, const int* in_sizes, int n_in,
                              void* d_out, int out_size, void* d_ws, size_t ws_size,
                              hipStream_t stream)
{
  const float* inp = (const float*)d_in[0];       // [B][260]
  const float* sinit = (const float*)d_in[1];     // [B][1]
  const float* ssamp = (const float*)d_in[2];     // [B][256]
  const float* p_smax = (const float*)d_in[3];
  const float* p_smin = (const float*)d_in[4];
  const float* p_sdmax = (const float*)d_in[5];
  const float* p_sdmin = (const float*)d_in[6];
  const float* p_sddmax = (const float*)d_in[7];
  const float* p_sddmin = (const float*)d_in[8];
  const float* W1 = (const float*)d_in[11];       // [260][1024]
  const float* b1 = (const float*)d_in[12];       // [1024]
  const float* W2 = (const float*)d_in[13];       // [1024][1786]
  const float* b2 = (const float*)d_in[14];       // [1786]
  float* out = (float*)d_out;

  const int B = in_sizes[1];                      // 4096
  const int IND = in_sizes[9];                    // 260
  const int H = in_sizes[12];                     // 1024
  const int OUTN = in_sizes[14];                  // 1786

  char* ws = (char*)d_ws;
  float* NO = (float*)ws;                                      // [B][1792] fp32
  char* p = ws + (size_t)B * NO_LD * 4;                        // 29,360,128
  _Float16* hH = (_Float16*)p;                                 // [B][1024] fp16 (dead after GEMM2)
  float* Xa = (float*)p;                                       // alias: fp32 [B][256]
  float* Xb = (float*)(p + (size_t)B * NUMV * 4);              // alias: fp32 [B][256]
  char* q = p + (size_t)B * H * 2;                             // 37,748,736
  _Float16* W2T = (_Float16*)q;                                // [1786][1024] fp16 (dead after GEMM2)
  _Float16* Vh = (_Float16*)q;                                 // alias: fp16 [B][256]
  _Float16* Vl = (_Float16*)(q + (size_t)B * NUMV * 2);        // alias: fp16 [B][256]
  char* q2 = q + (size_t)OUTN * H * 2;                         // 41,406,464
  _Float16* W1T = (_Float16*)q2;                               // [1024][260] fp16 (dead after GEMM1)
  char* r3 = ws + 41943040;                                    // 41,943,040
  float* lam = (float*)r3;                                     // fp32 [B][256]
  char* r4 = r3 + (size_t)B * NUMV * 4;                        // 46,137,344
  _Float16* Gh = (_Float16*)r4;                                // [256][256] fp16
  _Float16* Gl = (_Float16*)(r4 + 131072);                     // [256][256] fp16 (x2048)
  float* zc = (float*)(r4 + 262144);                           // [256] fp32
  _Float16* Uh = (_Float16*)(r4 + 263168);                     // [256][256] fp16 (U^T)
  _Float16* Ul = (_Float16*)(r4 + 263168 + 131072);            // [256][256] fp16 (x2048)

  split_u<<<256, 256, 0, stream>>>(Uh, Ul, zc);
  {
    dim3 g(16, 8);
    gemm_g<<<g, 64, 0, stream>>>(Uh, Ul, Gh, Gl);
  }
  {
    dim3 g((IND + 31) / 32, (H + 31) / 32), blk(32, 8);
    transpose_cvt<<<g, blk, 0, stream>>>(W1, W1T, IND, H);
  }
  {
    dim3 g((H + 31) / 32, (OUTN + 31) / 32), blk(32, 8);
    transpose_cvt<<<g, blk, 0, stream>>>(W2, W2T, H, OUTN);
  }
  {
    dim3 g(B / 128, H / 128);
    mfma_gemm<true, true><<<g, 256, 0, stream>>>(inp, W1T, b1, hH, B, H, IND, IND, IND, H);
  }
  {
    dim3 g(B / 128, (OUTN + 127) / 128);
    mfma_gemm64<<<g, 256, 0, stream>>>(hH, W2T, b2, NO, B, OUTN, H, H, H, NO_LD);
  }
  init_v<<<B, 256, 0, stream>>>(NO, ssamp, p_smax, p_smin, p_sdmax, p_sdmin,
                                p_sddmax, p_sddmin, Vh, Vl, B);
  float* Xcur = Xa;
  float* Xprev = Xb;
  for (int it = 0; it < QP_ITERS; it++) {
    dim3 g(B / 16, 8);
    solve_mfma<<<g, 64, 0, stream>>>(Vh, Vl, Gh, Gl, sinit, zc, Xcur, B);
    qp_update<<<B, 256, 0, stream>>>(Xcur, Xprev, NO, lam, ssamp,
                                     p_smax, p_smin, p_sdmax, p_sdmin,
                                     p_sddmax, p_sddmin, Vh, Vl, out, B, it);
    float* t = Xcur; Xcur = Xprev; Xprev = t;
  }
  accum_out<<<B / 256, 256, 0, stream>>>(out, B);
}

// Round 16
// 215.232 us; speedup vs baseline: 1.4372x; 1.0696x over previous
//
#include <hip/hip_runtime.h>
#include <cstddef>

// learned_qp_solver: B=4096, NUM=256, NC=1530, IND=260, H=1024, OUT=1786, 5 iters.
//
//   KKT solve closed form:  x = G v + (b_eq/z0) z,  G = C^{-1} - z z^T / z0 (symmetric)
//   MLP on matrix cores: v_mfma_f32_16x16x32_f16 (BK=32 GEMM1 / BK=64 GEMM2).
//   Solve: scaled split-fp16 (Gl,Vl x2048 dodge fp16 denormal flush in MFMA).
//   G build: U = L^{-1} at COMPILE TIME (constexpr quarters); gemm_g on MFMA.
//   Round-16: solve+update FUSED per iteration (qp_iter_fused): 256 blocks x
//   8 waves, block = 16 rows; wave w = col-block w via validated MFMA path;
//   x in LDS; round-8-validated local-recompute stencil; accum folded into it=4.
//   17 -> 12 dispatches; X crosses global once/iter.
//
// ws layout (bytes), ~46.7 MB; X/V/lam aliased onto dead hH/W2T/W1T regions:
//   [0,          29360128)  NO   fp32 [B][1792]
//   [29360128,   37748736)  hH   fp16 [B][1024]  -> after GEMM2: Xa, Xb (fp32 [B][256])
//   [37748736,   41406464)  W2T  fp16 [1786][1024] -> after GEMM2: Vh, Vl (fp16 [B][256])
//   [41406464,   41938944)  W1T  fp16 [1024][260]
//   [41943040,   46137344)  lam  fp32 [B][256]
//   [46137344,   46268416)  Gh   fp16 [256][256]
//   [46268416,   46399488)  Gl   fp16 [256][256]  (scaled x2048)
//   [46399488,   46400512)  zc   fp32 [256]
//   [46400512,   46531584)  Uh   fp16 [256][256]
//   [46531584,   46662656)  Ul   fp16 [256][256]  (scaled x2048)

#define NUMV 256
#define QP_ITERS 5
#define NO_LD 1792
#define LSCALE 2048.0f
#define INV_LSCALE (1.0f / 2048.0f)

typedef _Float16 f16x4 __attribute__((ext_vector_type(4)));
typedef _Float16 f16x8 __attribute__((ext_vector_type(8)));
typedef float f32x4 __attribute__((ext_vector_type(4)));

// ---------------- compile-time pentadiagonal Cholesky tables ----------------
struct FacT {
  double invd[256];
  double l1[257];
  double l2[258];
  double z[256];
  float  zcf[256];
};

constexpr double csqrt_(double x) {
  double g = (x > 1.0) ? x : 1.0;
  for (int i = 0; i < 64; ++i) g = 0.5 * (g + x / g);
  return g;
}

constexpr FacT make_fac() {
  FacT f{};
  const double T = 0.05, a = 1.0 / (T * T), b2 = a * a;
  double c0[256] = {}, c1[255] = {}, c2[254] = {};
  double dd[256] = {}, l1[256] = {}, l2[256] = {};
  for (int j = 0; j < 256; j++) {
    double cd1 = (j == 0 || j == 255) ? 1.0 : 2.0;
    double cd2 = (j == 0 || j == 255) ? 1.0 : ((j == 1 || j == 254) ? 5.0 : 6.0);
    c0[j] = 3.0 + 2.0 * a * cd1 + 2.0 * b2 * cd2;
  }
  for (int j = 0; j < 255; j++) c1[j] = -2.0 * a + 2.0 * b2 * ((j == 0 || j == 254) ? -2.0 : -4.0);
  for (int j = 0; j < 254; j++) c2[j] = 2.0 * b2;
  dd[0] = csqrt_(c0[0]); l1[0] = 0.0; l2[0] = 0.0;
  l1[1] = c1[0] / dd[0]; l2[1] = 0.0;
  dd[1] = csqrt_(c0[1] - l1[1] * l1[1]);
  for (int j = 2; j < 256; j++) {
    l2[j] = c2[j - 2] / dd[j - 2];
    l1[j] = (c1[j - 1] - l2[j] * l1[j - 1]) / dd[j - 1];
    dd[j] = csqrt_(c0[j] - l1[j] * l1[j] - l2[j] * l2[j]);
  }
  for (int j = 0; j < 256; j++) f.invd[j] = 1.0 / dd[j];
  for (int j = 0; j < 256; j++) f.l1[j] = l1[j];
  f.l1[256] = 0.0;
  for (int j = 0; j < 256; j++) f.l2[j] = l2[j];
  f.l2[256] = 0.0; f.l2[257] = 0.0;
  double w[256] = {}, zz[256] = {};
  w[0] = 1.0 / dd[0];
  w[1] = (-l1[1] * w[0]) / dd[1];
  for (int j = 2; j < 256; j++) w[j] = (-l1[j] * w[j - 1] - l2[j] * w[j - 2]) / dd[j];
  zz[255] = w[255] / dd[255];
  zz[254] = (w[254] - l1[255] * zz[255]) / dd[254];
  for (int j = 253; j >= 0; j--)
    zz[j] = (w[j] - l1[j + 1] * zz[j + 1] - l2[j + 2] * zz[j + 2]) / dd[j];
  for (int j = 0; j < 256; j++) f.z[j] = zz[j];
  for (int j = 0; j < 256; j++) f.zcf[j] = (float)(zz[j] / zz[0]);
  return f;
}

constexpr FacT FAC_HOST = make_fac();
__constant__ FacT FAC = FAC_HOST;

// ---- compile-time U = L^{-1}: quarter (64 columns) per constexpr evaluation ----
struct UQ { float u[64][256]; };

constexpr UQ make_uq(int cbase) {
  UQ q{};
  const double T = 0.05, a = 1.0 / (T * T), b2 = a * a;
  double c0a[256] = {}, c1a[255] = {}, c2a[254] = {};
  double dd[256] = {}, l1[256] = {}, l2[256] = {};
  for (int j = 0; j < 256; j++) {
    double cd1 = (j == 0 || j == 255) ? 1.0 : 2.0;
    double cd2 = (j == 0 || j == 255) ? 1.0 : ((j == 1 || j == 254) ? 5.0 : 6.0);
    c0a[j] = 3.0 + 2.0 * a * cd1 + 2.0 * b2 * cd2;
  }
  for (int j = 0; j < 255; j++) c1a[j] = -2.0 * a + 2.0 * b2 * ((j == 0 || j == 254) ? -2.0 : -4.0);
  for (int j = 0; j < 254; j++) c2a[j] = 2.0 * b2;
  dd[0] = csqrt_(c0a[0]); l1[0] = 0.0; l2[0] = 0.0;
  l1[1] = c1a[0] / dd[0]; l2[1] = 0.0;
  dd[1] = csqrt_(c0a[1] - l1[1] * l1[1]);
  for (int j = 2; j < 256; j++) {
    l2[j] = c2a[j - 2] / dd[j - 2];
    l1[j] = (c1a[j - 1] - l2[j] * l1[j - 1]) / dd[j - 1];
    dd[j] = csqrt_(c0a[j] - l1[j] * l1[j] - l2[j] * l2[j]);
  }
  for (int c = cbase; c < cbase + 64; ++c) {
    double w1 = 0.0, w2 = 0.0;
    for (int j = c; j < 256; ++j) {
      const double rhs = (j == c) ? 1.0 : 0.0;
      const double wj = (rhs - l1[j] * w1 - l2[j] * w2) / dd[j];
      q.u[c - cbase][j] = (float)wj;
      w2 = w1; w1 = wj;
    }
  }
  return q;
}

constexpr UQ UQ0_H = make_uq(0);
constexpr UQ UQ1_H = make_uq(64);
constexpr UQ UQ2_H = make_uq(128);
constexpr UQ UQ3_H = make_uq(192);
__constant__ UQ UFQ0 = UQ0_H;
__constant__ UQ UFQ1 = UQ1_H;
__constant__ UQ UFQ2 = UQ2_H;
__constant__ UQ UFQ3 = UQ3_H;

// ---- split compile-time U into scaled split-fp16 Uh/Ul; write zc ----
__global__ __launch_bounds__(256) void split_u(
    _Float16* __restrict__ Uh, _Float16* __restrict__ Ul, float* __restrict__ zc)
{
  const int c = blockIdx.x, j = threadIdx.x;
  float wf;
  if (c < 64)       wf = UFQ0.u[c][j];
  else if (c < 128) wf = UFQ1.u[c - 64][j];
  else if (c < 192) wf = UFQ2.u[c - 128][j];
  else              wf = UFQ3.u[c - 192][j];
  const _Float16 h = (_Float16)wf;
  Uh[(size_t)c * 256 + j] = h;
  Ul[(size_t)c * 256 + j] = (_Float16)((wf - (float)h) * LSCALE);
  if (c == 0) zc[j] = FAC.zcf[j];
}

// ---- G = UT * UT^T - z z^T/z0 via split-fp16 MFMA; output re-split to Gh/Gl ----
__global__ __launch_bounds__(64) void gemm_g(
    const _Float16* __restrict__ Uh, const _Float16* __restrict__ Ul,
    _Float16* __restrict__ Gh, _Float16* __restrict__ Gl)
{
  const int lane = threadIdx.x;
  const int lr = lane & 15, lg = lane >> 4;
  const int m0 = blockIdx.x * 16, n0 = blockIdx.y * 32;
  f32x4 accH[2], accL[2];
#pragma unroll
  for (int nf = 0; nf < 2; nf++) { accH[nf] = (f32x4)0.0f; accL[nf] = (f32x4)0.0f; }
  const size_t arow = (size_t)(m0 + lr) * 256 + lg * 8;
#pragma unroll 2
  for (int k0 = 0; k0 < 256; k0 += 32) {
    const f16x8 ah = *reinterpret_cast<const f16x8*>(&Uh[arow + k0]);
    const f16x8 al = *reinterpret_cast<const f16x8*>(&Ul[arow + k0]);
#pragma unroll
    for (int nf = 0; nf < 2; nf++) {
      const size_t bidx = (size_t)(n0 + nf * 16 + lr) * 256 + k0 + lg * 8;
      const f16x8 bh = *reinterpret_cast<const f16x8*>(&Uh[bidx]);
      const f16x8 bl = *reinterpret_cast<const f16x8*>(&Ul[bidx]);
      accH[nf] = __builtin_amdgcn_mfma_f32_16x16x32_f16(ah, bh, accH[nf], 0, 0, 0);
      accL[nf] = __builtin_amdgcn_mfma_f32_16x16x32_f16(ah, bl, accL[nf], 0, 0, 0);
      accL[nf] = __builtin_amdgcn_mfma_f32_16x16x32_f16(al, bh, accL[nf], 0, 0, 0);
    }
  }
  const int row0 = m0 + lg * 4;
#pragma unroll
  for (int nf = 0; nf < 2; nf++) {
    const int col = n0 + nf * 16 + lr;
    const double zcd = FAC.z[col] / FAC.z[0];
#pragma unroll
    for (int r = 0; r < 4; r++) {
      const int row = row0 + r;
      const float g = accH[nf][r] + accL[nf][r] * INV_LSCALE
                    - (float)(FAC.z[row] * zcd);
      const _Float16 gh = (_Float16)g;
      Gh[(size_t)row * 256 + col] = gh;
      Gl[(size_t)row * 256 + col] = (_Float16)((g - (float)gh) * LSCALE);
    }
  }
}

// ---------------- transpose + fp32->fp16 convert: in [K][N] -> out [N][K] ----------------
__global__ __launch_bounds__(256) void transpose_cvt(
    const float* __restrict__ in, _Float16* __restrict__ out, int K, int N)
{
  __shared__ float t[32][33];
  const int bk = blockIdx.x * 32, bn = blockIdx.y * 32;
  const int x = threadIdx.x, y = threadIdx.y;
  for (int yy = y; yy < 32; yy += 8) {
    const int k = bk + yy, n = bn + x;
    t[yy][x] = (k < K && n < N) ? in[(size_t)k * N + n] : 0.f;
  }
  __syncthreads();
  for (int yy = y; yy < 32; yy += 8) {
    const int n = bn + yy, k = bk + x;
    if (n < N && k < K) out[(size_t)n * K + k] = (_Float16)t[x][yy];
  }
}

// ---------------- MFMA GEMM (BK=32, handles fp32 A + K tails): GEMM1 ----------------
template<bool A_FP32, bool OUT_H16>
__global__ __launch_bounds__(256) void mfma_gemm(
    const void* __restrict__ Av, const _Float16* __restrict__ Bt,
    const float* __restrict__ bias, void* __restrict__ Cv,
    int M, int Nv, int K, int lda, int ldk, int ldc)
{
  __shared__ _Float16 At[128][40];
  __shared__ _Float16 Bs[128][40];
  const int tid = threadIdx.x;
  const int lane = tid & 63, wid = tid >> 6;
  const int wr = wid >> 1, wc = wid & 1;
  const int lrow = lane & 15, lb = lane >> 4;
  const int m0 = blockIdx.x * 128, n0 = blockIdx.y * 128;
  const int srow = tid >> 1, skh = (tid & 1) * 16;

  f32x4 acc[4][4];
#pragma unroll
  for (int i = 0; i < 4; i++)
#pragma unroll
    for (int j = 0; j < 4; j++) acc[i][j] = (f32x4)0.0f;

  const int nsteps = (K + 31) / 32;
  for (int t = 0; t < nsteps; ++t) {
    const int k0 = t * 32;
    if (A_FP32) {
      const float* A = (const float*)Av;
#pragma unroll
      for (int i = 0; i < 4; i++) {
        const int k = k0 + skh + i * 4;
        f16x4 hv = {};
        if (k + 4 <= K) {
          const float4 v = *reinterpret_cast<const float4*>(&A[(size_t)(m0 + srow) * lda + k]);
          hv[0] = (_Float16)v.x; hv[1] = (_Float16)v.y;
          hv[2] = (_Float16)v.z; hv[3] = (_Float16)v.w;
        } else if (k < K) {
          for (int e = 0; e < 4; e++)
            if (k + e < K) hv[e] = (_Float16)A[(size_t)(m0 + srow) * lda + k + e];
        }
        *reinterpret_cast<f16x4*>(&At[srow][skh + i * 4]) = hv;
      }
    } else {
      const _Float16* A = (const _Float16*)Av;
#pragma unroll
      for (int i = 0; i < 4; i++) {
        const int k = k0 + skh + i * 4;
        f16x4 hv = {};
        if (k + 4 <= K) hv = *reinterpret_cast<const f16x4*>(&A[(size_t)(m0 + srow) * lda + k]);
        *reinterpret_cast<f16x4*>(&At[srow][skh + i * 4]) = hv;
      }
    }
    {
      const int n = n0 + srow;
#pragma unroll
      for (int i = 0; i < 4; i++) {
        const int k = k0 + skh + i * 4;
        f16x4 hv = {};
        if (n < Nv && k + 4 <= K)
          hv = *reinterpret_cast<const f16x4*>(&Bt[(size_t)n * ldk + k]);
        *reinterpret_cast<f16x4*>(&Bs[srow][skh + i * 4]) = hv;
      }
    }
    __syncthreads();
    f16x8 af[4], bf[4];
#pragma unroll
    for (int i = 0; i < 4; i++)
      af[i] = *reinterpret_cast<const f16x8*>(&At[wr * 64 + i * 16 + lrow][lb * 8]);
#pragma unroll
    for (int j = 0; j < 4; j++)
      bf[j] = *reinterpret_cast<const f16x8*>(&Bs[wc * 64 + j * 16 + lrow][lb * 8]);
#pragma unroll
    for (int i = 0; i < 4; i++)
#pragma unroll
      for (int j = 0; j < 4; j++)
        acc[i][j] = __builtin_amdgcn_mfma_f32_16x16x32_f16(af[i], bf[j], acc[i][j], 0, 0, 0);
    __syncthreads();
  }
#pragma unroll
  for (int i = 0; i < 4; i++) {
#pragma unroll
    for (int j = 0; j < 4; j++) {
      const int gcol = n0 + wc * 64 + j * 16 + lrow;
      if (gcol < Nv) {
        const float bv = bias[gcol];
#pragma unroll
        for (int r = 0; r < 4; r++) {
          const int grow = m0 + wr * 64 + i * 16 + lb * 4 + r;
          float v = acc[i][j][r] + bv;
          if (OUT_H16) {
            v = fmaxf(v, 0.f);
            ((_Float16*)Cv)[(size_t)grow * ldc + gcol] = (_Float16)v;
          } else {
            ((float*)Cv)[(size_t)grow * ldc + gcol] = v;
          }
        }
      }
    }
  }
}

// ---------------- MFMA GEMM BK=64 (fp16 A, K%64==0, fp32 out): GEMM2 ----------------
__global__ __launch_bounds__(256) void mfma_gemm64(
    const _Float16* __restrict__ A, const _Float16* __restrict__ Bt,
    const float* __restrict__ bias, float* __restrict__ C,
    int M, int Nv, int K, int lda, int ldk, int ldc)
{
  __shared__ _Float16 At[128][72];
  __shared__ _Float16 Bs[128][72];
  const int tid = threadIdx.x;
  const int lane = tid & 63, wid = tid >> 6;
  const int wr = wid >> 1, wc = wid & 1;
  const int lrow = lane & 15, lb = lane >> 4;
  const int m0 = blockIdx.x * 128, n0 = blockIdx.y * 128;
  const int srow = tid >> 1, sh = (tid & 1) * 32;

  f32x4 acc[4][4];
#pragma unroll
  for (int i = 0; i < 4; i++)
#pragma unroll
    for (int j = 0; j < 4; j++) acc[i][j] = (f32x4)0.0f;

  const int nsteps = K >> 6;
  for (int t = 0; t < nsteps; ++t) {
    const int k0 = t * 64;
    const _Float16* asrc = &A[(size_t)(m0 + srow) * lda + k0 + sh];
#pragma unroll
    for (int i = 0; i < 4; i++)
      *reinterpret_cast<f16x8*>(&At[srow][sh + i * 8]) =
          *reinterpret_cast<const f16x8*>(asrc + i * 8);
    {
      const int n = n0 + srow;
      const _Float16* bsrc = &Bt[(size_t)n * ldk + k0 + sh];
#pragma unroll
      for (int i = 0; i < 4; i++) {
        f16x8 hv = {};
        if (n < Nv) hv = *reinterpret_cast<const f16x8*>(bsrc + i * 8);
        *reinterpret_cast<f16x8*>(&Bs[srow][sh + i * 8]) = hv;
      }
    }
    __syncthreads();
#pragma unroll
    for (int h = 0; h < 2; h++) {
      f16x8 af[4], bf[4];
#pragma unroll
      for (int i = 0; i < 4; i++)
        af[i] = *reinterpret_cast<const f16x8*>(&At[wr * 64 + i * 16 + lrow][h * 32 + lb * 8]);
#pragma unroll
      for (int j = 0; j < 4; j++)
        bf[j] = *reinterpret_cast<const f16x8*>(&Bs[wc * 64 + j * 16 + lrow][h * 32 + lb * 8]);
#pragma unroll
      for (int i = 0; i < 4; i++)
#pragma unroll
        for (int j = 0; j < 4; j++)
          acc[i][j] = __builtin_amdgcn_mfma_f32_16x16x32_f16(af[i], bf[j], acc[i][j], 0, 0, 0);
    }
    __syncthreads();
  }
#pragma unroll
  for (int i = 0; i < 4; i++) {
#pragma unroll
    for (int j = 0; j < 4; j++) {
      const int gcol = n0 + wc * 64 + j * 16 + lrow;
      if (gcol < Nv) {
        const float bv = bias[gcol];
#pragma unroll
        for (int r = 0; r < 4; r++) {
          const int grow = m0 + wr * 64 + i * 16 + lb * 4 + r;
          C[(size_t)grow * ldc + gcol] = acc[i][j][r] + bv;
        }
      }
    }
  }
}

// ---------------- initial rhs V0 = lam0 + ss + b_aug0 @ A_control (scaled split) ----
__global__ __launch_bounds__(256) void init_v(
    const float* __restrict__ NO, const float* __restrict__ ss,
    const float* __restrict__ p_smax, const float* __restrict__ p_smin,
    const float* __restrict__ p_sdmax, const float* __restrict__ p_sdmin,
    const float* __restrict__ p_sddmax, const float* __restrict__ p_sddmin,
    _Float16* __restrict__ Vh, _Float16* __restrict__ Vl, int B)
{
  __shared__ float d1s[258], d2s[258];
  const int r = blockIdx.x, j = threadIdx.x;
  const float K0 = *p_smax + *p_smin, K1 = *p_sdmax + *p_sdmin, K2 = *p_sddmax + *p_sddmin;
  const float invT = 20.f, invT2 = 400.f;
  const float* no = NO + (size_t)r * NO_LD;
  float s1 = fmaxf(0.f, no[256 + j]), s2 = fmaxf(0.f, no[512 + j]);
  float D0 = K0 - s1 + s2;
  float D1 = 0.f, D2 = 0.f;
  if (j < 255) D1 = K1 - fmaxf(0.f, no[768 + j]) + fmaxf(0.f, no[1023 + j]);
  if (j < 254) D2 = K2 - fmaxf(0.f, no[1278 + j]) + fmaxf(0.f, no[1532 + j]);
  d1s[2 + j] = D1; d2s[2 + j] = D2;
  if (j < 2) { d1s[j] = 0.f; d2s[j] = 0.f; }
  __syncthreads();
  float qn = D0 + (d1s[j + 1] - d1s[j + 2]) * invT
                + (d2s[j] - 2.f * d2s[j + 1] + d2s[j + 2]) * invT2;
  const float vn = no[j] + ss[(size_t)r * NUMV + j] + qn;
  const _Float16 vh = (_Float16)vn;
  Vh[(size_t)r * NUMV + j] = vh;
  Vl[(size_t)r * NUMV + j] = (_Float16)((vn - (float)vh) * LSCALE);
}

// ---- FUSED per-iteration kernel: MFMA solve (8 waves x 16x32 tiles) + update ----
// Block = 16 rows, 512 threads. Wave w computes cols [32w, 32w+32) of x into LDS;
// after barrier, thread (j = tid&255, half = tid>>8) updates rows half*8..+7 at
// col j using round-8-validated local-recompute stencils. V updated in place
// (block touches only its own rows). X written to Xo for next iter's s_prev.
__global__ __launch_bounds__(512) void qp_iter_fused(
    _Float16* __restrict__ Vh, _Float16* __restrict__ Vl,
    const _Float16* __restrict__ Gh, const _Float16* __restrict__ Gl,
    const float* __restrict__ beq, const float* __restrict__ zc,
    const float* __restrict__ Xp, float* __restrict__ Xo,
    const float* __restrict__ NO, float* __restrict__ lam,
    const float* __restrict__ ss,
    const float* __restrict__ p_smax, const float* __restrict__ p_smin,
    const float* __restrict__ p_sdmax, const float* __restrict__ p_sdmin,
    const float* __restrict__ p_sddmax, const float* __restrict__ p_sddmin,
    float* __restrict__ out, int B, int it)
{
  __shared__ float xs[16][264];
  __shared__ float xps[16][264];
  __shared__ float red[8][8][3];
  const int tid = threadIdx.x;
  const int wave = tid >> 6, lane = tid & 63;
  const int lr = lane & 15, lg = lane >> 4;
  const int m0 = blockIdx.x * 16;
  const int n0 = wave * 32;

  // stage Xprev + pads
  if (it > 0) {
    for (int i = tid; i < 16 * 256; i += 512) {
      const int rl = i >> 8, c = i & 255;
      xps[rl][c + 2] = Xp[(size_t)(m0 + rl) * NUMV + c];
    }
  }
  if (tid < 16) {
    xps[tid][0] = 0.f; xps[tid][1] = 0.f; xps[tid][258] = 0.f; xps[tid][259] = 0.f;
    xs[tid][0] = 0.f;  xs[tid][1] = 0.f;  xs[tid][258] = 0.f;  xs[tid][259] = 0.f;
  }

  // ---- Phase 1: MFMA solve (validated split-fp16 path) ----
  f32x4 accH[2], accL[2];
#pragma unroll
  for (int nf = 0; nf < 2; nf++) { accH[nf] = (f32x4)0.0f; accL[nf] = (f32x4)0.0f; }
  const size_t arow = (size_t)(m0 + lr) * 256 + lg * 8;
#pragma unroll 2
  for (int k0 = 0; k0 < 256; k0 += 32) {
    const f16x8 ah = *reinterpret_cast<const f16x8*>(&Vh[arow + k0]);
    const f16x8 al = *reinterpret_cast<const f16x8*>(&Vl[arow + k0]);
#pragma unroll
    for (int nf = 0; nf < 2; nf++) {
      const size_t bidx = (size_t)(n0 + nf * 16 + lr) * 256 + k0 + lg * 8;
      const f16x8 bh = *reinterpret_cast<const f16x8*>(&Gh[bidx]);
      const f16x8 bl = *reinterpret_cast<const f16x8*>(&Gl[bidx]);
      accH[nf] = __builtin_amdgcn_mfma_f32_16x16x32_f16(ah, bh, accH[nf], 0, 0, 0);
      accL[nf] = __builtin_amdgcn_mfma_f32_16x16x32_f16(ah, bl, accL[nf], 0, 0, 0);
      accL[nf] = __builtin_amdgcn_mfma_f32_16x16x32_f16(al, bh, accL[nf], 0, 0, 0);
    }
  }
  {
    const int r0l = lg * 4;
    float bq[4];
#pragma unroll
    for (int r = 0; r < 4; r++) bq[r] = beq[m0 + r0l + r];
#pragma unroll
    for (int nf = 0; nf < 2; nf++) {
      const int col = n0 + nf * 16 + lr;
      const float zv = zc[col];
#pragma unroll
      for (int r = 0; r < 4; r++)
        xs[r0l + r][col + 2] = accH[nf][r] + accL[nf][r] * INV_LSCALE + bq[r] * zv;
    }
  }
  __syncthreads();

  // ---- Phase 2: update (round-8 validated local-recompute stencils) ----
  const int j = tid & 255;
  const int half = tid >> 8;
  const bool h1 = j < 255, h2 = j < 254;
  const float smax = *p_smax, smin = *p_smin;
  const float sdmax = *p_sdmax, sdmin = *p_sdmin;
  const float sddmax = *p_sddmax, sddmin = *p_sddmin;
  const float invT = 20.f, invT2 = 400.f;

  const size_t primOff = (size_t)B * NUMV;
  const size_t fpOff = primOff + (size_t)QP_ITERS * B;
  const size_t accPOff = fpOff + (size_t)QP_ITERS * B;
  const size_t accFOff = accPOff + (size_t)B;

  for (int rr = 0; rr < 8; rr++) {
    const int rl = half * 8 + rr;
    const int gr = m0 + rl;
    const float xm2 = xs[rl][j];
    const float xm1 = xs[rl][j + 1];
    const float x0  = xs[rl][j + 2];
    const float x1  = xs[rl][j + 3];
    const float x2  = xs[rl][j + 4];

    const float vj = (x1 - x0) * invT;
    const float aj = (x2 - 2.f * x1 + x0) * invT2;
    const float vm1 = (x0 - xm1) * invT;
    const float am1 = (x1 - 2.f * x0 + xm1) * invT2;
    const float am2 = (x0 - 2.f * xm1 + xm2) * invT2;

    const float rv0a = fmaxf(0.f, x0 - smax), rv0b = fmaxf(0.f, smin - x0);
    const float E0 = rv0a - rv0b;
    float rv1a = 0.f, rv1b = 0.f, rv2a = 0.f, rv2b = 0.f, E1 = 0.f, E2 = 0.f;
    if (h1) { rv1a = fmaxf(0.f, vj - sdmax); rv1b = fmaxf(0.f, sdmin - vj); E1 = rv1a - rv1b; }
    if (h2) { rv2a = fmaxf(0.f, aj - sddmax); rv2b = fmaxf(0.f, sddmin - aj); E2 = rv2a - rv2b; }
    float res2 = rv0a * rv0a + rv0b * rv0b + rv1a * rv1a + rv1b * rv1b
               + rv2a * rv2a + rv2b * rv2b;

    const float E1m = (j >= 1) ? (fmaxf(0.f, vm1 - sdmax) - fmaxf(0.f, sdmin - vm1)) : 0.f;
    const float E2m1 = (j >= 1 && h1) ? (fmaxf(0.f, am1 - sddmax) - fmaxf(0.f, sddmin - am1)) : 0.f;
    const float E2m2 = (j >= 2) ? (fmaxf(0.f, am2 - sddmax) - fmaxf(0.f, sddmin - am2)) : 0.f;

    const float dl = E0 + (E1m - E1) * invT + (E2m2 - 2.f * E2m1 + E2) * invT2;
    const float lamj = (it == 0) ? NO[(size_t)gr * NO_LD + j] : lam[(size_t)gr * NUMV + j];
    const float lnew = lamj - dl;
    const float fpl2 = dl * dl;
    lam[(size_t)gr * NUMV + j] = lnew;

    const float sn0a = fmaxf(0.f, smax - x0), sn0b = fmaxf(0.f, x0 - smin);
    float sn1a = 0.f, sn1b = 0.f, sn2a = 0.f, sn2b = 0.f;
    if (h1) { sn1a = fmaxf(0.f, sdmax - vj); sn1b = fmaxf(0.f, vj - sdmin); }
    if (h2) { sn2a = fmaxf(0.f, sddmax - aj); sn2b = fmaxf(0.f, aj - sddmin); }

    float sp0a, sp0b, sp1a = 0.f, sp1b = 0.f, sp2a = 0.f, sp2b = 0.f;
    if (it == 0) {
      const float* no = NO + (size_t)gr * NO_LD;
      sp0a = fmaxf(0.f, no[256 + j]); sp0b = fmaxf(0.f, no[512 + j]);
      if (h1) { sp1a = fmaxf(0.f, no[768 + j]); sp1b = fmaxf(0.f, no[1023 + j]); }
      if (h2) { sp2a = fmaxf(0.f, no[1278 + j]); sp2b = fmaxf(0.f, no[1532 + j]); }
    } else {
      const float p0 = xps[rl][j + 2], p1 = xps[rl][j + 3], p2 = xps[rl][j + 4];
      const float vp = (p1 - p0) * invT;
      const float ap = (p2 - 2.f * p1 + p0) * invT2;
      sp0a = fmaxf(0.f, smax - p0); sp0b = fmaxf(0.f, p0 - smin);
      if (h1) { sp1a = fmaxf(0.f, sdmax - vp); sp1b = fmaxf(0.f, vp - sdmin); }
      if (h2) { sp2a = fmaxf(0.f, sddmax - ap); sp2b = fmaxf(0.f, ap - sddmin); }
    }
    const float d0a = sp0a - sn0a, d0b = sp0b - sn0b;
    const float d1a = sp1a - sn1a, d1b = sp1b - sn1b;
    const float d2a = sp2a - sn2a, d2b = sp2b - sn2b;
    float fps2 = d0a * d0a + d0b * d0b + d1a * d1a + d1b * d1b
               + d2a * d2a + d2b * d2b;

    const float D0 = fminf(smax, x0) + fmaxf(smin, x0);
    const float D1 = h1 ? (fminf(sdmax, vj) + fmaxf(sdmin, vj)) : 0.f;
    const float D2 = h2 ? (fminf(sddmax, aj) + fmaxf(sddmin, aj)) : 0.f;
    const float D1m = (j >= 1) ? (fminf(sdmax, vm1) + fmaxf(sdmin, vm1)) : 0.f;
    const float D2m1 = (j >= 1 && h1) ? (fminf(sddmax, am1) + fmaxf(sddmin, am1)) : 0.f;
    const float D2m2 = (j >= 2) ? (fminf(sddmax, am2) + fmaxf(sddmin, am2)) : 0.f;

    if (it < QP_ITERS - 1) {
      const float vn = lnew + ss[(size_t)gr * NUMV + j]
                     + D0 + (D1m - D1) * invT + (D2m2 - 2.f * D2m1 + D2) * invT2;
      const _Float16 vh16 = (_Float16)vn;
      Vh[(size_t)gr * NUMV + j] = vh16;
      Vl[(size_t)gr * NUMV + j] = (_Float16)((vn - (float)vh16) * LSCALE);
      Xo[(size_t)gr * NUMV + j] = x0;
    } else {
      out[(size_t)gr * NUMV + j] = x0;
    }

    float a = res2, b = fps2, c = fpl2;
    for (int o = 32; o > 0; o >>= 1) {
      a += __shfl_down(a, o);
      b += __shfl_down(b, o);
      c += __shfl_down(c, o);
    }
    if (lane == 0) { red[wave][rr][0] = a; red[wave][rr][1] = b; red[wave][rr][2] = c; }
  }
  __syncthreads();

  if (tid < 16) {
    const int rl = tid, hf = rl >> 3, rr = rl & 7;
    const int w0 = hf * 4;
    const float r2 = red[w0][rr][0] + red[w0 + 1][rr][0] + red[w0 + 2][rr][0] + red[w0 + 3][rr][0];
    const float s2 = red[w0][rr][1] + red[w0 + 1][rr][1] + red[w0 + 2][rr][1] + red[w0 + 3][rr][1];
    const float l2 = red[w0][rr][2] + red[w0 + 1][rr][2] + red[w0 + 2][rr][2] + red[w0 + 3][rr][2];
    const float pr = sqrtf(r2);
    const float fp = sqrtf(s2) + sqrtf(l2);
    out[primOff + (size_t)it * B + m0 + rl] = pr;
    out[fpOff + (size_t)it * B + m0 + rl] = fp;
    if (it == QP_ITERS - 1) {
      float aP = pr, aF = fp;
      for (int t2 = 0; t2 < QP_ITERS - 1; t2++) {
        aP += out[primOff + (size_t)t2 * B + m0 + rl];
        aF += out[fpOff + (size_t)t2 * B + m0 + rl];
      }
      out[accPOff + m0 + rl] = aP * (1.f / QP_ITERS);
      out[accFOff + m0 + rl] = aF * (1.f / QP_ITERS);
    }
  }
}

extern "C" void kernel_launch(void* const* d_in, const int* in_sizes, int n_in,
                              void* d_out, int out_size, void* d_ws, size_t ws_size,
                              hipStream_t stream)
{
  const float* inp = (const float*)d_in[0];       // [B][260]
  const float* sinit = (const float*)d_in[1];     // [B][1]
  const float* ssamp = (const float*)d_in[2];     // [B][256]
  const float* p_smax = (const float*)d_in[3];
  const float* p_smin = (const float*)d_in[4];
  const float* p_sdmax = (const float*)d_in[5];
  const float* p_sdmin = (const float*)d_in[6];
  const float* p_sddmax = (const float*)d_in[7];
  const float* p_sddmin = (const float*)d_in[8];
  const float* W1 = (const float*)d_in[11];       // [260][1024]
  const float* b1 = (const float*)d_in[12];       // [1024]
  const float* W2 = (const float*)d_in[13];       // [1024][1786]
  const float* b2 = (const float*)d_in[14];       // [1786]
  float* out = (float*)d_out;

  const int B = in_sizes[1];                      // 4096
  const int IND = in_sizes[9];                    // 260
  const int H = in_sizes[12];                     // 1024
  const int OUTN = in_sizes[14];                  // 1786

  char* ws = (char*)d_ws;
  float* NO = (float*)ws;                                      // [B][1792] fp32
  char* p = ws + (size_t)B * NO_LD * 4;                        // 29,360,128
  _Float16* hH = (_Float16*)p;                                 // [B][1024] fp16 (dead after GEMM2)
  float* Xa = (float*)p;                                       // alias: fp32 [B][256]
  float* Xb = (float*)(p + (size_t)B * NUMV * 4);              // alias: fp32 [B][256]
  char* q = p + (size_t)B * H * 2;                             // 37,748,736
  _Float16* W2T = (_Float16*)q;                                // [1786][1024] fp16 (dead after GEMM2)
  _Float16* Vh = (_Float16*)q;                                 // alias: fp16 [B][256]
  _Float16* Vl = (_Float16*)(q + (size_t)B * NUMV * 2);        // alias: fp16 [B][256]
  char* q2 = q + (size_t)OUTN * H * 2;                         // 41,406,464
  _Float16* W1T = (_Float16*)q2;                               // [1024][260] fp16 (dead after GEMM1)
  char* r3 = ws + 41943040;                                    // 41,943,040
  float* lam = (float*)r3;                                     // fp32 [B][256]
  char* r4 = r3 + (size_t)B * NUMV * 4;                        // 46,137,344
  _Float16* Gh = (_Float16*)r4;                                // [256][256] fp16
  _Float16* Gl = (_Float16*)(r4 + 131072);                     // [256][256] fp16 (x2048)
  float* zc = (float*)(r4 + 262144);                           // [256] fp32
  _Float16* Uh = (_Float16*)(r4 + 263168);                     // [256][256] fp16 (U^T)
  _Float16* Ul = (_Float16*)(r4 + 263168 + 131072);            // [256][256] fp16 (x2048)

  split_u<<<256, 256, 0, stream>>>(Uh, Ul, zc);
  {
    dim3 g(16, 8);
    gemm_g<<<g, 64, 0, stream>>>(Uh, Ul, Gh, Gl);
  }
  {
    dim3 g((IND + 31) / 32, (H + 31) / 32), blk(32, 8);
    transpose_cvt<<<g, blk, 0, stream>>>(W1, W1T, IND, H);
  }
  {
    dim3 g((H + 31) / 32, (OUTN + 31) / 32), blk(32, 8);
    transpose_cvt<<<g, blk, 0, stream>>>(W2, W2T, H, OUTN);
  }
  {
    dim3 g(B / 128, H / 128);
    mfma_gemm<true, true><<<g, 256, 0, stream>>>(inp, W1T, b1, hH, B, H, IND, IND, IND, H);
  }
  {
    dim3 g(B / 128, (OUTN + 127) / 128);
    mfma_gemm64<<<g, 256, 0, stream>>>(hH, W2T, b2, NO, B, OUTN, H, H, H, NO_LD);
  }
  init_v<<<B, 256, 0, stream>>>(NO, ssamp, p_smax, p_smin, p_sdmax, p_sdmin,
                                p_sddmax, p_sddmin, Vh, Vl, B);
  float* Xprev = Xa;
  float* Xout = Xb;
  for (int it = 0; it < QP_ITERS; it++) {
    qp_iter_fused<<<B / 16, 512, 0, stream>>>(Vh, Vl, Gh, Gl, sinit, zc,
                                              Xprev, Xout, NO, lam, ssamp,
                                              p_smax, p_smin, p_sdmax, p_sdmin,
                                              p_sddmax, p_sddmin, out, B, it);
    float* t = Xprev; Xprev = Xout; Xout = t;
  }
}

// Round 17
// 173.227 us; speedup vs baseline: 1.7857x; 1.2425x over previous
//
#include <hip/hip_runtime.h>
#include <cstddef>

// learned_qp_solver: B=4096, NUM=256, NC=1530, IND=260, H=1024, OUT=1786, 5 iters.
//
//   KKT solve closed form:  x = G v + (b_eq/z0) z,  G = C^{-1} - z z^T / z0 (symmetric)
//   MLP on matrix cores: v_mfma_f32_16x16x32_f16 (BK=32 GEMM1 / BK=64 GEMM2).
//   Solve: scaled split-fp16 (Gl,Vl x2048 dodge fp16 denormal flush in MFMA).
//   G build: U = L^{-1} at COMPILE TIME (constexpr quarters); gemm_g on MFMA.
//   Round-17: ALL 5 QP iterations in ONE kernel (qp_solve5). Block owns 16 rows
//   entirely -> V in LDS (split fp16), lam/ss in REGISTERS (same thread<->(row,col)
//   map each iter), x double-buffered in LDS. Zero intermediate global traffic in
//   the loop except G (L2-hot) and out. 12 -> 8 dispatches.
//
// ws layout (bytes), ~46.7 MB:
//   [0,          29360128)  NO   fp32 [B][1792]
//   [29360128,   37748736)  hH   fp16 [B][1024]
//   [37748736,   41406464)  W2T  fp16 [1786][1024] -> after GEMM2: Vh, Vl (fp16 [B][256])
//   [41406464,   41938944)  W1T  fp16 [1024][260]
//   [46137344,   46268416)  Gh   fp16 [256][256]
//   [46268416,   46399488)  Gl   fp16 [256][256]  (scaled x2048)
//   [46399488,   46400512)  zc   fp32 [256]
//   [46400512,   46531584)  Uh   fp16 [256][256]
//   [46531584,   46662656)  Ul   fp16 [256][256]  (scaled x2048)

#define NUMV 256
#define QP_ITERS 5
#define NO_LD 1792
#define LSCALE 2048.0f
#define INV_LSCALE (1.0f / 2048.0f)

typedef _Float16 f16x4 __attribute__((ext_vector_type(4)));
typedef _Float16 f16x8 __attribute__((ext_vector_type(8)));
typedef float f32x4 __attribute__((ext_vector_type(4)));

// ---------------- compile-time pentadiagonal Cholesky tables ----------------
struct FacT {
  double invd[256];
  double l1[257];
  double l2[258];
  double z[256];
  float  zcf[256];
};

constexpr double csqrt_(double x) {
  double g = (x > 1.0) ? x : 1.0;
  for (int i = 0; i < 64; ++i) g = 0.5 * (g + x / g);
  return g;
}

constexpr FacT make_fac() {
  FacT f{};
  const double T = 0.05, a = 1.0 / (T * T), b2 = a * a;
  double c0[256] = {}, c1[255] = {}, c2[254] = {};
  double dd[256] = {}, l1[256] = {}, l2[256] = {};
  for (int j = 0; j < 256; j++) {
    double cd1 = (j == 0 || j == 255) ? 1.0 : 2.0;
    double cd2 = (j == 0 || j == 255) ? 1.0 : ((j == 1 || j == 254) ? 5.0 : 6.0);
    c0[j] = 3.0 + 2.0 * a * cd1 + 2.0 * b2 * cd2;
  }
  for (int j = 0; j < 255; j++) c1[j] = -2.0 * a + 2.0 * b2 * ((j == 0 || j == 254) ? -2.0 : -4.0);
  for (int j = 0; j < 254; j++) c2[j] = 2.0 * b2;
  dd[0] = csqrt_(c0[0]); l1[0] = 0.0; l2[0] = 0.0;
  l1[1] = c1[0] / dd[0]; l2[1] = 0.0;
  dd[1] = csqrt_(c0[1] - l1[1] * l1[1]);
  for (int j = 2; j < 256; j++) {
    l2[j] = c2[j - 2] / dd[j - 2];
    l1[j] = (c1[j - 1] - l2[j] * l1[j - 1]) / dd[j - 1];
    dd[j] = csqrt_(c0[j] - l1[j] * l1[j] - l2[j] * l2[j]);
  }
  for (int j = 0; j < 256; j++) f.invd[j] = 1.0 / dd[j];
  for (int j = 0; j < 256; j++) f.l1[j] = l1[j];
  f.l1[256] = 0.0;
  for (int j = 0; j < 256; j++) f.l2[j] = l2[j];
  f.l2[256] = 0.0; f.l2[257] = 0.0;
  double w[256] = {}, zz[256] = {};
  w[0] = 1.0 / dd[0];
  w[1] = (-l1[1] * w[0]) / dd[1];
  for (int j = 2; j < 256; j++) w[j] = (-l1[j] * w[j - 1] - l2[j] * w[j - 2]) / dd[j];
  zz[255] = w[255] / dd[255];
  zz[254] = (w[254] - l1[255] * zz[255]) / dd[254];
  for (int j = 253; j >= 0; j--)
    zz[j] = (w[j] - l1[j + 1] * zz[j + 1] - l2[j + 2] * zz[j + 2]) / dd[j];
  for (int j = 0; j < 256; j++) f.z[j] = zz[j];
  for (int j = 0; j < 256; j++) f.zcf[j] = (float)(zz[j] / zz[0]);
  return f;
}

constexpr FacT FAC_HOST = make_fac();
__constant__ FacT FAC = FAC_HOST;

// ---- compile-time U = L^{-1}: quarter (64 columns) per constexpr evaluation ----
struct UQ { float u[64][256]; };

constexpr UQ make_uq(int cbase) {
  UQ q{};
  const double T = 0.05, a = 1.0 / (T * T), b2 = a * a;
  double c0a[256] = {}, c1a[255] = {}, c2a[254] = {};
  double dd[256] = {}, l1[256] = {}, l2[256] = {};
  for (int j = 0; j < 256; j++) {
    double cd1 = (j == 0 || j == 255) ? 1.0 : 2.0;
    double cd2 = (j == 0 || j == 255) ? 1.0 : ((j == 1 || j == 254) ? 5.0 : 6.0);
    c0a[j] = 3.0 + 2.0 * a * cd1 + 2.0 * b2 * cd2;
  }
  for (int j = 0; j < 255; j++) c1a[j] = -2.0 * a + 2.0 * b2 * ((j == 0 || j == 254) ? -2.0 : -4.0);
  for (int j = 0; j < 254; j++) c2a[j] = 2.0 * b2;
  dd[0] = csqrt_(c0a[0]); l1[0] = 0.0; l2[0] = 0.0;
  l1[1] = c1a[0] / dd[0]; l2[1] = 0.0;
  dd[1] = csqrt_(c0a[1] - l1[1] * l1[1]);
  for (int j = 2; j < 256; j++) {
    l2[j] = c2a[j - 2] / dd[j - 2];
    l1[j] = (c1a[j - 1] - l2[j] * l1[j - 1]) / dd[j - 1];
    dd[j] = csqrt_(c0a[j] - l1[j] * l1[j] - l2[j] * l2[j]);
  }
  for (int c = cbase; c < cbase + 64; ++c) {
    double w1 = 0.0, w2 = 0.0;
    for (int j = c; j < 256; ++j) {
      const double rhs = (j == c) ? 1.0 : 0.0;
      const double wj = (rhs - l1[j] * w1 - l2[j] * w2) / dd[j];
      q.u[c - cbase][j] = (float)wj;
      w2 = w1; w1 = wj;
    }
  }
  return q;
}

constexpr UQ UQ0_H = make_uq(0);
constexpr UQ UQ1_H = make_uq(64);
constexpr UQ UQ2_H = make_uq(128);
constexpr UQ UQ3_H = make_uq(192);
__constant__ UQ UFQ0 = UQ0_H;
__constant__ UQ UFQ1 = UQ1_H;
__constant__ UQ UFQ2 = UQ2_H;
__constant__ UQ UFQ3 = UQ3_H;

// ---- split compile-time U into scaled split-fp16 Uh/Ul; write zc ----
__global__ __launch_bounds__(256) void split_u(
    _Float16* __restrict__ Uh, _Float16* __restrict__ Ul, float* __restrict__ zc)
{
  const int c = blockIdx.x, j = threadIdx.x;
  float wf;
  if (c < 64)       wf = UFQ0.u[c][j];
  else if (c < 128) wf = UFQ1.u[c - 64][j];
  else if (c < 192) wf = UFQ2.u[c - 128][j];
  else              wf = UFQ3.u[c - 192][j];
  const _Float16 h = (_Float16)wf;
  Uh[(size_t)c * 256 + j] = h;
  Ul[(size_t)c * 256 + j] = (_Float16)((wf - (float)h) * LSCALE);
  if (c == 0) zc[j] = FAC.zcf[j];
}

// ---- G = UT * UT^T - z z^T/z0 via split-fp16 MFMA; output re-split to Gh/Gl ----
__global__ __launch_bounds__(64) void gemm_g(
    const _Float16* __restrict__ Uh, const _Float16* __restrict__ Ul,
    _Float16* __restrict__ Gh, _Float16* __restrict__ Gl)
{
  const int lane = threadIdx.x;
  const int lr = lane & 15, lg = lane >> 4;
  const int m0 = blockIdx.x * 16, n0 = blockIdx.y * 32;
  f32x4 accH[2], accL[2];
#pragma unroll
  for (int nf = 0; nf < 2; nf++) { accH[nf] = (f32x4)0.0f; accL[nf] = (f32x4)0.0f; }
  const size_t arow = (size_t)(m0 + lr) * 256 + lg * 8;
#pragma unroll 2
  for (int k0 = 0; k0 < 256; k0 += 32) {
    const f16x8 ah = *reinterpret_cast<const f16x8*>(&Uh[arow + k0]);
    const f16x8 al = *reinterpret_cast<const f16x8*>(&Ul[arow + k0]);
#pragma unroll
    for (int nf = 0; nf < 2; nf++) {
      const size_t bidx = (size_t)(n0 + nf * 16 + lr) * 256 + k0 + lg * 8;
      const f16x8 bh = *reinterpret_cast<const f16x8*>(&Uh[bidx]);
      const f16x8 bl = *reinterpret_cast<const f16x8*>(&Ul[bidx]);
      accH[nf] = __builtin_amdgcn_mfma_f32_16x16x32_f16(ah, bh, accH[nf], 0, 0, 0);
      accL[nf] = __builtin_amdgcn_mfma_f32_16x16x32_f16(ah, bl, accL[nf], 0, 0, 0);
      accL[nf] = __builtin_amdgcn_mfma_f32_16x16x32_f16(al, bh, accL[nf], 0, 0, 0);
    }
  }
  const int row0 = m0 + lg * 4;
#pragma unroll
  for (int nf = 0; nf < 2; nf++) {
    const int col = n0 + nf * 16 + lr;
    const double zcd = FAC.z[col] / FAC.z[0];
#pragma unroll
    for (int r = 0; r < 4; r++) {
      const int row = row0 + r;
      const float g = accH[nf][r] + accL[nf][r] * INV_LSCALE
                    - (float)(FAC.z[row] * zcd);
      const _Float16 gh = (_Float16)g;
      Gh[(size_t)row * 256 + col] = gh;
      Gl[(size_t)row * 256 + col] = (_Float16)((g - (float)gh) * LSCALE);
    }
  }
}

// ---------------- transpose + fp32->fp16 convert: in [K][N] -> out [N][K] ----------------
__global__ __launch_bounds__(256) void transpose_cvt(
    const float* __restrict__ in, _Float16* __restrict__ out, int K, int N)
{
  __shared__ float t[32][33];
  const int bk = blockIdx.x * 32, bn = blockIdx.y * 32;
  const int x = threadIdx.x, y = threadIdx.y;
  for (int yy = y; yy < 32; yy += 8) {
    const int k = bk + yy, n = bn + x;
    t[yy][x] = (k < K && n < N) ? in[(size_t)k * N + n] : 0.f;
  }
  __syncthreads();
  for (int yy = y; yy < 32; yy += 8) {
    const int n = bn + yy, k = bk + x;
    if (n < N && k < K) out[(size_t)n * K + k] = (_Float16)t[x][yy];
  }
}

// ---------------- MFMA GEMM (BK=32, handles fp32 A + K tails): GEMM1 ----------------
template<bool A_FP32, bool OUT_H16>
__global__ __launch_bounds__(256) void mfma_gemm(
    const void* __restrict__ Av, const _Float16* __restrict__ Bt,
    const float* __restrict__ bias, void* __restrict__ Cv,
    int M, int Nv, int K, int lda, int ldk, int ldc)
{
  __shared__ _Float16 At[128][40];
  __shared__ _Float16 Bs[128][40];
  const int tid = threadIdx.x;
  const int lane = tid & 63, wid = tid >> 6;
  const int wr = wid >> 1, wc = wid & 1;
  const int lrow = lane & 15, lb = lane >> 4;
  const int m0 = blockIdx.x * 128, n0 = blockIdx.y * 128;
  const int srow = tid >> 1, skh = (tid & 1) * 16;

  f32x4 acc[4][4];
#pragma unroll
  for (int i = 0; i < 4; i++)
#pragma unroll
    for (int j = 0; j < 4; j++) acc[i][j] = (f32x4)0.0f;

  const int nsteps = (K + 31) / 32;
  for (int t = 0; t < nsteps; ++t) {
    const int k0 = t * 32;
    if (A_FP32) {
      const float* A = (const float*)Av;
#pragma unroll
      for (int i = 0; i < 4; i++) {
        const int k = k0 + skh + i * 4;
        f16x4 hv = {};
        if (k + 4 <= K) {
          const float4 v = *reinterpret_cast<const float4*>(&A[(size_t)(m0 + srow) * lda + k]);
          hv[0] = (_Float16)v.x; hv[1] = (_Float16)v.y;
          hv[2] = (_Float16)v.z; hv[3] = (_Float16)v.w;
        } else if (k < K) {
          for (int e = 0; e < 4; e++)
            if (k + e < K) hv[e] = (_Float16)A[(size_t)(m0 + srow) * lda + k + e];
        }
        *reinterpret_cast<f16x4*>(&At[srow][skh + i * 4]) = hv;
      }
    } else {
      const _Float16* A = (const _Float16*)Av;
#pragma unroll
      for (int i = 0; i < 4; i++) {
        const int k = k0 + skh + i * 4;
        f16x4 hv = {};
        if (k + 4 <= K) hv = *reinterpret_cast<const f16x4*>(&A[(size_t)(m0 + srow) * lda + k]);
        *reinterpret_cast<f16x4*>(&At[srow][skh + i * 4]) = hv;
      }
    }
    {
      const int n = n0 + srow;
#pragma unroll
      for (int i = 0; i < 4; i++) {
        const int k = k0 + skh + i * 4;
        f16x4 hv = {};
        if (n < Nv && k + 4 <= K)
          hv = *reinterpret_cast<const f16x4*>(&Bt[(size_t)n * ldk + k]);
        *reinterpret_cast<f16x4*>(&Bs[srow][skh + i * 4]) = hv;
      }
    }
    __syncthreads();
    f16x8 af[4], bf[4];
#pragma unroll
    for (int i = 0; i < 4; i++)
      af[i] = *reinterpret_cast<const f16x8*>(&At[wr * 64 + i * 16 + lrow][lb * 8]);
#pragma unroll
    for (int j = 0; j < 4; j++)
      bf[j] = *reinterpret_cast<const f16x8*>(&Bs[wc * 64 + j * 16 + lrow][lb * 8]);
#pragma unroll
    for (int i = 0; i < 4; i++)
#pragma unroll
      for (int j = 0; j < 4; j++)
        acc[i][j] = __builtin_amdgcn_mfma_f32_16x16x32_f16(af[i], bf[j], acc[i][j], 0, 0, 0);
    __syncthreads();
  }
#pragma unroll
  for (int i = 0; i < 4; i++) {
#pragma unroll
    for (int j = 0; j < 4; j++) {
      const int gcol = n0 + wc * 64 + j * 16 + lrow;
      if (gcol < Nv) {
        const float bv = bias[gcol];
#pragma unroll
        for (int r = 0; r < 4; r++) {
          const int grow = m0 + wr * 64 + i * 16 + lb * 4 + r;
          float v = acc[i][j][r] + bv;
          if (OUT_H16) {
            v = fmaxf(v, 0.f);
            ((_Float16*)Cv)[(size_t)grow * ldc + gcol] = (_Float16)v;
          } else {
            ((float*)Cv)[(size_t)grow * ldc + gcol] = v;
          }
        }
      }
    }
  }
}

// ---------------- MFMA GEMM BK=64 (fp16 A, K%64==0, fp32 out): GEMM2 ----------------
__global__ __launch_bounds__(256) void mfma_gemm64(
    const _Float16* __restrict__ A, const _Float16* __restrict__ Bt,
    const float* __restrict__ bias, float* __restrict__ C,
    int M, int Nv, int K, int lda, int ldk, int ldc)
{
  __shared__ _Float16 At[128][72];
  __shared__ _Float16 Bs[128][72];
  const int tid = threadIdx.x;
  const int lane = tid & 63, wid = tid >> 6;
  const int wr = wid >> 1, wc = wid & 1;
  const int lrow = lane & 15, lb = lane >> 4;
  const int m0 = blockIdx.x * 128, n0 = blockIdx.y * 128;
  const int srow = tid >> 1, sh = (tid & 1) * 32;

  f32x4 acc[4][4];
#pragma unroll
  for (int i = 0; i < 4; i++)
#pragma unroll
    for (int j = 0; j < 4; j++) acc[i][j] = (f32x4)0.0f;

  const int nsteps = K >> 6;
  for (int t = 0; t < nsteps; ++t) {
    const int k0 = t * 64;
    const _Float16* asrc = &A[(size_t)(m0 + srow) * lda + k0 + sh];
#pragma unroll
    for (int i = 0; i < 4; i++)
      *reinterpret_cast<f16x8*>(&At[srow][sh + i * 8]) =
          *reinterpret_cast<const f16x8*>(asrc + i * 8);
    {
      const int n = n0 + srow;
      const _Float16* bsrc = &Bt[(size_t)n * ldk + k0 + sh];
#pragma unroll
      for (int i = 0; i < 4; i++) {
        f16x8 hv = {};
        if (n < Nv) hv = *reinterpret_cast<const f16x8*>(bsrc + i * 8);
        *reinterpret_cast<f16x8*>(&Bs[srow][sh + i * 8]) = hv;
      }
    }
    __syncthreads();
#pragma unroll
    for (int h = 0; h < 2; h++) {
      f16x8 af[4], bf[4];
#pragma unroll
      for (int i = 0; i < 4; i++)
        af[i] = *reinterpret_cast<const f16x8*>(&At[wr * 64 + i * 16 + lrow][h * 32 + lb * 8]);
#pragma unroll
      for (int j = 0; j < 4; j++)
        bf[j] = *reinterpret_cast<const f16x8*>(&Bs[wc * 64 + j * 16 + lrow][h * 32 + lb * 8]);
#pragma unroll
      for (int i = 0; i < 4; i++)
#pragma unroll
        for (int j = 0; j < 4; j++)
          acc[i][j] = __builtin_amdgcn_mfma_f32_16x16x32_f16(af[i], bf[j], acc[i][j], 0, 0, 0);
    }
    __syncthreads();
  }
#pragma unroll
  for (int i = 0; i < 4; i++) {
#pragma unroll
    for (int j = 0; j < 4; j++) {
      const int gcol = n0 + wc * 64 + j * 16 + lrow;
      if (gcol < Nv) {
        const float bv = bias[gcol];
#pragma unroll
        for (int r = 0; r < 4; r++) {
          const int grow = m0 + wr * 64 + i * 16 + lb * 4 + r;
          C[(size_t)grow * ldc + gcol] = acc[i][j][r] + bv;
        }
      }
    }
  }
}

// ---------------- initial rhs V0 = lam0 + ss + b_aug0 @ A_control (scaled split) ----
__global__ __launch_bounds__(256) void init_v(
    const float* __restrict__ NO, const float* __restrict__ ss,
    const float* __restrict__ p_smax, const float* __restrict__ p_smin,
    const float* __restrict__ p_sdmax, const float* __restrict__ p_sdmin,
    const float* __restrict__ p_sddmax, const float* __restrict__ p_sddmin,
    _Float16* __restrict__ Vh, _Float16* __restrict__ Vl, int B)
{
  __shared__ float d1s[258], d2s[258];
  const int r = blockIdx.x, j = threadIdx.x;
  const float K0 = *p_smax + *p_smin, K1 = *p_sdmax + *p_sdmin, K2 = *p_sddmax + *p_sddmin;
  const float invT = 20.f, invT2 = 400.f;
  const float* no = NO + (size_t)r * NO_LD;
  float s1 = fmaxf(0.f, no[256 + j]), s2 = fmaxf(0.f, no[512 + j]);
  float D0 = K0 - s1 + s2;
  float D1 = 0.f, D2 = 0.f;
  if (j < 255) D1 = K1 - fmaxf(0.f, no[768 + j]) + fmaxf(0.f, no[1023 + j]);
  if (j < 254) D2 = K2 - fmaxf(0.f, no[1278 + j]) + fmaxf(0.f, no[1532 + j]);
  d1s[2 + j] = D1; d2s[2 + j] = D2;
  if (j < 2) { d1s[j] = 0.f; d2s[j] = 0.f; }
  __syncthreads();
  float qn = D0 + (d1s[j + 1] - d1s[j + 2]) * invT
                + (d2s[j] - 2.f * d2s[j + 1] + d2s[j + 2]) * invT2;
  const float vn = no[j] + ss[(size_t)r * NUMV + j] + qn;
  const _Float16 vh = (_Float16)vn;
  Vh[(size_t)r * NUMV + j] = vh;
  Vl[(size_t)r * NUMV + j] = (_Float16)((vn - (float)vh) * LSCALE);
}

// ---- ALL 5 QP iterations in one kernel. Block = 16 rows, 512 threads.
// V in LDS (split fp16), lam/ss in registers, x double-buffered in LDS.
__global__ __launch_bounds__(512) void qp_solve5(
    const _Float16* __restrict__ Vh0, const _Float16* __restrict__ Vl0,
    const _Float16* __restrict__ Gh, const _Float16* __restrict__ Gl,
    const float* __restrict__ beq, const float* __restrict__ zc,
    const float* __restrict__ NO, const float* __restrict__ ss,
    const float* __restrict__ p_smax, const float* __restrict__ p_smin,
    const float* __restrict__ p_sdmax, const float* __restrict__ p_sdmin,
    const float* __restrict__ p_sddmax, const float* __restrict__ p_sddmin,
    float* __restrict__ out, int B)
{
  __shared__ float xsA[16][264], xsB[16][264];
  __shared__ _Float16 vhs[16][264], vls[16][264];
  __shared__ float zcs[256], beqs[16];
  __shared__ float red[8][8][3];
  const int tid = threadIdx.x;
  const int wave = tid >> 6, lane = tid & 63;
  const int lr = lane & 15, lg = lane >> 4;
  const int m0 = blockIdx.x * 16;
  const int n0 = wave * 32;
  const int j = tid & 255, half = tid >> 8;

  // ---- stage V0, zc, beq; zero x pads ----
  {
    const int idx = tid * 8;
    const int rl = idx >> 8, c = idx & 255;
    *reinterpret_cast<f16x8*>(&vhs[rl][c]) =
        *reinterpret_cast<const f16x8*>(&Vh0[(size_t)(m0 + rl) * 256 + c]);
    *reinterpret_cast<f16x8*>(&vls[rl][c]) =
        *reinterpret_cast<const f16x8*>(&Vl0[(size_t)(m0 + rl) * 256 + c]);
  }
  if (tid < 256) zcs[tid] = zc[tid];
  if (tid < 16) {
    beqs[tid] = beq[m0 + tid];
    xsA[tid][0] = 0.f; xsA[tid][1] = 0.f; xsA[tid][258] = 0.f; xsA[tid][259] = 0.f;
    xsB[tid][0] = 0.f; xsB[tid][1] = 0.f; xsB[tid][258] = 0.f; xsB[tid][259] = 0.f;
  }

  // ---- per-thread persistent state: lam + ss for 8 (row,col) pairs ----
  float lamr[8], ssv[8];
#pragma unroll
  for (int rr = 0; rr < 8; rr++) {
    const int gr = m0 + half * 8 + rr;
    ssv[rr] = ss[(size_t)gr * NUMV + j];
    lamr[rr] = NO[(size_t)gr * NO_LD + j];
  }
  float accP = 0.f, accF = 0.f;

  const float smax = *p_smax, smin = *p_smin;
  const float sdmax = *p_sdmax, sdmin = *p_sdmin;
  const float sddmax = *p_sddmax, sddmin = *p_sddmin;
  const float invT = 20.f, invT2 = 400.f;
  const bool h1 = j < 255, h2 = j < 254;

  const size_t primOff = (size_t)B * NUMV;
  const size_t fpOff = primOff + (size_t)QP_ITERS * B;
  const size_t accPOff = fpOff + (size_t)QP_ITERS * B;
  const size_t accFOff = accPOff + (size_t)B;

  float (*xc)[264] = xsA;
  float (*xp)[264] = xsB;

  for (int it = 0; it < QP_ITERS; ++it) {
    __syncthreads();    // vhs/vls ready (staged or updated)

    // ---- Phase 1: MFMA solve (validated split-fp16 path; V from LDS) ----
    f32x4 accH[2], accL[2];
#pragma unroll
    for (int nf = 0; nf < 2; nf++) { accH[nf] = (f32x4)0.0f; accL[nf] = (f32x4)0.0f; }
#pragma unroll 2
    for (int k0 = 0; k0 < 256; k0 += 32) {
      const f16x8 ah = *reinterpret_cast<const f16x8*>(&vhs[lr][k0 + lg * 8]);
      const f16x8 al = *reinterpret_cast<const f16x8*>(&vls[lr][k0 + lg * 8]);
#pragma unroll
      for (int nf = 0; nf < 2; nf++) {
        const size_t bidx = (size_t)(n0 + nf * 16 + lr) * 256 + k0 + lg * 8;
        const f16x8 bh = *reinterpret_cast<const f16x8*>(&Gh[bidx]);
        const f16x8 bl = *reinterpret_cast<const f16x8*>(&Gl[bidx]);
        accH[nf] = __builtin_amdgcn_mfma_f32_16x16x32_f16(ah, bh, accH[nf], 0, 0, 0);
        accL[nf] = __builtin_amdgcn_mfma_f32_16x16x32_f16(ah, bl, accL[nf], 0, 0, 0);
        accL[nf] = __builtin_amdgcn_mfma_f32_16x16x32_f16(al, bh, accL[nf], 0, 0, 0);
      }
    }
    {
      const int r0l = lg * 4;
#pragma unroll
      for (int nf = 0; nf < 2; nf++) {
        const int col = n0 + nf * 16 + lr;
        const float zv = zcs[col];
#pragma unroll
        for (int r = 0; r < 4; r++)
          xc[r0l + r][col + 2] = accH[nf][r] + accL[nf][r] * INV_LSCALE + beqs[r0l + r] * zv;
      }
    }
    __syncthreads();    // x ready

    // ---- Phase 2: update (round-8/16 validated local-recompute stencils) ----
#pragma unroll
    for (int rr = 0; rr < 8; rr++) {
      const int rl = half * 8 + rr;
      const int gr = m0 + rl;
      const float xm2 = xc[rl][j];
      const float xm1 = xc[rl][j + 1];
      const float x0  = xc[rl][j + 2];
      const float x1  = xc[rl][j + 3];
      const float x2  = xc[rl][j + 4];

      const float vj = (x1 - x0) * invT;
      const float aj = (x2 - 2.f * x1 + x0) * invT2;
      const float vm1 = (x0 - xm1) * invT;
      const float am1 = (x1 - 2.f * x0 + xm1) * invT2;
      const float am2 = (x0 - 2.f * xm1 + xm2) * invT2;

      const float rv0a = fmaxf(0.f, x0 - smax), rv0b = fmaxf(0.f, smin - x0);
      const float E0 = rv0a - rv0b;
      float rv1a = 0.f, rv1b = 0.f, rv2a = 0.f, rv2b = 0.f, E1 = 0.f, E2 = 0.f;
      if (h1) { rv1a = fmaxf(0.f, vj - sdmax); rv1b = fmaxf(0.f, sdmin - vj); E1 = rv1a - rv1b; }
      if (h2) { rv2a = fmaxf(0.f, aj - sddmax); rv2b = fmaxf(0.f, sddmin - aj); E2 = rv2a - rv2b; }
      float res2 = rv0a * rv0a + rv0b * rv0b + rv1a * rv1a + rv1b * rv1b
                 + rv2a * rv2a + rv2b * rv2b;

      const float E1m = (j >= 1) ? (fmaxf(0.f, vm1 - sdmax) - fmaxf(0.f, sdmin - vm1)) : 0.f;
      const float E2m1 = (j >= 1 && h1) ? (fmaxf(0.f, am1 - sddmax) - fmaxf(0.f, sddmin - am1)) : 0.f;
      const float E2m2 = (j >= 2) ? (fmaxf(0.f, am2 - sddmax) - fmaxf(0.f, sddmin - am2)) : 0.f;

      const float dl = E0 + (E1m - E1) * invT + (E2m2 - 2.f * E2m1 + E2) * invT2;
      const float lnew = lamr[rr] - dl;
      const float fpl2 = dl * dl;
      lamr[rr] = lnew;

      const float sn0a = fmaxf(0.f, smax - x0), sn0b = fmaxf(0.f, x0 - smin);
      float sn1a = 0.f, sn1b = 0.f, sn2a = 0.f, sn2b = 0.f;
      if (h1) { sn1a = fmaxf(0.f, sdmax - vj); sn1b = fmaxf(0.f, vj - sdmin); }
      if (h2) { sn2a = fmaxf(0.f, sddmax - aj); sn2b = fmaxf(0.f, aj - sddmin); }

      float sp0a, sp0b, sp1a = 0.f, sp1b = 0.f, sp2a = 0.f, sp2b = 0.f;
      if (it == 0) {
        const float* no = NO + (size_t)gr * NO_LD;
        sp0a = fmaxf(0.f, no[256 + j]); sp0b = fmaxf(0.f, no[512 + j]);
        if (h1) { sp1a = fmaxf(0.f, no[768 + j]); sp1b = fmaxf(0.f, no[1023 + j]); }
        if (h2) { sp2a = fmaxf(0.f, no[1278 + j]); sp2b = fmaxf(0.f, no[1532 + j]); }
      } else {
        const float p0 = xp[rl][j + 2], p1 = xp[rl][j + 3], p2 = xp[rl][j + 4];
        const float vp = (p1 - p0) * invT;
        const float ap = (p2 - 2.f * p1 + p0) * invT2;
        sp0a = fmaxf(0.f, smax - p0); sp0b = fmaxf(0.f, p0 - smin);
        if (h1) { sp1a = fmaxf(0.f, sdmax - vp); sp1b = fmaxf(0.f, vp - sdmin); }
        if (h2) { sp2a = fmaxf(0.f, sddmax - ap); sp2b = fmaxf(0.f, ap - sddmin); }
      }
      const float d0a = sp0a - sn0a, d0b = sp0b - sn0b;
      const float d1a = sp1a - sn1a, d1b = sp1b - sn1b;
      const float d2a = sp2a - sn2a, d2b = sp2b - sn2b;
      float fps2 = d0a * d0a + d0b * d0b + d1a * d1a + d1b * d1b
                 + d2a * d2a + d2b * d2b;

      const float D0 = fminf(smax, x0) + fmaxf(smin, x0);
      const float D1 = h1 ? (fminf(sdmax, vj) + fmaxf(sdmin, vj)) : 0.f;
      const float D2 = h2 ? (fminf(sddmax, aj) + fmaxf(sddmin, aj)) : 0.f;
      const float D1m = (j >= 1) ? (fminf(sdmax, vm1) + fmaxf(sdmin, vm1)) : 0.f;
      const float D2m1 = (j >= 1 && h1) ? (fminf(sddmax, am1) + fmaxf(sddmin, am1)) : 0.f;
      const float D2m2 = (j >= 2) ? (fminf(sddmax, am2) + fmaxf(sddmin, am2)) : 0.f;

      if (it < QP_ITERS - 1) {
        const float vn = lnew + ssv[rr]
                       + D0 + (D1m - D1) * invT + (D2m2 - 2.f * D2m1 + D2) * invT2;
        const _Float16 vh16 = (_Float16)vn;
        vhs[rl][j] = vh16;
        vls[rl][j] = (_Float16)((vn - (float)vh16) * LSCALE);
      } else {
        out[(size_t)gr * NUMV + j] = x0;
      }

      float a = res2, b = fps2, c = fpl2;
      for (int o = 32; o > 0; o >>= 1) {
        a += __shfl_down(a, o);
        b += __shfl_down(b, o);
        c += __shfl_down(c, o);
      }
      if (lane == 0) { red[wave][rr][0] = a; red[wave][rr][1] = b; red[wave][rr][2] = c; }
    }
    __syncthreads();    // red + vhs/vls ready

    if (tid < 16) {
      const int rl = tid, hf = rl >> 3, rr = rl & 7;
      const int w0 = hf * 4;
      const float r2 = red[w0][rr][0] + red[w0 + 1][rr][0] + red[w0 + 2][rr][0] + red[w0 + 3][rr][0];
      const float s2 = red[w0][rr][1] + red[w0 + 1][rr][1] + red[w0 + 2][rr][1] + red[w0 + 3][rr][1];
      const float l2 = red[w0][rr][2] + red[w0 + 1][rr][2] + red[w0 + 2][rr][2] + red[w0 + 3][rr][2];
      const float pr = sqrtf(r2);
      const float fp = sqrtf(s2) + sqrtf(l2);
      out[primOff + (size_t)it * B + m0 + rl] = pr;
      out[fpOff + (size_t)it * B + m0 + rl] = fp;
      accP += pr; accF += fp;
    }
    // swap x buffers
    float (*t)[264] = xc; xc = xp; xp = t;
  }
  if (tid < 16) {
    out[accPOff + m0 + tid] = accP * (1.f / QP_ITERS);
    out[accFOff + m0 + tid] = accF * (1.f / QP_ITERS);
  }
}

extern "C" void kernel_launch(void* const* d_in, const int* in_sizes, int n_in,
                              void* d_out, int out_size, void* d_ws, size_t ws_size,
                              hipStream_t stream)
{
  const float* inp = (const float*)d_in[0];       // [B][260]
  const float* sinit = (const float*)d_in[1];     // [B][1]
  const float* ssamp = (const float*)d_in[2];     // [B][256]
  const float* p_smax = (const float*)d_in[3];
  const float* p_smin = (const float*)d_in[4];
  const float* p_sdmax = (const float*)d_in[5];
  const float* p_sdmin = (const float*)d_in[6];
  const float* p_sddmax = (const float*)d_in[7];
  const float* p_sddmin = (const float*)d_in[8];
  const float* W1 = (const float*)d_in[11];       // [260][1024]
  const float* b1 = (const float*)d_in[12];       // [1024]
  const float* W2 = (const float*)d_in[13];       // [1024][1786]
  const float* b2 = (const float*)d_in[14];       // [1786]
  float* out = (float*)d_out;

  const int B = in_sizes[1];                      // 4096
  const int IND = in_sizes[9];                    // 260
  const int H = in_sizes[12];                     // 1024
  const int OUTN = in_sizes[14];                  // 1786

  char* ws = (char*)d_ws;
  float* NO = (float*)ws;                                      // [B][1792] fp32
  char* p = ws + (size_t)B * NO_LD * 4;                        // 29,360,128
  _Float16* hH = (_Float16*)p;                                 // [B][1024] fp16
  char* q = p + (size_t)B * H * 2;                             // 37,748,736
  _Float16* W2T = (_Float16*)q;                                // [1786][1024] fp16 (dead after GEMM2)
  _Float16* Vh = (_Float16*)q;                                 // alias: fp16 [B][256]
  _Float16* Vl = (_Float16*)(q + (size_t)B * NUMV * 2);        // alias: fp16 [B][256]
  char* q2 = q + (size_t)OUTN * H * 2;                         // 41,406,464
  _Float16* W1T = (_Float16*)q2;                               // [1024][260] fp16 (dead after GEMM1)
  char* r4 = ws + 46137344;                                    // 46,137,344
  _Float16* Gh = (_Float16*)r4;                                // [256][256] fp16
  _Float16* Gl = (_Float16*)(r4 + 131072);                     // [256][256] fp16 (x2048)
  float* zc = (float*)(r4 + 262144);                           // [256] fp32
  _Float16* Uh = (_Float16*)(r4 + 263168);                     // [256][256] fp16 (U^T)
  _Float16* Ul = (_Float16*)(r4 + 263168 + 131072);            // [256][256] fp16 (x2048)

  split_u<<<256, 256, 0, stream>>>(Uh, Ul, zc);
  {
    dim3 g(16, 8);
    gemm_g<<<g, 64, 0, stream>>>(Uh, Ul, Gh, Gl);
  }
  {
    dim3 g((IND + 31) / 32, (H + 31) / 32), blk(32, 8);
    transpose_cvt<<<g, blk, 0, stream>>>(W1, W1T, IND, H);
  }
  {
    dim3 g((H + 31) / 32, (OUTN + 31) / 32), blk(32, 8);
    transpose_cvt<<<g, blk, 0, stream>>>(W2, W2T, H, OUTN);
  }
  {
    dim3 g(B / 128, H / 128);
    mfma_gemm<true, true><<<g, 256, 0, stream>>>(inp, W1T, b1, hH, B, H, IND, IND, IND, H);
  }
  {
    dim3 g(B / 128, (OUTN + 127) / 128);
    mfma_gemm64<<<g, 256, 0, stream>>>(hH, W2T, b2, NO, B, OUTN, H, H, H, NO_LD);
  }
  init_v<<<B, 256, 0, stream>>>(NO, ssamp, p_smax, p_smin, p_sdmax, p_sdmin,
                                p_sddmax, p_sddmin, Vh, Vl, B);
  qp_solve5<<<B / 16, 512, 0, stream>>>(Vh, Vl, Gh, Gl, sinit, zc, NO, ssamp,
                                        p_smax, p_smin, p_sdmax, p_sdmin,
                                        p_sddmax, p_sddmin, out, B);
}

// Round 18
// 162.898 us; speedup vs baseline: 1.8989x; 1.0634x over previous
//
#include <hip/hip_runtime.h>
#include <cstddef>

// learned_qp_solver: B=4096, NUM=256, NC=1530, IND=260, H=1024, OUT=1786, 5 iters.
//
//   KKT solve closed form:  x = G v + (b_eq/z0) z,  G = C^{-1} - z z^T / z0 (symmetric)
//   MLP on matrix cores: v_mfma_f32_16x16x32_f16 (BK=32 GEMM1 / BK=64 GEMM2).
//   Solve: scaled split-fp16 (Gl,Vl x2048 dodge fp16 denormal flush in MFMA).
//   G build: U = L^{-1} at COMPILE TIME (constexpr quarters); gemm_g on MFMA.
//   qp_solve5: ALL 5 QP iterations in one kernel; block owns 16 rows; V in LDS,
//   lam/ss in registers, x double-buffered in LDS.
//   Round-18 (round-17 lesson: 22% occupancy, latency-bound at 100us): 1024
//   threads (16 waves, 4/SIMD), each thread 4 rows; wave = one 16-col MFMA slice.
//
// ws layout (bytes), ~46.7 MB:
//   [0,          29360128)  NO   fp32 [B][1792]
//   [29360128,   37748736)  hH   fp16 [B][1024]
//   [37748736,   41406464)  W2T  fp16 [1786][1024] -> after GEMM2: Vh, Vl (fp16 [B][256])
//   [41406464,   41938944)  W1T  fp16 [1024][260]
//   [46137344,   46268416)  Gh   fp16 [256][256]
//   [46268416,   46399488)  Gl   fp16 [256][256]  (scaled x2048)
//   [46399488,   46400512)  zc   fp32 [256]
//   [46400512,   46531584)  Uh   fp16 [256][256]
//   [46531584,   46662656)  Ul   fp16 [256][256]  (scaled x2048)

#define NUMV 256
#define QP_ITERS 5
#define NO_LD 1792
#define LSCALE 2048.0f
#define INV_LSCALE (1.0f / 2048.0f)

typedef _Float16 f16x4 __attribute__((ext_vector_type(4)));
typedef _Float16 f16x8 __attribute__((ext_vector_type(8)));
typedef float f32x4 __attribute__((ext_vector_type(4)));

// ---------------- compile-time pentadiagonal Cholesky tables ----------------
struct FacT {
  double invd[256];
  double l1[257];
  double l2[258];
  double z[256];
  float  zcf[256];
};

constexpr double csqrt_(double x) {
  double g = (x > 1.0) ? x : 1.0;
  for (int i = 0; i < 64; ++i) g = 0.5 * (g + x / g);
  return g;
}

constexpr FacT make_fac() {
  FacT f{};
  const double T = 0.05, a = 1.0 / (T * T), b2 = a * a;
  double c0[256] = {}, c1[255] = {}, c2[254] = {};
  double dd[256] = {}, l1[256] = {}, l2[256] = {};
  for (int j = 0; j < 256; j++) {
    double cd1 = (j == 0 || j == 255) ? 1.0 : 2.0;
    double cd2 = (j == 0 || j == 255) ? 1.0 : ((j == 1 || j == 254) ? 5.0 : 6.0);
    c0[j] = 3.0 + 2.0 * a * cd1 + 2.0 * b2 * cd2;
  }
  for (int j = 0; j < 255; j++) c1[j] = -2.0 * a + 2.0 * b2 * ((j == 0 || j == 254) ? -2.0 : -4.0);
  for (int j = 0; j < 254; j++) c2[j] = 2.0 * b2;
  dd[0] = csqrt_(c0[0]); l1[0] = 0.0; l2[0] = 0.0;
  l1[1] = c1[0] / dd[0]; l2[1] = 0.0;
  dd[1] = csqrt_(c0[1] - l1[1] * l1[1]);
  for (int j = 2; j < 256; j++) {
    l2[j] = c2[j - 2] / dd[j - 2];
    l1[j] = (c1[j - 1] - l2[j] * l1[j - 1]) / dd[j - 1];
    dd[j] = csqrt_(c0[j] - l1[j] * l1[j] - l2[j] * l2[j]);
  }
  for (int j = 0; j < 256; j++) f.invd[j] = 1.0 / dd[j];
  for (int j = 0; j < 256; j++) f.l1[j] = l1[j];
  f.l1[256] = 0.0;
  for (int j = 0; j < 256; j++) f.l2[j] = l2[j];
  f.l2[256] = 0.0; f.l2[257] = 0.0;
  double w[256] = {}, zz[256] = {};
  w[0] = 1.0 / dd[0];
  w[1] = (-l1[1] * w[0]) / dd[1];
  for (int j = 2; j < 256; j++) w[j] = (-l1[j] * w[j - 1] - l2[j] * w[j - 2]) / dd[j];
  zz[255] = w[255] / dd[255];
  zz[254] = (w[254] - l1[255] * zz[255]) / dd[254];
  for (int j = 253; j >= 0; j--)
    zz[j] = (w[j] - l1[j + 1] * zz[j + 1] - l2[j + 2] * zz[j + 2]) / dd[j];
  for (int j = 0; j < 256; j++) f.z[j] = zz[j];
  for (int j = 0; j < 256; j++) f.zcf[j] = (float)(zz[j] / zz[0]);
  return f;
}

constexpr FacT FAC_HOST = make_fac();
__constant__ FacT FAC = FAC_HOST;

// ---- compile-time U = L^{-1}: quarter (64 columns) per constexpr evaluation ----
struct UQ { float u[64][256]; };

constexpr UQ make_uq(int cbase) {
  UQ q{};
  const double T = 0.05, a = 1.0 / (T * T), b2 = a * a;
  double c0a[256] = {}, c1a[255] = {}, c2a[254] = {};
  double dd[256] = {}, l1[256] = {}, l2[256] = {};
  for (int j = 0; j < 256; j++) {
    double cd1 = (j == 0 || j == 255) ? 1.0 : 2.0;
    double cd2 = (j == 0 || j == 255) ? 1.0 : ((j == 1 || j == 254) ? 5.0 : 6.0);
    c0a[j] = 3.0 + 2.0 * a * cd1 + 2.0 * b2 * cd2;
  }
  for (int j = 0; j < 255; j++) c1a[j] = -2.0 * a + 2.0 * b2 * ((j == 0 || j == 254) ? -2.0 : -4.0);
  for (int j = 0; j < 254; j++) c2a[j] = 2.0 * b2;
  dd[0] = csqrt_(c0a[0]); l1[0] = 0.0; l2[0] = 0.0;
  l1[1] = c1a[0] / dd[0]; l2[1] = 0.0;
  dd[1] = csqrt_(c0a[1] - l1[1] * l1[1]);
  for (int j = 2; j < 256; j++) {
    l2[j] = c2a[j - 2] / dd[j - 2];
    l1[j] = (c1a[j - 1] - l2[j] * l1[j - 1]) / dd[j - 1];
    dd[j] = csqrt_(c0a[j] - l1[j] * l1[j] - l2[j] * l2[j]);
  }
  for (int c = cbase; c < cbase + 64; ++c) {
    double w1 = 0.0, w2 = 0.0;
    for (int j = c; j < 256; ++j) {
      const double rhs = (j == c) ? 1.0 : 0.0;
      const double wj = (rhs - l1[j] * w1 - l2[j] * w2) / dd[j];
      q.u[c - cbase][j] = (float)wj;
      w2 = w1; w1 = wj;
    }
  }
  return q;
}

constexpr UQ UQ0_H = make_uq(0);
constexpr UQ UQ1_H = make_uq(64);
constexpr UQ UQ2_H = make_uq(128);
constexpr UQ UQ3_H = make_uq(192);
__constant__ UQ UFQ0 = UQ0_H;
__constant__ UQ UFQ1 = UQ1_H;
__constant__ UQ UFQ2 = UQ2_H;
__constant__ UQ UFQ3 = UQ3_H;

// ---- split compile-time U into scaled split-fp16 Uh/Ul; write zc ----
__global__ __launch_bounds__(256) void split_u(
    _Float16* __restrict__ Uh, _Float16* __restrict__ Ul, float* __restrict__ zc)
{
  const int c = blockIdx.x, j = threadIdx.x;
  float wf;
  if (c < 64)       wf = UFQ0.u[c][j];
  else if (c < 128) wf = UFQ1.u[c - 64][j];
  else if (c < 192) wf = UFQ2.u[c - 128][j];
  else              wf = UFQ3.u[c - 192][j];
  const _Float16 h = (_Float16)wf;
  Uh[(size_t)c * 256 + j] = h;
  Ul[(size_t)c * 256 + j] = (_Float16)((wf - (float)h) * LSCALE);
  if (c == 0) zc[j] = FAC.zcf[j];
}

// ---- G = UT * UT^T - z z^T/z0 via split-fp16 MFMA; output re-split to Gh/Gl ----
__global__ __launch_bounds__(64) void gemm_g(
    const _Float16* __restrict__ Uh, const _Float16* __restrict__ Ul,
    _Float16* __restrict__ Gh, _Float16* __restrict__ Gl)
{
  const int lane = threadIdx.x;
  const int lr = lane & 15, lg = lane >> 4;
  const int m0 = blockIdx.x * 16, n0 = blockIdx.y * 32;
  f32x4 accH[2], accL[2];
#pragma unroll
  for (int nf = 0; nf < 2; nf++) { accH[nf] = (f32x4)0.0f; accL[nf] = (f32x4)0.0f; }
  const size_t arow = (size_t)(m0 + lr) * 256 + lg * 8;
#pragma unroll 2
  for (int k0 = 0; k0 < 256; k0 += 32) {
    const f16x8 ah = *reinterpret_cast<const f16x8*>(&Uh[arow + k0]);
    const f16x8 al = *reinterpret_cast<const f16x8*>(&Ul[arow + k0]);
#pragma unroll
    for (int nf = 0; nf < 2; nf++) {
      const size_t bidx = (size_t)(n0 + nf * 16 + lr) * 256 + k0 + lg * 8;
      const f16x8 bh = *reinterpret_cast<const f16x8*>(&Uh[bidx]);
      const f16x8 bl = *reinterpret_cast<const f16x8*>(&Ul[bidx]);
      accH[nf] = __builtin_amdgcn_mfma_f32_16x16x32_f16(ah, bh, accH[nf], 0, 0, 0);
      accL[nf] = __builtin_amdgcn_mfma_f32_16x16x32_f16(ah, bl, accL[nf], 0, 0, 0);
      accL[nf] = __builtin_amdgcn_mfma_f32_16x16x32_f16(al, bh, accL[nf], 0, 0, 0);
    }
  }
  const int row0 = m0 + lg * 4;
#pragma unroll
  for (int nf = 0; nf < 2; nf++) {
    const int col = n0 + nf * 16 + lr;
    const double zcd = FAC.z[col] / FAC.z[0];
#pragma unroll
    for (int r = 0; r < 4; r++) {
      const int row = row0 + r;
      const float g = accH[nf][r] + accL[nf][r] * INV_LSCALE
                    - (float)(FAC.z[row] * zcd);
      const _Float16 gh = (_Float16)g;
      Gh[(size_t)row * 256 + col] = gh;
      Gl[(size_t)row * 256 + col] = (_Float16)((g - (float)gh) * LSCALE);
    }
  }
}

// ---------------- transpose + fp32->fp16 convert: in [K][N] -> out [N][K] ----------------
__global__ __launch_bounds__(256) void transpose_cvt(
    const float* __restrict__ in, _Float16* __restrict__ out, int K, int N)
{
  __shared__ float t[32][33];
  const int bk = blockIdx.x * 32, bn = blockIdx.y * 32;
  const int x = threadIdx.x, y = threadIdx.y;
  for (int yy = y; yy < 32; yy += 8) {
    const int k = bk + yy, n = bn + x;
    t[yy][x] = (k < K && n < N) ? in[(size_t)k * N + n] : 0.f;
  }
  __syncthreads();
  for (int yy = y; yy < 32; yy += 8) {
    const int n = bn + yy, k = bk + x;
    if (n < N && k < K) out[(size_t)n * K + k] = (_Float16)t[x][yy];
  }
}

// ---------------- MFMA GEMM (BK=32, handles fp32 A + K tails): GEMM1 ----------------
template<bool A_FP32, bool OUT_H16>
__global__ __launch_bounds__(256) void mfma_gemm(
    const void* __restrict__ Av, const _Float16* __restrict__ Bt,
    const float* __restrict__ bias, void* __restrict__ Cv,
    int M, int Nv, int K, int lda, int ldk, int ldc)
{
  __shared__ _Float16 At[128][40];
  __shared__ _Float16 Bs[128][40];
  const int tid = threadIdx.x;
  const int lane = tid & 63, wid = tid >> 6;
  const int wr = wid >> 1, wc = wid & 1;
  const int lrow = lane & 15, lb = lane >> 4;
  const int m0 = blockIdx.x * 128, n0 = blockIdx.y * 128;
  const int srow = tid >> 1, skh = (tid & 1) * 16;

  f32x4 acc[4][4];
#pragma unroll
  for (int i = 0; i < 4; i++)
#pragma unroll
    for (int j = 0; j < 4; j++) acc[i][j] = (f32x4)0.0f;

  const int nsteps = (K + 31) / 32;
  for (int t = 0; t < nsteps; ++t) {
    const int k0 = t * 32;
    if (A_FP32) {
      const float* A = (const float*)Av;
#pragma unroll
      for (int i = 0; i < 4; i++) {
        const int k = k0 + skh + i * 4;
        f16x4 hv = {};
        if (k + 4 <= K) {
          const float4 v = *reinterpret_cast<const float4*>(&A[(size_t)(m0 + srow) * lda + k]);
          hv[0] = (_Float16)v.x; hv[1] = (_Float16)v.y;
          hv[2] = (_Float16)v.z; hv[3] = (_Float16)v.w;
        } else if (k < K) {
          for (int e = 0; e < 4; e++)
            if (k + e < K) hv[e] = (_Float16)A[(size_t)(m0 + srow) * lda + k + e];
        }
        *reinterpret_cast<f16x4*>(&At[srow][skh + i * 4]) = hv;
      }
    } else {
      const _Float16* A = (const _Float16*)Av;
#pragma unroll
      for (int i = 0; i < 4; i++) {
        const int k = k0 + skh + i * 4;
        f16x4 hv = {};
        if (k + 4 <= K) hv = *reinterpret_cast<const f16x4*>(&A[(size_t)(m0 + srow) * lda + k]);
        *reinterpret_cast<f16x4*>(&At[srow][skh + i * 4]) = hv;
      }
    }
    {
      const int n = n0 + srow;
#pragma unroll
      for (int i = 0; i < 4; i++) {
        const int k = k0 + skh + i * 4;
        f16x4 hv = {};
        if (n < Nv && k + 4 <= K)
          hv = *reinterpret_cast<const f16x4*>(&Bt[(size_t)n * ldk + k]);
        *reinterpret_cast<f16x4*>(&Bs[srow][skh + i * 4]) = hv;
      }
    }
    __syncthreads();
    f16x8 af[4], bf[4];
#pragma unroll
    for (int i = 0; i < 4; i++)
      af[i] = *reinterpret_cast<const f16x8*>(&At[wr * 64 + i * 16 + lrow][lb * 8]);
#pragma unroll
    for (int j = 0; j < 4; j++)
      bf[j] = *reinterpret_cast<const f16x8*>(&Bs[wc * 64 + j * 16 + lrow][lb * 8]);
#pragma unroll
    for (int i = 0; i < 4; i++)
#pragma unroll
      for (int j = 0; j < 4; j++)
        acc[i][j] = __builtin_amdgcn_mfma_f32_16x16x32_f16(af[i], bf[j], acc[i][j], 0, 0, 0);
    __syncthreads();
  }
#pragma unroll
  for (int i = 0; i < 4; i++) {
#pragma unroll
    for (int j = 0; j < 4; j++) {
      const int gcol = n0 + wc * 64 + j * 16 + lrow;
      if (gcol < Nv) {
        const float bv = bias[gcol];
#pragma unroll
        for (int r = 0; r < 4; r++) {
          const int grow = m0 + wr * 64 + i * 16 + lb * 4 + r;
          float v = acc[i][j][r] + bv;
          if (OUT_H16) {
            v = fmaxf(v, 0.f);
            ((_Float16*)Cv)[(size_t)grow * ldc + gcol] = (_Float16)v;
          } else {
            ((float*)Cv)[(size_t)grow * ldc + gcol] = v;
          }
        }
      }
    }
  }
}

// ---------------- MFMA GEMM BK=64 (fp16 A, K%64==0, fp32 out): GEMM2 ----------------
__global__ __launch_bounds__(256) void mfma_gemm64(
    const _Float16* __restrict__ A, const _Float16* __restrict__ Bt,
    const float* __restrict__ bias, float* __restrict__ C,
    int M, int Nv, int K, int lda, int ldk, int ldc)
{
  __shared__ _Float16 At[128][72];
  __shared__ _Float16 Bs[128][72];
  const int tid = threadIdx.x;
  const int lane = tid & 63, wid = tid >> 6;
  const int wr = wid >> 1, wc = wid & 1;
  const int lrow = lane & 15, lb = lane >> 4;
  const int m0 = blockIdx.x * 128, n0 = blockIdx.y * 128;
  const int srow = tid >> 1, sh = (tid & 1) * 32;

  f32x4 acc[4][4];
#pragma unroll
  for (int i = 0; i < 4; i++)
#pragma unroll
    for (int j = 0; j < 4; j++) acc[i][j] = (f32x4)0.0f;

  const int nsteps = K >> 6;
  for (int t = 0; t < nsteps; ++t) {
    const int k0 = t * 64;
    const _Float16* asrc = &A[(size_t)(m0 + srow) * lda + k0 + sh];
#pragma unroll
    for (int i = 0; i < 4; i++)
      *reinterpret_cast<f16x8*>(&At[srow][sh + i * 8]) =
          *reinterpret_cast<const f16x8*>(asrc + i * 8);
    {
      const int n = n0 + srow;
      const _Float16* bsrc = &Bt[(size_t)n * ldk + k0 + sh];
#pragma unroll
      for (int i = 0; i < 4; i++) {
        f16x8 hv = {};
        if (n < Nv) hv = *reinterpret_cast<const f16x8*>(bsrc + i * 8);
        *reinterpret_cast<f16x8*>(&Bs[srow][sh + i * 8]) = hv;
      }
    }
    __syncthreads();
#pragma unroll
    for (int h = 0; h < 2; h++) {
      f16x8 af[4], bf[4];
#pragma unroll
      for (int i = 0; i < 4; i++)
        af[i] = *reinterpret_cast<const f16x8*>(&At[wr * 64 + i * 16 + lrow][h * 32 + lb * 8]);
#pragma unroll
      for (int j = 0; j < 4; j++)
        bf[j] = *reinterpret_cast<const f16x8*>(&Bs[wc * 64 + j * 16 + lrow][h * 32 + lb * 8]);
#pragma unroll
      for (int i = 0; i < 4; i++)
#pragma unroll
        for (int j = 0; j < 4; j++)
          acc[i][j] = __builtin_amdgcn_mfma_f32_16x16x32_f16(af[i], bf[j], acc[i][j], 0, 0, 0);
    }
    __syncthreads();
  }
#pragma unroll
  for (int i = 0; i < 4; i++) {
#pragma unroll
    for (int j = 0; j < 4; j++) {
      const int gcol = n0 + wc * 64 + j * 16 + lrow;
      if (gcol < Nv) {
        const float bv = bias[gcol];
#pragma unroll
        for (int r = 0; r < 4; r++) {
          const int grow = m0 + wr * 64 + i * 16 + lb * 4 + r;
          C[(size_t)grow * ldc + gcol] = acc[i][j][r] + bv;
        }
      }
    }
  }
}

// ---------------- initial rhs V0 = lam0 + ss + b_aug0 @ A_control (scaled split) ----
__global__ __launch_bounds__(256) void init_v(
    const float* __restrict__ NO, const float* __restrict__ ss,
    const float* __restrict__ p_smax, const float* __restrict__ p_smin,
    const float* __restrict__ p_sdmax, const float* __restrict__ p_sdmin,
    const float* __restrict__ p_sddmax, const float* __restrict__ p_sddmin,
    _Float16* __restrict__ Vh, _Float16* __restrict__ Vl, int B)
{
  __shared__ float d1s[258], d2s[258];
  const int r = blockIdx.x, j = threadIdx.x;
  const float K0 = *p_smax + *p_smin, K1 = *p_sdmax + *p_sdmin, K2 = *p_sddmax + *p_sddmin;
  const float invT = 20.f, invT2 = 400.f;
  const float* no = NO + (size_t)r * NO_LD;
  float s1 = fmaxf(0.f, no[256 + j]), s2 = fmaxf(0.f, no[512 + j]);
  float D0 = K0 - s1 + s2;
  float D1 = 0.f, D2 = 0.f;
  if (j < 255) D1 = K1 - fmaxf(0.f, no[768 + j]) + fmaxf(0.f, no[1023 + j]);
  if (j < 254) D2 = K2 - fmaxf(0.f, no[1278 + j]) + fmaxf(0.f, no[1532 + j]);
  d1s[2 + j] = D1; d2s[2 + j] = D2;
  if (j < 2) { d1s[j] = 0.f; d2s[j] = 0.f; }
  __syncthreads();
  float qn = D0 + (d1s[j + 1] - d1s[j + 2]) * invT
                + (d2s[j] - 2.f * d2s[j + 1] + d2s[j + 2]) * invT2;
  const float vn = no[j] + ss[(size_t)r * NUMV + j] + qn;
  const _Float16 vh = (_Float16)vn;
  Vh[(size_t)r * NUMV + j] = vh;
  Vl[(size_t)r * NUMV + j] = (_Float16)((vn - (float)vh) * LSCALE);
}

// ---- ALL 5 QP iterations in one kernel. Block = 16 rows, 1024 threads (16 waves).
// Wave w = 16-col MFMA slice; update thread = (j = tid&255, half = tid>>8) x 4 rows.
__global__ __launch_bounds__(1024) void qp_solve5(
    const _Float16* __restrict__ Vh0, const _Float16* __restrict__ Vl0,
    const _Float16* __restrict__ Gh, const _Float16* __restrict__ Gl,
    const float* __restrict__ beq, const float* __restrict__ zc,
    const float* __restrict__ NO, const float* __restrict__ ss,
    const float* __restrict__ p_smax, const float* __restrict__ p_smin,
    const float* __restrict__ p_sdmax, const float* __restrict__ p_sdmin,
    const float* __restrict__ p_sddmax, const float* __restrict__ p_sddmin,
    float* __restrict__ out, int B)
{
  __shared__ float xsA[16][264], xsB[16][264];
  __shared__ _Float16 vhs[16][264], vls[16][264];
  __shared__ float zcs[256], beqs[16];
  __shared__ float red[16][4][3];
  const int tid = threadIdx.x;
  const int wave = tid >> 6, lane = tid & 63;
  const int lr = lane & 15, lg = lane >> 4;
  const int m0 = blockIdx.x * 16;
  const int n0 = wave * 16;
  const int j = tid & 255, half = tid >> 8;    // half in 0..3

  // ---- stage V0 (4 halfs per thread), zc, beq; zero x pads ----
  {
    const int idx = tid * 4;
    const int rl = idx >> 8, c = idx & 255;
    *reinterpret_cast<f16x4*>(&vhs[rl][c]) =
        *reinterpret_cast<const f16x4*>(&Vh0[(size_t)(m0 + rl) * 256 + c]);
    *reinterpret_cast<f16x4*>(&vls[rl][c]) =
        *reinterpret_cast<const f16x4*>(&Vl0[(size_t)(m0 + rl) * 256 + c]);
  }
  if (tid < 256) zcs[tid] = zc[tid];
  if (tid < 16) {
    beqs[tid] = beq[m0 + tid];
    xsA[tid][0] = 0.f; xsA[tid][1] = 0.f; xsA[tid][258] = 0.f; xsA[tid][259] = 0.f;
    xsB[tid][0] = 0.f; xsB[tid][1] = 0.f; xsB[tid][258] = 0.f; xsB[tid][259] = 0.f;
  }

  // ---- per-thread persistent state: lam + ss for 4 (row,col) pairs ----
  float lamr[4], ssv[4];
#pragma unroll
  for (int rr = 0; rr < 4; rr++) {
    const int gr = m0 + half * 4 + rr;
    ssv[rr] = ss[(size_t)gr * NUMV + j];
    lamr[rr] = NO[(size_t)gr * NO_LD + j];
  }
  float accP = 0.f, accF = 0.f;

  const float smax = *p_smax, smin = *p_smin;
  const float sdmax = *p_sdmax, sdmin = *p_sdmin;
  const float sddmax = *p_sddmax, sddmin = *p_sddmin;
  const float invT = 20.f, invT2 = 400.f;
  const bool h1 = j < 255, h2 = j < 254;

  const size_t primOff = (size_t)B * NUMV;
  const size_t fpOff = primOff + (size_t)QP_ITERS * B;
  const size_t accPOff = fpOff + (size_t)QP_ITERS * B;
  const size_t accFOff = accPOff + (size_t)B;

  float (*xc)[264] = xsA;
  float (*xp)[264] = xsB;

  for (int it = 0; it < QP_ITERS; ++it) {
    __syncthreads();    // vhs/vls ready (staged or updated)

    // ---- Phase 1: MFMA solve (validated split-fp16 path; V from LDS) ----
    f32x4 accH = (f32x4)0.0f, accL = (f32x4)0.0f;
#pragma unroll 2
    for (int k0 = 0; k0 < 256; k0 += 32) {
      const f16x8 ah = *reinterpret_cast<const f16x8*>(&vhs[lr][k0 + lg * 8]);
      const f16x8 al = *reinterpret_cast<const f16x8*>(&vls[lr][k0 + lg * 8]);
      const size_t bidx = (size_t)(n0 + lr) * 256 + k0 + lg * 8;
      const f16x8 bh = *reinterpret_cast<const f16x8*>(&Gh[bidx]);
      const f16x8 bl = *reinterpret_cast<const f16x8*>(&Gl[bidx]);
      accH = __builtin_amdgcn_mfma_f32_16x16x32_f16(ah, bh, accH, 0, 0, 0);
      accL = __builtin_amdgcn_mfma_f32_16x16x32_f16(ah, bl, accL, 0, 0, 0);
      accL = __builtin_amdgcn_mfma_f32_16x16x32_f16(al, bh, accL, 0, 0, 0);
    }
    {
      const int r0l = lg * 4;
      const int col = n0 + lr;
      const float zv = zcs[col];
#pragma unroll
      for (int r = 0; r < 4; r++)
        xc[r0l + r][col + 2] = accH[r] + accL[r] * INV_LSCALE + beqs[r0l + r] * zv;
    }
    __syncthreads();    // x ready

    // ---- Phase 2: update (validated local-recompute stencils), 4 rows/thread ----
#pragma unroll
    for (int rr = 0; rr < 4; rr++) {
      const int rl = half * 4 + rr;
      const int gr = m0 + rl;
      const float xm2 = xc[rl][j];
      const float xm1 = xc[rl][j + 1];
      const float x0  = xc[rl][j + 2];
      const float x1  = xc[rl][j + 3];
      const float x2  = xc[rl][j + 4];

      const float vj = (x1 - x0) * invT;
      const float aj = (x2 - 2.f * x1 + x0) * invT2;
      const float vm1 = (x0 - xm1) * invT;
      const float am1 = (x1 - 2.f * x0 + xm1) * invT2;
      const float am2 = (x0 - 2.f * xm1 + xm2) * invT2;

      const float rv0a = fmaxf(0.f, x0 - smax), rv0b = fmaxf(0.f, smin - x0);
      const float E0 = rv0a - rv0b;
      float rv1a = 0.f, rv1b = 0.f, rv2a = 0.f, rv2b = 0.f, E1 = 0.f, E2 = 0.f;
      if (h1) { rv1a = fmaxf(0.f, vj - sdmax); rv1b = fmaxf(0.f, sdmin - vj); E1 = rv1a - rv1b; }
      if (h2) { rv2a = fmaxf(0.f, aj - sddmax); rv2b = fmaxf(0.f, sddmin - aj); E2 = rv2a - rv2b; }
      float res2 = rv0a * rv0a + rv0b * rv0b + rv1a * rv1a + rv1b * rv1b
                 + rv2a * rv2a + rv2b * rv2b;

      const float E1m = (j >= 1) ? (fmaxf(0.f, vm1 - sdmax) - fmaxf(0.f, sdmin - vm1)) : 0.f;
      const float E2m1 = (j >= 1 && h1) ? (fmaxf(0.f, am1 - sddmax) - fmaxf(0.f, sddmin - am1)) : 0.f;
      const float E2m2 = (j >= 2) ? (fmaxf(0.f, am2 - sddmax) - fmaxf(0.f, sddmin - am2)) : 0.f;

      const float dl = E0 + (E1m - E1) * invT + (E2m2 - 2.f * E2m1 + E2) * invT2;
      const float lnew = lamr[rr] - dl;
      const float fpl2 = dl * dl;
      lamr[rr] = lnew;

      const float sn0a = fmaxf(0.f, smax - x0), sn0b = fmaxf(0.f, x0 - smin);
      float sn1a = 0.f, sn1b = 0.f, sn2a = 0.f, sn2b = 0.f;
      if (h1) { sn1a = fmaxf(0.f, sdmax - vj); sn1b = fmaxf(0.f, vj - sdmin); }
      if (h2) { sn2a = fmaxf(0.f, sddmax - aj); sn2b = fmaxf(0.f, aj - sddmin); }

      float sp0a, sp0b, sp1a = 0.f, sp1b = 0.f, sp2a = 0.f, sp2b = 0.f;
      if (it == 0) {
        const float* no = NO + (size_t)gr * NO_LD;
        sp0a = fmaxf(0.f, no[256 + j]); sp0b = fmaxf(0.f, no[512 + j]);
        if (h1) { sp1a = fmaxf(0.f, no[768 + j]); sp1b = fmaxf(0.f, no[1023 + j]); }
        if (h2) { sp2a = fmaxf(0.f, no[1278 + j]); sp2b = fmaxf(0.f, no[1532 + j]); }
      } else {
        const float p0 = xp[rl][j + 2], p1 = xp[rl][j + 3], p2 = xp[rl][j + 4];
        const float vp = (p1 - p0) * invT;
        const float ap = (p2 - 2.f * p1 + p0) * invT2;
        sp0a = fmaxf(0.f, smax - p0); sp0b = fmaxf(0.f, p0 - smin);
        if (h1) { sp1a = fmaxf(0.f, sdmax - vp); sp1b = fmaxf(0.f, vp - sdmin); }
        if (h2) { sp2a = fmaxf(0.f, sddmax - ap); sp2b = fmaxf(0.f, ap - sddmin); }
      }
      const float d0a = sp0a - sn0a, d0b = sp0b - sn0b;
      const float d1a = sp1a - sn1a, d1b = sp1b - sn1b;
      const float d2a = sp2a - sn2a, d2b = sp2b - sn2b;
      float fps2 = d0a * d0a + d0b * d0b + d1a * d1a + d1b * d1b
                 + d2a * d2a + d2b * d2b;

      const float D0 = fminf(smax, x0) + fmaxf(smin, x0);
      const float D1 = h1 ? (fminf(sdmax, vj) + fmaxf(sdmin, vj)) : 0.f;
      const float D2 = h2 ? (fminf(sddmax, aj) + fmaxf(sddmin, aj)) : 0.f;
      const float D1m = (j >= 1) ? (fminf(sdmax, vm1) + fmaxf(sdmin, vm1)) : 0.f;
      const float D2m1 = (j >= 1 && h1) ? (fminf(sddmax, am1) + fmaxf(sddmin, am1)) : 0.f;
      const float D2m2 = (j >= 2) ? (fminf(sddmax, am2) + fmaxf(sddmin, am2)) : 0.f;

      if (it < QP_ITERS - 1) {
        const float vn = lnew + ssv[rr]
                       + D0 + (D1m - D1) * invT + (D2m2 - 2.f * D2m1 + D2) * invT2;
        const _Float16 vh16 = (_Float16)vn;
        vhs[rl][j] = vh16;
        vls[rl][j] = (_Float16)((vn - (float)vh16) * LSCALE);
      } else {
        out[(size_t)gr * NUMV + j] = x0;
      }

      float a = res2, b = fps2, c = fpl2;
      for (int o = 32; o > 0; o >>= 1) {
        a += __shfl_down(a, o);
        b += __shfl_down(b, o);
        c += __shfl_down(c, o);
      }
      if (lane == 0) { red[wave][rr][0] = a; red[wave][rr][1] = b; red[wave][rr][2] = c; }
    }
    __syncthreads();    // red + vhs/vls ready

    if (tid < 16) {
      const int rl = tid, hf = rl >> 2, rr = rl & 3;
      const int w0 = hf * 4;
      const float r2 = red[w0][rr][0] + red[w0 + 1][rr][0] + red[w0 + 2][rr][0] + red[w0 + 3][rr][0];
      const float s2 = red[w0][rr][1] + red[w0 + 1][rr][1] + red[w0 + 2][rr][1] + red[w0 + 3][rr][1];
      const float l2 = red[w0][rr][2] + red[w0 + 1][rr][2] + red[w0 + 2][rr][2] + red[w0 + 3][rr][2];
      const float pr = sqrtf(r2);
      const float fp = sqrtf(s2) + sqrtf(l2);
      out[primOff + (size_t)it * B + m0 + rl] = pr;
      out[fpOff + (size_t)it * B + m0 + rl] = fp;
      accP += pr; accF += fp;
    }
    // swap x buffers
    float (*t)[264] = xc; xc = xp; xp = t;
  }
  if (tid < 16) {
    out[accPOff + m0 + tid] = accP * (1.f / QP_ITERS);
    out[accFOff + m0 + tid] = accF * (1.f / QP_ITERS);
  }
}

extern "C" void kernel_launch(void* const* d_in, const int* in_sizes, int n_in,
                              void* d_out, int out_size, void* d_ws, size_t ws_size,
                              hipStream_t stream)
{
  const float* inp = (const float*)d_in[0];       // [B][260]
  const float* sinit = (const float*)d_in[1];     // [B][1]
  const float* ssamp = (const float*)d_in[2];     // [B][256]
  const float* p_smax = (const float*)d_in[3];
  const float* p_smin = (const float*)d_in[4];
  const float* p_sdmax = (const float*)d_in[5];
  const float* p_sdmin = (const float*)d_in[6];
  const float* p_sddmax = (const float*)d_in[7];
  const float* p_sddmin = (const float*)d_in[8];
  const float* W1 = (const float*)d_in[11];       // [260][1024]
  const float* b1 = (const float*)d_in[12];       // [1024]
  const float* W2 = (const float*)d_in[13];       // [1024][1786]
  const float* b2 = (const float*)d_in[14];       // [1786]
  float* out = (float*)d_out;

  const int B = in_sizes[1];                      // 4096
  const int IND = in_sizes[9];                    // 260
  const int H = in_sizes[12];                     // 1024
  const int OUTN = in_sizes[14];                  // 1786

  char* ws = (char*)d_ws;
  float* NO = (float*)ws;                                      // [B][1792] fp32
  char* p = ws + (size_t)B * NO_LD * 4;                        // 29,360,128
  _Float16* hH = (_Float16*)p;                                 // [B][1024] fp16
  char* q = p + (size_t)B * H * 2;                             // 37,748,736
  _Float16* W2T = (_Float16*)q;                                // [1786][1024] fp16 (dead after GEMM2)
  _Float16* Vh = (_Float16*)q;                                 // alias: fp16 [B][256]
  _Float16* Vl = (_Float16*)(q + (size_t)B * NUMV * 2);        // alias: fp16 [B][256]
  char* q2 = q + (size_t)OUTN * H * 2;                         // 41,406,464
  _Float16* W1T = (_Float16*)q2;                               // [1024][260] fp16 (dead after GEMM1)
  char* r4 = ws + 46137344;                                    // 46,137,344
  _Float16* Gh = (_Float16*)r4;                                // [256][256] fp16
  _Float16* Gl = (_Float16*)(r4 + 131072);                     // [256][256] fp16 (x2048)
  float* zc = (float*)(r4 + 262144);                           // [256] fp32
  _Float16* Uh = (_Float16*)(r4 + 263168);                     // [256][256] fp16 (U^T)
  _Float16* Ul = (_Float16*)(r4 + 263168 + 131072);            // [256][256] fp16 (x2048)

  split_u<<<256, 256, 0, stream>>>(Uh, Ul, zc);
  {
    dim3 g(16, 8);
    gemm_g<<<g, 64, 0, stream>>>(Uh, Ul, Gh, Gl);
  }
  {
    dim3 g((IND + 31) / 32, (H + 31) / 32), blk(32, 8);
    transpose_cvt<<<g, blk, 0, stream>>>(W1, W1T, IND, H);
  }
  {
    dim3 g((H + 31) / 32, (OUTN + 31) / 32), blk(32, 8);
    transpose_cvt<<<g, blk, 0, stream>>>(W2, W2T, H, OUTN);
  }
  {
    dim3 g(B / 128, H / 128);
    mfma_gemm<true, true><<<g, 256, 0, stream>>>(inp, W1T, b1, hH, B, H, IND, IND, IND, H);
  }
  {
    dim3 g(B / 128, (OUTN + 127) / 128);
    mfma_gemm64<<<g, 256, 0, stream>>>(hH, W2T, b2, NO, B, OUTN, H, H, H, NO_LD);
  }
  init_v<<<B, 256, 0, stream>>>(NO, ssamp, p_smax, p_smin, p_sdmax, p_sdmin,
                                p_sddmax, p_sddmin, Vh, Vl, B);
  qp_solve5<<<B / 16, 1024, 0, stream>>>(Vh, Vl, Gh, Gl, sinit, zc, NO, ssamp,
                                         p_smax, p_smin, p_sdmax, p_sdmin,
                                         p_sddmax, p_sddmin, out, B);
}

// Round 19
// 152.930 us; speedup vs baseline: 2.0227x; 1.0652x over previous
//
#include <hip/hip_runtime.h>
#include <cstddef>

// learned_qp_solver: B=4096, NUM=256, NC=1530, IND=260, H=1024, OUT=1786, 5 iters.
//
//   KKT solve closed form:  x = G v + (b_eq/z0) z,  G = C^{-1} - z z^T / z0 (symmetric)
//   MLP on matrix cores: v_mfma_f32_16x16x32_f16 (BK=32 GEMM1 / BK=64 GEMM2).
//   Solve: scaled split-fp16 (Gl,Vl x2048 dodge fp16 denormal flush in MFMA).
//   G build: U = L^{-1} at COMPILE TIME (constexpr quarters); gemm_g on MFMA.
//   qp_solve5: ALL 5 QP iterations in one kernel; block owns 16 rows; V in LDS,
//   lam/ss in registers, x double-buffered in LDS; 1024 threads (16 waves).
//   Round-19 (round-18 lesson: grid=1 block/CU caps occupancy; G L2-loads on the
//   MFMA chain + 3 barriers/iter dominate): G fragments HOISTED to registers
//   (16x f16x8 = 64 VGPR, loaded once; zero global loads in the loop) and
//   loop-top barrier removed (2 barriers/iter).
//
// ws layout (bytes), ~46.7 MB:
//   [0,          29360128)  NO   fp32 [B][1792]
//   [29360128,   37748736)  hH   fp16 [B][1024]
//   [37748736,   41406464)  W2T  fp16 [1786][1024] -> after GEMM2: Vh, Vl (fp16 [B][256])
//   [41406464,   41938944)  W1T  fp16 [1024][260]
//   [46137344,   46268416)  Gh   fp16 [256][256]
//   [46268416,   46399488)  Gl   fp16 [256][256]  (scaled x2048)
//   [46399488,   46400512)  zc   fp32 [256]
//   [46400512,   46531584)  Uh   fp16 [256][256]
//   [46531584,   46662656)  Ul   fp16 [256][256]  (scaled x2048)

#define NUMV 256
#define QP_ITERS 5
#define NO_LD 1792
#define LSCALE 2048.0f
#define INV_LSCALE (1.0f / 2048.0f)

typedef _Float16 f16x4 __attribute__((ext_vector_type(4)));
typedef _Float16 f16x8 __attribute__((ext_vector_type(8)));
typedef float f32x4 __attribute__((ext_vector_type(4)));

// ---------------- compile-time pentadiagonal Cholesky tables ----------------
struct FacT {
  double invd[256];
  double l1[257];
  double l2[258];
  double z[256];
  float  zcf[256];
};

constexpr double csqrt_(double x) {
  double g = (x > 1.0) ? x : 1.0;
  for (int i = 0; i < 64; ++i) g = 0.5 * (g + x / g);
  return g;
}

constexpr FacT make_fac() {
  FacT f{};
  const double T = 0.05, a = 1.0 / (T * T), b2 = a * a;
  double c0[256] = {}, c1[255] = {}, c2[254] = {};
  double dd[256] = {}, l1[256] = {}, l2[256] = {};
  for (int j = 0; j < 256; j++) {
    double cd1 = (j == 0 || j == 255) ? 1.0 : 2.0;
    double cd2 = (j == 0 || j == 255) ? 1.0 : ((j == 1 || j == 254) ? 5.0 : 6.0);
    c0[j] = 3.0 + 2.0 * a * cd1 + 2.0 * b2 * cd2;
  }
  for (int j = 0; j < 255; j++) c1[j] = -2.0 * a + 2.0 * b2 * ((j == 0 || j == 254) ? -2.0 : -4.0);
  for (int j = 0; j < 254; j++) c2[j] = 2.0 * b2;
  dd[0] = csqrt_(c0[0]); l1[0] = 0.0; l2[0] = 0.0;
  l1[1] = c1[0] / dd[0]; l2[1] = 0.0;
  dd[1] = csqrt_(c0[1] - l1[1] * l1[1]);
  for (int j = 2; j < 256; j++) {
    l2[j] = c2[j - 2] / dd[j - 2];
    l1[j] = (c1[j - 1] - l2[j] * l1[j - 1]) / dd[j - 1];
    dd[j] = csqrt_(c0[j] - l1[j] * l1[j] - l2[j] * l2[j]);
  }
  for (int j = 0; j < 256; j++) f.invd[j] = 1.0 / dd[j];
  for (int j = 0; j < 256; j++) f.l1[j] = l1[j];
  f.l1[256] = 0.0;
  for (int j = 0; j < 256; j++) f.l2[j] = l2[j];
  f.l2[256] = 0.0; f.l2[257] = 0.0;
  double w[256] = {}, zz[256] = {};
  w[0] = 1.0 / dd[0];
  w[1] = (-l1[1] * w[0]) / dd[1];
  for (int j = 2; j < 256; j++) w[j] = (-l1[j] * w[j - 1] - l2[j] * w[j - 2]) / dd[j];
  zz[255] = w[255] / dd[255];
  zz[254] = (w[254] - l1[255] * zz[255]) / dd[254];
  for (int j = 253; j >= 0; j--)
    zz[j] = (w[j] - l1[j + 1] * zz[j + 1] - l2[j + 2] * zz[j + 2]) / dd[j];
  for (int j = 0; j < 256; j++) f.z[j] = zz[j];
  for (int j = 0; j < 256; j++) f.zcf[j] = (float)(zz[j] / zz[0]);
  return f;
}

constexpr FacT FAC_HOST = make_fac();
__constant__ FacT FAC = FAC_HOST;

// ---- compile-time U = L^{-1}: quarter (64 columns) per constexpr evaluation ----
struct UQ { float u[64][256]; };

constexpr UQ make_uq(int cbase) {
  UQ q{};
  const double T = 0.05, a = 1.0 / (T * T), b2 = a * a;
  double c0a[256] = {}, c1a[255] = {}, c2a[254] = {};
  double dd[256] = {}, l1[256] = {}, l2[256] = {};
  for (int j = 0; j < 256; j++) {
    double cd1 = (j == 0 || j == 255) ? 1.0 : 2.0;
    double cd2 = (j == 0 || j == 255) ? 1.0 : ((j == 1 || j == 254) ? 5.0 : 6.0);
    c0a[j] = 3.0 + 2.0 * a * cd1 + 2.0 * b2 * cd2;
  }
  for (int j = 0; j < 255; j++) c1a[j] = -2.0 * a + 2.0 * b2 * ((j == 0 || j == 254) ? -2.0 : -4.0);
  for (int j = 0; j < 254; j++) c2a[j] = 2.0 * b2;
  dd[0] = csqrt_(c0a[0]); l1[0] = 0.0; l2[0] = 0.0;
  l1[1] = c1a[0] / dd[0]; l2[1] = 0.0;
  dd[1] = csqrt_(c0a[1] - l1[1] * l1[1]);
  for (int j = 2; j < 256; j++) {
    l2[j] = c2a[j - 2] / dd[j - 2];
    l1[j] = (c1a[j - 1] - l2[j] * l1[j - 1]) / dd[j - 1];
    dd[j] = csqrt_(c0a[j] - l1[j] * l1[j] - l2[j] * l2[j]);
  }
  for (int c = cbase; c < cbase + 64; ++c) {
    double w1 = 0.0, w2 = 0.0;
    for (int j = c; j < 256; ++j) {
      const double rhs = (j == c) ? 1.0 : 0.0;
      const double wj = (rhs - l1[j] * w1 - l2[j] * w2) / dd[j];
      q.u[c - cbase][j] = (float)wj;
      w2 = w1; w1 = wj;
    }
  }
  return q;
}

constexpr UQ UQ0_H = make_uq(0);
constexpr UQ UQ1_H = make_uq(64);
constexpr UQ UQ2_H = make_uq(128);
constexpr UQ UQ3_H = make_uq(192);
__constant__ UQ UFQ0 = UQ0_H;
__constant__ UQ UFQ1 = UQ1_H;
__constant__ UQ UFQ2 = UQ2_H;
__constant__ UQ UFQ3 = UQ3_H;

// ---- split compile-time U into scaled split-fp16 Uh/Ul; write zc ----
__global__ __launch_bounds__(256) void split_u(
    _Float16* __restrict__ Uh, _Float16* __restrict__ Ul, float* __restrict__ zc)
{
  const int c = blockIdx.x, j = threadIdx.x;
  float wf;
  if (c < 64)       wf = UFQ0.u[c][j];
  else if (c < 128) wf = UFQ1.u[c - 64][j];
  else if (c < 192) wf = UFQ2.u[c - 128][j];
  else              wf = UFQ3.u[c - 192][j];
  const _Float16 h = (_Float16)wf;
  Uh[(size_t)c * 256 + j] = h;
  Ul[(size_t)c * 256 + j] = (_Float16)((wf - (float)h) * LSCALE);
  if (c == 0) zc[j] = FAC.zcf[j];
}

// ---- G = UT * UT^T - z z^T/z0 via split-fp16 MFMA; output re-split to Gh/Gl ----
__global__ __launch_bounds__(64) void gemm_g(
    const _Float16* __restrict__ Uh, const _Float16* __restrict__ Ul,
    _Float16* __restrict__ Gh, _Float16* __restrict__ Gl)
{
  const int lane = threadIdx.x;
  const int lr = lane & 15, lg = lane >> 4;
  const int m0 = blockIdx.x * 16, n0 = blockIdx.y * 32;
  f32x4 accH[2], accL[2];
#pragma unroll
  for (int nf = 0; nf < 2; nf++) { accH[nf] = (f32x4)0.0f; accL[nf] = (f32x4)0.0f; }
  const size_t arow = (size_t)(m0 + lr) * 256 + lg * 8;
#pragma unroll 2
  for (int k0 = 0; k0 < 256; k0 += 32) {
    const f16x8 ah = *reinterpret_cast<const f16x8*>(&Uh[arow + k0]);
    const f16x8 al = *reinterpret_cast<const f16x8*>(&Ul[arow + k0]);
#pragma unroll
    for (int nf = 0; nf < 2; nf++) {
      const size_t bidx = (size_t)(n0 + nf * 16 + lr) * 256 + k0 + lg * 8;
      const f16x8 bh = *reinterpret_cast<const f16x8*>(&Uh[bidx]);
      const f16x8 bl = *reinterpret_cast<const f16x8*>(&Ul[bidx]);
      accH[nf] = __builtin_amdgcn_mfma_f32_16x16x32_f16(ah, bh, accH[nf], 0, 0, 0);
      accL[nf] = __builtin_amdgcn_mfma_f32_16x16x32_f16(ah, bl, accL[nf], 0, 0, 0);
      accL[nf] = __builtin_amdgcn_mfma_f32_16x16x32_f16(al, bh, accL[nf], 0, 0, 0);
    }
  }
  const int row0 = m0 + lg * 4;
#pragma unroll
  for (int nf = 0; nf < 2; nf++) {
    const int col = n0 + nf * 16 + lr;
    const double zcd = FAC.z[col] / FAC.z[0];
#pragma unroll
    for (int r = 0; r < 4; r++) {
      const int row = row0 + r;
      const float g = accH[nf][r] + accL[nf][r] * INV_LSCALE
                    - (float)(FAC.z[row] * zcd);
      const _Float16 gh = (_Float16)g;
      Gh[(size_t)row * 256 + col] = gh;
      Gl[(size_t)row * 256 + col] = (_Float16)((g - (float)gh) * LSCALE);
    }
  }
}

// ---------------- transpose + fp32->fp16 convert: in [K][N] -> out [N][K] ----------------
__global__ __launch_bounds__(256) void transpose_cvt(
    const float* __restrict__ in, _Float16* __restrict__ out, int K, int N)
{
  __shared__ float t[32][33];
  const int bk = blockIdx.x * 32, bn = blockIdx.y * 32;
  const int x = threadIdx.x, y = threadIdx.y;
  for (int yy = y; yy < 32; yy += 8) {
    const int k = bk + yy, n = bn + x;
    t[yy][x] = (k < K && n < N) ? in[(size_t)k * N + n] : 0.f;
  }
  __syncthreads();
  for (int yy = y; yy < 32; yy += 8) {
    const int n = bn + yy, k = bk + x;
    if (n < N && k < K) out[(size_t)n * K + k] = (_Float16)t[x][yy];
  }
}

// ---------------- MFMA GEMM (BK=32, handles fp32 A + K tails): GEMM1 ----------------
template<bool A_FP32, bool OUT_H16>
__global__ __launch_bounds__(256) void mfma_gemm(
    const void* __restrict__ Av, const _Float16* __restrict__ Bt,
    const float* __restrict__ bias, void* __restrict__ Cv,
    int M, int Nv, int K, int lda, int ldk, int ldc)
{
  __shared__ _Float16 At[128][40];
  __shared__ _Float16 Bs[128][40];
  const int tid = threadIdx.x;
  const int lane = tid & 63, wid = tid >> 6;
  const int wr = wid >> 1, wc = wid & 1;
  const int lrow = lane & 15, lb = lane >> 4;
  const int m0 = blockIdx.x * 128, n0 = blockIdx.y * 128;
  const int srow = tid >> 1, skh = (tid & 1) * 16;

  f32x4 acc[4][4];
#pragma unroll
  for (int i = 0; i < 4; i++)
#pragma unroll
    for (int j = 0; j < 4; j++) acc[i][j] = (f32x4)0.0f;

  const int nsteps = (K + 31) / 32;
  for (int t = 0; t < nsteps; ++t) {
    const int k0 = t * 32;
    if (A_FP32) {
      const float* A = (const float*)Av;
#pragma unroll
      for (int i = 0; i < 4; i++) {
        const int k = k0 + skh + i * 4;
        f16x4 hv = {};
        if (k + 4 <= K) {
          const float4 v = *reinterpret_cast<const float4*>(&A[(size_t)(m0 + srow) * lda + k]);
          hv[0] = (_Float16)v.x; hv[1] = (_Float16)v.y;
          hv[2] = (_Float16)v.z; hv[3] = (_Float16)v.w;
        } else if (k < K) {
          for (int e = 0; e < 4; e++)
            if (k + e < K) hv[e] = (_Float16)A[(size_t)(m0 + srow) * lda + k + e];
        }
        *reinterpret_cast<f16x4*>(&At[srow][skh + i * 4]) = hv;
      }
    } else {
      const _Float16* A = (const _Float16*)Av;
#pragma unroll
      for (int i = 0; i < 4; i++) {
        const int k = k0 + skh + i * 4;
        f16x4 hv = {};
        if (k + 4 <= K) hv = *reinterpret_cast<const f16x4*>(&A[(size_t)(m0 + srow) * lda + k]);
        *reinterpret_cast<f16x4*>(&At[srow][skh + i * 4]) = hv;
      }
    }
    {
      const int n = n0 + srow;
#pragma unroll
      for (int i = 0; i < 4; i++) {
        const int k = k0 + skh + i * 4;
        f16x4 hv = {};
        if (n < Nv && k + 4 <= K)
          hv = *reinterpret_cast<const f16x4*>(&Bt[(size_t)n * ldk + k]);
        *reinterpret_cast<f16x4*>(&Bs[srow][skh + i * 4]) = hv;
      }
    }
    __syncthreads();
    f16x8 af[4], bf[4];
#pragma unroll
    for (int i = 0; i < 4; i++)
      af[i] = *reinterpret_cast<const f16x8*>(&At[wr * 64 + i * 16 + lrow][lb * 8]);
#pragma unroll
    for (int j = 0; j < 4; j++)
      bf[j] = *reinterpret_cast<const f16x8*>(&Bs[wc * 64 + j * 16 + lrow][lb * 8]);
#pragma unroll
    for (int i = 0; i < 4; i++)
#pragma unroll
      for (int j = 0; j < 4; j++)
        acc[i][j] = __builtin_amdgcn_mfma_f32_16x16x32_f16(af[i], bf[j], acc[i][j], 0, 0, 0);
    __syncthreads();
  }
#pragma unroll
  for (int i = 0; i < 4; i++) {
#pragma unroll
    for (int j = 0; j < 4; j++) {
      const int gcol = n0 + wc * 64 + j * 16 + lrow;
      if (gcol < Nv) {
        const float bv = bias[gcol];
#pragma unroll
        for (int r = 0; r < 4; r++) {
          const int grow = m0 + wr * 64 + i * 16 + lb * 4 + r;
          float v = acc[i][j][r] + bv;
          if (OUT_H16) {
            v = fmaxf(v, 0.f);
            ((_Float16*)Cv)[(size_t)grow * ldc + gcol] = (_Float16)v;
          } else {
            ((float*)Cv)[(size_t)grow * ldc + gcol] = v;
          }
        }
      }
    }
  }
}

// ---------------- MFMA GEMM BK=64 (fp16 A, K%64==0, fp32 out): GEMM2 ----------------
__global__ __launch_bounds__(256) void mfma_gemm64(
    const _Float16* __restrict__ A, const _Float16* __restrict__ Bt,
    const float* __restrict__ bias, float* __restrict__ C,
    int M, int Nv, int K, int lda, int ldk, int ldc)
{
  __shared__ _Float16 At[128][72];
  __shared__ _Float16 Bs[128][72];
  const int tid = threadIdx.x;
  const int lane = tid & 63, wid = tid >> 6;
  const int wr = wid >> 1, wc = wid & 1;
  const int lrow = lane & 15, lb = lane >> 4;
  const int m0 = blockIdx.x * 128, n0 = blockIdx.y * 128;
  const int srow = tid >> 1, sh = (tid & 1) * 32;

  f32x4 acc[4][4];
#pragma unroll
  for (int i = 0; i < 4; i++)
#pragma unroll
    for (int j = 0; j < 4; j++) acc[i][j] = (f32x4)0.0f;

  const int nsteps = K >> 6;
  for (int t = 0; t < nsteps; ++t) {
    const int k0 = t * 64;
    const _Float16* asrc = &A[(size_t)(m0 + srow) * lda + k0 + sh];
#pragma unroll
    for (int i = 0; i < 4; i++)
      *reinterpret_cast<f16x8*>(&At[srow][sh + i * 8]) =
          *reinterpret_cast<const f16x8*>(asrc + i * 8);
    {
      const int n = n0 + srow;
      const _Float16* bsrc = &Bt[(size_t)n * ldk + k0 + sh];
#pragma unroll
      for (int i = 0; i < 4; i++) {
        f16x8 hv = {};
        if (n < Nv) hv = *reinterpret_cast<const f16x8*>(bsrc + i * 8);
        *reinterpret_cast<f16x8*>(&Bs[srow][sh + i * 8]) = hv;
      }
    }
    __syncthreads();
#pragma unroll
    for (int h = 0; h < 2; h++) {
      f16x8 af[4], bf[4];
#pragma unroll
      for (int i = 0; i < 4; i++)
        af[i] = *reinterpret_cast<const f16x8*>(&At[wr * 64 + i * 16 + lrow][h * 32 + lb * 8]);
#pragma unroll
      for (int j = 0; j < 4; j++)
        bf[j] = *reinterpret_cast<const f16x8*>(&Bs[wc * 64 + j * 16 + lrow][h * 32 + lb * 8]);
#pragma unroll
      for (int i = 0; i < 4; i++)
#pragma unroll
        for (int j = 0; j < 4; j++)
          acc[i][j] = __builtin_amdgcn_mfma_f32_16x16x32_f16(af[i], bf[j], acc[i][j], 0, 0, 0);
    }
    __syncthreads();
  }
#pragma unroll
  for (int i = 0; i < 4; i++) {
#pragma unroll
    for (int j = 0; j < 4; j++) {
      const int gcol = n0 + wc * 64 + j * 16 + lrow;
      if (gcol < Nv) {
        const float bv = bias[gcol];
#pragma unroll
        for (int r = 0; r < 4; r++) {
          const int grow = m0 + wr * 64 + i * 16 + lb * 4 + r;
          C[(size_t)grow * ldc + gcol] = acc[i][j][r] + bv;
        }
      }
    }
  }
}

// ---------------- initial rhs V0 = lam0 + ss + b_aug0 @ A_control (scaled split) ----
__global__ __launch_bounds__(256) void init_v(
    const float* __restrict__ NO, const float* __restrict__ ss,
    const float* __restrict__ p_smax, const float* __restrict__ p_smin,
    const float* __restrict__ p_sdmax, const float* __restrict__ p_sdmin,
    const float* __restrict__ p_sddmax, const float* __restrict__ p_sddmin,
    _Float16* __restrict__ Vh, _Float16* __restrict__ Vl, int B)
{
  __shared__ float d1s[258], d2s[258];
  const int r = blockIdx.x, j = threadIdx.x;
  const float K0 = *p_smax + *p_smin, K1 = *p_sdmax + *p_sdmin, K2 = *p_sddmax + *p_sddmin;
  const float invT = 20.f, invT2 = 400.f;
  const float* no = NO + (size_t)r * NO_LD;
  float s1 = fmaxf(0.f, no[256 + j]), s2 = fmaxf(0.f, no[512 + j]);
  float D0 = K0 - s1 + s2;
  float D1 = 0.f, D2 = 0.f;
  if (j < 255) D1 = K1 - fmaxf(0.f, no[768 + j]) + fmaxf(0.f, no[1023 + j]);
  if (j < 254) D2 = K2 - fmaxf(0.f, no[1278 + j]) + fmaxf(0.f, no[1532 + j]);
  d1s[2 + j] = D1; d2s[2 + j] = D2;
  if (j < 2) { d1s[j] = 0.f; d2s[j] = 0.f; }
  __syncthreads();
  float qn = D0 + (d1s[j + 1] - d1s[j + 2]) * invT
                + (d2s[j] - 2.f * d2s[j + 1] + d2s[j + 2]) * invT2;
  const float vn = no[j] + ss[(size_t)r * NUMV + j] + qn;
  const _Float16 vh = (_Float16)vn;
  Vh[(size_t)r * NUMV + j] = vh;
  Vl[(size_t)r * NUMV + j] = (_Float16)((vn - (float)vh) * LSCALE);
}

// ---- ALL 5 QP iterations in one kernel. Block = 16 rows, 1024 threads (16 waves).
// Wave w = 16-col MFMA slice with G fragments in REGISTERS (loaded once);
// update thread = (j = tid&255, half = tid>>8) x 4 rows. 2 barriers/iter.
__global__ __launch_bounds__(1024) void qp_solve5(
    const _Float16* __restrict__ Vh0, const _Float16* __restrict__ Vl0,
    const _Float16* __restrict__ Gh, const _Float16* __restrict__ Gl,
    const float* __restrict__ beq, const float* __restrict__ zc,
    const float* __restrict__ NO, const float* __restrict__ ss,
    const float* __restrict__ p_smax, const float* __restrict__ p_smin,
    const float* __restrict__ p_sdmax, const float* __restrict__ p_sdmin,
    const float* __restrict__ p_sddmax, const float* __restrict__ p_sddmin,
    float* __restrict__ out, int B)
{
  __shared__ float xsA[16][264], xsB[16][264];
  __shared__ _Float16 vhs[16][264], vls[16][264];
  __shared__ float zcs[256], beqs[16];
  __shared__ float red[16][4][3];
  const int tid = threadIdx.x;
  const int wave = tid >> 6, lane = tid & 63;
  const int lr = lane & 15, lg = lane >> 4;
  const int m0 = blockIdx.x * 16;
  const int n0 = wave * 16;
  const int j = tid & 255, half = tid >> 8;    // half in 0..3

  // ---- hoist G fragments for this wave's 16-col slice into registers ----
  f16x8 gh_r[8], gl_r[8];
#pragma unroll
  for (int kk = 0; kk < 8; kk++) {
    const size_t bidx = (size_t)(n0 + lr) * 256 + kk * 32 + lg * 8;
    gh_r[kk] = *reinterpret_cast<const f16x8*>(&Gh[bidx]);
    gl_r[kk] = *reinterpret_cast<const f16x8*>(&Gl[bidx]);
  }

  // ---- stage V0 (4 halfs per thread), zc, beq; zero x pads ----
  {
    const int idx = tid * 4;
    const int rl = idx >> 8, c = idx & 255;
    *reinterpret_cast<f16x4*>(&vhs[rl][c]) =
        *reinterpret_cast<const f16x4*>(&Vh0[(size_t)(m0 + rl) * 256 + c]);
    *reinterpret_cast<f16x4*>(&vls[rl][c]) =
        *reinterpret_cast<const f16x4*>(&Vl0[(size_t)(m0 + rl) * 256 + c]);
  }
  if (tid < 256) zcs[tid] = zc[tid];
  if (tid < 16) {
    beqs[tid] = beq[m0 + tid];
    xsA[tid][0] = 0.f; xsA[tid][1] = 0.f; xsA[tid][258] = 0.f; xsA[tid][259] = 0.f;
    xsB[tid][0] = 0.f; xsB[tid][1] = 0.f; xsB[tid][258] = 0.f; xsB[tid][259] = 0.f;
  }

  // ---- per-thread persistent state: lam + ss for 4 (row,col) pairs ----
  float lamr[4], ssv[4];
#pragma unroll
  for (int rr = 0; rr < 4; rr++) {
    const int gr = m0 + half * 4 + rr;
    ssv[rr] = ss[(size_t)gr * NUMV + j];
    lamr[rr] = NO[(size_t)gr * NO_LD + j];
  }
  float accP = 0.f, accF = 0.f;

  const float smax = *p_smax, smin = *p_smin;
  const float sdmax = *p_sdmax, sdmin = *p_sdmin;
  const float sddmax = *p_sddmax, sddmin = *p_sddmin;
  const float invT = 20.f, invT2 = 400.f;
  const bool h1 = j < 255, h2 = j < 254;

  const size_t primOff = (size_t)B * NUMV;
  const size_t fpOff = primOff + (size_t)QP_ITERS * B;
  const size_t accPOff = fpOff + (size_t)QP_ITERS * B;
  const size_t accFOff = accPOff + (size_t)B;

  float (*xc)[264] = xsA;
  float (*xp)[264] = xsB;

  __syncthreads();    // staged vhs/vls/zcs/beqs ready

  for (int it = 0; it < QP_ITERS; ++it) {
    // ---- Phase 1: MFMA solve (validated split-fp16 path; V in LDS, G in regs) ----
    f32x4 accH = (f32x4)0.0f, accL = (f32x4)0.0f;
#pragma unroll
    for (int kk = 0; kk < 8; kk++) {
      const f16x8 ah = *reinterpret_cast<const f16x8*>(&vhs[lr][kk * 32 + lg * 8]);
      const f16x8 al = *reinterpret_cast<const f16x8*>(&vls[lr][kk * 32 + lg * 8]);
      accH = __builtin_amdgcn_mfma_f32_16x16x32_f16(ah, gh_r[kk], accH, 0, 0, 0);
      accL = __builtin_amdgcn_mfma_f32_16x16x32_f16(ah, gl_r[kk], accL, 0, 0, 0);
      accL = __builtin_amdgcn_mfma_f32_16x16x32_f16(al, gh_r[kk], accL, 0, 0, 0);
    }
    {
      const int r0l = lg * 4;
      const int col = n0 + lr;
      const float zv = zcs[col];
#pragma unroll
      for (int r = 0; r < 4; r++)
        xc[r0l + r][col + 2] = accH[r] + accL[r] * INV_LSCALE + beqs[r0l + r] * zv;
    }
    __syncthreads();    // x ready; previous red consumed

    // ---- Phase 2: update (validated local-recompute stencils), 4 rows/thread ----
#pragma unroll
    for (int rr = 0; rr < 4; rr++) {
      const int rl = half * 4 + rr;
      const int gr = m0 + rl;
      const float xm2 = xc[rl][j];
      const float xm1 = xc[rl][j + 1];
      const float x0  = xc[rl][j + 2];
      const float x1  = xc[rl][j + 3];
      const float x2  = xc[rl][j + 4];

      const float vj = (x1 - x0) * invT;
      const float aj = (x2 - 2.f * x1 + x0) * invT2;
      const float vm1 = (x0 - xm1) * invT;
      const float am1 = (x1 - 2.f * x0 + xm1) * invT2;
      const float am2 = (x0 - 2.f * xm1 + xm2) * invT2;

      const float rv0a = fmaxf(0.f, x0 - smax), rv0b = fmaxf(0.f, smin - x0);
      const float E0 = rv0a - rv0b;
      float rv1a = 0.f, rv1b = 0.f, rv2a = 0.f, rv2b = 0.f, E1 = 0.f, E2 = 0.f;
      if (h1) { rv1a = fmaxf(0.f, vj - sdmax); rv1b = fmaxf(0.f, sdmin - vj); E1 = rv1a - rv1b; }
      if (h2) { rv2a = fmaxf(0.f, aj - sddmax); rv2b = fmaxf(0.f, sddmin - aj); E2 = rv2a - rv2b; }
      float res2 = rv0a * rv0a + rv0b * rv0b + rv1a * rv1a + rv1b * rv1b
                 + rv2a * rv2a + rv2b * rv2b;

      const float E1m = (j >= 1) ? (fmaxf(0.f, vm1 - sdmax) - fmaxf(0.f, sdmin - vm1)) : 0.f;
      const float E2m1 = (j >= 1 && h1) ? (fmaxf(0.f, am1 - sddmax) - fmaxf(0.f, sddmin - am1)) : 0.f;
      const float E2m2 = (j >= 2) ? (fmaxf(0.f, am2 - sddmax) - fmaxf(0.f, sddmin - am2)) : 0.f;

      const float dl = E0 + (E1m - E1) * invT + (E2m2 - 2.f * E2m1 + E2) * invT2;
      const float lnew = lamr[rr] - dl;
      const float fpl2 = dl * dl;
      lamr[rr] = lnew;

      const float sn0a = fmaxf(0.f, smax - x0), sn0b = fmaxf(0.f, x0 - smin);
      float sn1a = 0.f, sn1b = 0.f, sn2a = 0.f, sn2b = 0.f;
      if (h1) { sn1a = fmaxf(0.f, sdmax - vj); sn1b = fmaxf(0.f, vj - sdmin); }
      if (h2) { sn2a = fmaxf(0.f, sddmax - aj); sn2b = fmaxf(0.f, aj - sddmin); }

      float sp0a, sp0b, sp1a = 0.f, sp1b = 0.f, sp2a = 0.f, sp2b = 0.f;
      if (it == 0) {
        const float* no = NO + (size_t)gr * NO_LD;
        sp0a = fmaxf(0.f, no[256 + j]); sp0b = fmaxf(0.f, no[512 + j]);
        if (h1) { sp1a = fmaxf(0.f, no[768 + j]); sp1b = fmaxf(0.f, no[1023 + j]); }
        if (h2) { sp2a = fmaxf(0.f, no[1278 + j]); sp2b = fmaxf(0.f, no[1532 + j]); }
      } else {
        const float p0 = xp[rl][j + 2], p1 = xp[rl][j + 3], p2 = xp[rl][j + 4];
        const float vp = (p1 - p0) * invT;
        const float ap = (p2 - 2.f * p1 + p0) * invT2;
        sp0a = fmaxf(0.f, smax - p0); sp0b = fmaxf(0.f, p0 - smin);
        if (h1) { sp1a = fmaxf(0.f, sdmax - vp); sp1b = fmaxf(0.f, vp - sdmin); }
        if (h2) { sp2a = fmaxf(0.f, sddmax - ap); sp2b = fmaxf(0.f, ap - sddmin); }
      }
      const float d0a = sp0a - sn0a, d0b = sp0b - sn0b;
      const float d1a = sp1a - sn1a, d1b = sp1b - sn1b;
      const float d2a = sp2a - sn2a, d2b = sp2b - sn2b;
      float fps2 = d0a * d0a + d0b * d0b + d1a * d1a + d1b * d1b
                 + d2a * d2a + d2b * d2b;

      const float D0 = fminf(smax, x0) + fmaxf(smin, x0);
      const float D1 = h1 ? (fminf(sdmax, vj) + fmaxf(sdmin, vj)) : 0.f;
      const float D2 = h2 ? (fminf(sddmax, aj) + fmaxf(sddmin, aj)) : 0.f;
      const float D1m = (j >= 1) ? (fminf(sdmax, vm1) + fmaxf(sdmin, vm1)) : 0.f;
      const float D2m1 = (j >= 1 && h1) ? (fminf(sddmax, am1) + fmaxf(sddmin, am1)) : 0.f;
      const float D2m2 = (j >= 2) ? (fminf(sddmax, am2) + fmaxf(sddmin, am2)) : 0.f;

      if (it < QP_ITERS - 1) {
        const float vn = lnew + ssv[rr]
                       + D0 + (D1m - D1) * invT + (D2m2 - 2.f * D2m1 + D2) * invT2;
        const _Float16 vh16 = (_Float16)vn;
        vhs[rl][j] = vh16;
        vls[rl][j] = (_Float16)((vn - (float)vh16) * LSCALE);
      } else {
        out[(size_t)gr * NUMV + j] = x0;
      }

      float a = res2, b = fps2, c = fpl2;
      for (int o = 32; o > 0; o >>= 1) {
        a += __shfl_down(a, o);
        b += __shfl_down(b, o);
        c += __shfl_down(c, o);
      }
      if (lane == 0) { red[wave][rr][0] = a; red[wave][rr][1] = b; red[wave][rr][2] = c; }
    }
    __syncthreads();    // red + vhs/vls ready; xp consumed

    if (tid < 16) {
      const int rl = tid, hf = rl >> 2, rr = rl & 3;
      const int w0 = hf * 4;
      const float r2 = red[w0][rr][0] + red[w0 + 1][rr][0] + red[w0 + 2][rr][0] + red[w0 + 3][rr][0];
      const float s2 = red[w0][rr][1] + red[w0 + 1][rr][1] + red[w0 + 2][rr][1] + red[w0 + 3][rr][1];
      const float l2 = red[w0][rr][2] + red[w0 + 1][rr][2] + red[w0 + 2][rr][2] + red[w0 + 3][rr][2];
      const float pr = sqrtf(r2);
      const float fp = sqrtf(s2) + sqrtf(l2);
      out[primOff + (size_t)it * B + m0 + rl] = pr;
      out[fpOff + (size_t)it * B + m0 + rl] = fp;
      accP += pr; accF += fp;
    }
    // swap x buffers
    float (*t)[264] = xc; xc = xp; xp = t;
  }
  if (tid < 16) {
    out[accPOff + m0 + tid] = accP * (1.f / QP_ITERS);
    out[accFOff + m0 + tid] = accF * (1.f / QP_ITERS);
  }
}

extern "C" void kernel_launch(void* const* d_in, const int* in_sizes, int n_in,
                              void* d_out, int out_size, void* d_ws, size_t ws_size,
                              hipStream_t stream)
{
  const float* inp = (const float*)d_in[0];       // [B][260]
  const float* sinit = (const float*)d_in[1];     // [B][1]
  const float* ssamp = (const float*)d_in[2];     // [B][256]
  const float* p_smax = (const float*)d_in[3];
  const float* p_smin = (const float*)d_in[4];
  const float* p_sdmax = (const float*)d_in[5];
  const float* p_sdmin = (const float*)d_in[6];
  const float* p_sddmax = (const float*)d_in[7];
  const float* p_sddmin = (const float*)d_in[8];
  const float* W1 = (const float*)d_in[11];       // [260][1024]
  const float* b1 = (const float*)d_in[12];       // [1024]
  const float* W2 = (const float*)d_in[13];       // [1024][1786]
  const float* b2 = (const float*)d_in[14];       // [1786]
  float* out = (float*)d_out;

  const int B = in_sizes[1];                      // 4096
  const int IND = in_sizes[9];                    // 260
  const int H = in_sizes[12];                     // 1024
  const int OUTN = in_sizes[14];                  // 1786

  char* ws = (char*)d_ws;
  float* NO = (float*)ws;                                      // [B][1792] fp32
  char* p = ws + (size_t)B * NO_LD * 4;                        // 29,360,128
  _Float16* hH = (_Float16*)p;                                 // [B][1024] fp16
  char* q = p + (size_t)B * H * 2;                             // 37,748,736
  _Float16* W2T = (_Float16*)q;                                // [1786][1024] fp16 (dead after GEMM2)
  _Float16* Vh = (_Float16*)q;                                 // alias: fp16 [B][256]
  _Float16* Vl = (_Float16*)(q + (size_t)B * NUMV * 2);        // alias: fp16 [B][256]
  char* q2 = q + (size_t)OUTN * H * 2;                         // 41,406,464
  _Float16* W1T = (_Float16*)q2;                               // [1024][260] fp16 (dead after GEMM1)
  char* r4 = ws + 46137344;                                    // 46,137,344
  _Float16* Gh = (_Float16*)r4;                                // [256][256] fp16
  _Float16* Gl = (_Float16*)(r4 + 131072);                     // [256][256] fp16 (x2048)
  float* zc = (float*)(r4 + 262144);                           // [256] fp32
  _Float16* Uh = (_Float16*)(r4 + 263168);                     // [256][256] fp16 (U^T)
  _Float16* Ul = (_Float16*)(r4 + 263168 + 131072);            // [256][256] fp16 (x2048)

  split_u<<<256, 256, 0, stream>>>(Uh, Ul, zc);
  {
    dim3 g(16, 8);
    gemm_g<<<g, 64, 0, stream>>>(Uh, Ul, Gh, Gl);
  }
  {
    dim3 g((IND + 31) / 32, (H + 31) / 32), blk(32, 8);
    transpose_cvt<<<g, blk, 0, stream>>>(W1, W1T, IND, H);
  }
  {
    dim3 g((H + 31) / 32, (OUTN + 31) / 32), blk(32, 8);
    transpose_cvt<<<g, blk, 0, stream>>>(W2, W2T, H, OUTN);
  }
  {
    dim3 g(B / 128, H / 128);
    mfma_gemm<true, true><<<g, 256, 0, stream>>>(inp, W1T, b1, hH, B, H, IND, IND, IND, H);
  }
  {
    dim3 g(B / 128, (OUTN + 127) / 128);
    mfma_gemm64<<<g, 256, 0, stream>>>(hH, W2T, b2, NO, B, OUTN, H, H, H, NO_LD);
  }
  init_v<<<B, 256, 0, stream>>>(NO, ssamp, p_smax, p_smin, p_sdmax, p_sdmin,
                                p_sddmax, p_sddmin, Vh, Vl, B);
  qp_solve5<<<B / 16, 1024, 0, stream>>>(Vh, Vl, Gh, Gl, sinit, zc, NO, ssamp,
                                         p_smax, p_smin, p_sdmax, p_sdmin,
                                         p_sddmax, p_sddmin, out, B);
}